// Round 8
// baseline (1747.772 us; speedup 1.0000x reference)
//
#include <hip/hip_runtime.h>
#include <stdint.h>

// ---------------------------------------------------------------------------
// SpatialGNN forward, round 8.
// R7: 1016us. k_xcgru 80us x4: LDS 67KB -> 2 blocks/CU, VGPR 256 -> 2
// waves/SIMD, Occ 7%, VALUBusy 12% -- latency-bound barrier phases.
// R8: k_xcgru v2 ONLY: weight tiles 64x64 one-at-a-time (LDS 34.8KB -> 4
// blocks/CU), __launch_bounds__(256,4) caps VGPR at 128 (4 waves/SIMD),
// last-layer skips dead xb/xb2 work. Rest identical to R7.
// ---------------------------------------------------------------------------

#define NN 10000
#define EE 50000
#define BBG 512

typedef __attribute__((ext_vector_type(8))) short short8;
typedef __attribute__((ext_vector_type(4))) float f32x4;
typedef __attribute__((ext_vector_type(2))) float f32x2;

__device__ __forceinline__ float b2f(unsigned short u) {
  return __uint_as_float(((unsigned)u) << 16);
}
__device__ __forceinline__ float b2f_lo(unsigned u) { return __uint_as_float(u << 16); }
__device__ __forceinline__ float b2f_hi(unsigned u) { return __uint_as_float(u & 0xFFFF0000u); }
__device__ __forceinline__ unsigned short f2b(float f) {
  unsigned u = __float_as_uint(f);
  u += 0x7FFFu + ((u >> 16) & 1u);  // RNE
  return (unsigned short)(u >> 16);
}
__device__ __forceinline__ float sigm(float x) { return 1.0f / (1.0f + __expf(-x)); }
__device__ __forceinline__ float siluf(float x) { return x / (1.0f + __expf(-x)); }
__device__ __forceinline__ float rawf(const void* p, int f, int i) {
  return f ? b2f(((const unsigned short*)p)[i]) : ((const float*)p)[i];
}

// ---------------- dtype detection on edge_attr (uniform[0,1)) --------------
__global__ __launch_bounds__(256) void k_detect(const unsigned* __restrict__ w,
                                                int* __restrict__ flag) {
  __shared__ int cnt;
  if (threadIdx.x == 0) cnt = 0;
  __syncthreads();
  int c = 0;
  for (int i = threadIdx.x; i < 4096; i += 256) {
    unsigned lo = w[i] & 0xFFFFu;
    if (lo - 0x3A00u < 0x600u) c++;
  }
  atomicAdd(&cnt, c);
  __syncthreads();
  if (threadIdx.x == 0) *flag = (cnt > 2048) ? 1 : 0;  // 1 = inputs are bf16
}

// ---------------- convert weight inputs to canonical fp32 ------------------
#define NCVT 20
struct Cvt {
  const void* src[NCVT];
  float* dst[NCVT];
  int n[NCVT];
};

__global__ __launch_bounds__(256) void k_convert(Cvt c, const int* __restrict__ flag) {
  const int f = *flag;
  const int stride = gridDim.x * blockDim.x;
  const int tid = blockIdx.x * blockDim.x + threadIdx.x;
#pragma unroll 1
  for (int a = 0; a < NCVT; a++) {
    const int n = c.n[a];
    const float* sf = (const float*)c.src[a];
    const unsigned short* sb = (const unsigned short*)c.src[a];
    float* d = c.dst[a];
    for (int i = tid; i < n; i += stride) d[i] = f ? b2f(sb[i]) : sf[i];
  }
}

// ---- LSTM/head weight transposes for coalesced k_s2s access ---------------
__global__ __launch_bounds__(256) void k_ltrans(const float* __restrict__ Wih,
                                                const float* __restrict__ Whh,
                                                const float* __restrict__ W1,
                                                float* __restrict__ WihT,
                                                float* __restrict__ WhhT,
                                                float* __restrict__ W1T) {
  int j = blockIdx.x * 256 + threadIdx.x;
  if (j < 32768) {
    int r = j & 255, k = j >> 8;
    WihT[k * 256 + r] = Wih[r * 128 + k];
  } else if (j < 49152) {
    int q = j - 32768;
    int r = q & 255, k = q >> 8;
    WhhT[k * 256 + r] = Whh[r * 64 + k];
  } else if (j < 57344) {
    int q = j - 49152;
    int o = q & 63, k = q >> 6;
    W1T[k * 64 + o] = W1[o * 128 + k];
  }
}

// ---------------- CSR by src + dst degree histogram ------------------------
__global__ __launch_bounds__(256) void k_hist(const int* __restrict__ ei,
                                              int* __restrict__ cnt,
                                              int* __restrict__ cntd) {
  int e = blockIdx.x * 256 + threadIdx.x;
  if (e < EE) {
    atomicAdd(cnt + ei[e], 1);
    atomicAdd(cntd + ei[EE + e], 1);
  }
}

__global__ __launch_bounds__(256) void k_scan(const int* __restrict__ cnt,
                                              const int* __restrict__ cntd,
                                              int* __restrict__ eptr,
                                              int* __restrict__ cursor,
                                              float* __restrict__ invd) {
  __shared__ int part[256];
  const int t = threadIdx.x;
  const int c0 = t * 40;
  int s = 0;
  for (int i = 0; i < 40; i++) {
    int idx = c0 + i;
    if (idx < NN) s += cnt[idx];
  }
  part[t] = s;
  __syncthreads();
  if (t == 0) {
    int run = 0;
    for (int i = 0; i < 256; i++) { int v = part[i]; part[i] = run; run += v; }
  }
  __syncthreads();
  int run = part[t];
  for (int i = 0; i < 40; i++) {
    int idx = c0 + i;
    if (idx < NN) {
      eptr[idx] = run;
      cursor[idx] = run;
      run += cnt[idx];
      invd[idx] = 1.0f / fmaxf((float)cntd[idx], 1.0f);
    }
  }
  if (t == 255) eptr[NN] = EE;
}

__global__ __launch_bounds__(256) void k_scatter(const int* __restrict__ ei,
                                                 int* __restrict__ cursor,
                                                 int* __restrict__ eord) {
  int e = blockIdx.x * 256 + threadIdx.x;
  if (e < EE) {
    int pos = atomicAdd(cursor + ei[e], 1);
    eord[pos] = e;
  }
}

// -------- lift: x = silu(x_in@flW.T+flb); also xb, xb2, agg=0 --------------
__global__ __launch_bounds__(256) void k_lift(const void* __restrict__ xin,
                                              const float* __restrict__ flW,
                                              const float* __restrict__ flb,
                                              const float* __restrict__ b2,
                                              float* __restrict__ x,
                                              unsigned short* __restrict__ xb,
                                              float* __restrict__ xb2,
                                              float* __restrict__ agg,
                                              const int* __restrict__ flag) {
  const int f = *flag;
  int node = blockIdx.x * 4 + (threadIdx.x >> 6);
  int h = threadIdx.x & 63;
  float acc = flb[h];
#pragma unroll
  for (int c = 0; c < 11; c++)
    acc += rawf(xin, f, node * 11 + c) * flW[h * 11 + c];
  float v = siluf(acc);
  x[node * 64 + h] = v;
  xb[node * 64 + h] = f2b(v);
  int xvi = __float_as_int(v);
  float a2 = 0.0f;
#pragma unroll 8
  for (int i = 0; i < 64; i++) {
    float xi = __int_as_float(__builtin_amdgcn_readlane(xvi, i));
    a2 += xi * b2[i * 64 + h];
  }
  xb2[node * 64 + h] = a2;
  agg[(size_t)node * 64 + h] = 0.0f;
}

// ---------- s[e,k] = silu(ef @ nn_W1.T + nn_b1) bf16 -----------------------
__global__ __launch_bounds__(256) void k_sdeg(const void* __restrict__ ea,
                                              const void* __restrict__ pos,
                                              const int* __restrict__ ei,
                                              const float* __restrict__ W1,
                                              const float* __restrict__ b1,
                                              unsigned short* __restrict__ s_bf,
                                              const int* __restrict__ flag) {
  const int f = *flag;
  int e = blockIdx.x * 2 + (threadIdx.x >> 7);
  int k = threadIdx.x & 127;
  int src = ei[e], dst = ei[EE + e];
  float dx = rawf(pos, f, src * 3 + 0) - rawf(pos, f, dst * 3 + 0);
  float dy = rawf(pos, f, src * 3 + 1) - rawf(pos, f, dst * 3 + 1);
  float dz = rawf(pos, f, src * 3 + 2) - rawf(pos, f, dst * 3 + 2);
  float dist = sqrtf(dx * dx + dy * dy + dz * dz);
  float acc = b1[k];
  acc += rawf(ea, f, e * 4 + 0) * W1[k * 5 + 0];
  acc += rawf(ea, f, e * 4 + 1) * W1[k * 5 + 1];
  acc += rawf(ea, f, e * 4 + 2) * W1[k * 5 + 2];
  acc += rawf(ea, f, e * 4 + 3) * W1[k * 5 + 3];
  acc += dist * W1[k * 5 + 4];
  s_bf[e * 128 + k] = f2b(siluf(acc));
}

// ---- W2t[(o*128+k)*64 + i] = bf16(W2[(i*64+o)*128 + k]) -------------------
__global__ __launch_bounds__(256) void k_w2t(const float* __restrict__ W2,
                                             unsigned short* __restrict__ W2t) {
  int j = blockIdx.x * 256 + threadIdx.x;
  int i = j & 63;
  int k = (j >> 6) & 127;
  int o = j >> 13;
  W2t[j] = f2b(W2[(size_t)(i * 64 + o) * 128 + k]);
}

// ---- T GEMM with LDS-staged coalesced epilogue ----------------------------
template <int KC>
__global__ __launch_bounds__(256) void k_T(const unsigned short* __restrict__ xb,
                                           const unsigned short* __restrict__ W2t,
                                           unsigned short* __restrict__ Tc, int K0) {
  __shared__ unsigned short sh[2 * 128 * 72];
  unsigned short* As = sh;
  unsigned short* Bs = sh + 128 * 72;
  const int t = threadIdx.x;
  const int n0 = blockIdx.x * 128;
  const int c0 = blockIdx.y * 128;
  const int lane = t & 63;
  const int w = t >> 6;
  const int lm = lane & 15;
  const int quad = lane >> 4;
  const int wm = w & 1;
  const int wn = w >> 1;

  for (int p = t; p < 128 * 8; p += 256) {
    int r = p >> 3, cc = (p & 7) * 8;
    uint4 v = make_uint4(0u, 0u, 0u, 0u);
    if (n0 + r < NN) v = *reinterpret_cast<const uint4*>(xb + (size_t)(n0 + r) * 64 + cc);
    *reinterpret_cast<uint4*>(&As[r * 72 + cc]) = v;
  }
  for (int p = t; p < 128 * 8; p += 256) {
    int r = p >> 3, cc = (p & 7) * 8;
    int c = c0 + r;
    int o = c / KC;
    int kg = K0 + (c % KC);
    uint4 v = *reinterpret_cast<const uint4*>(W2t + (size_t)(o * 128 + kg) * 64 + cc);
    *reinterpret_cast<uint4*>(&Bs[r * 72 + cc]) = v;
  }
  __syncthreads();

  f32x4 acc[4][4];
#pragma unroll
  for (int mt = 0; mt < 4; mt++)
#pragma unroll
    for (int nt = 0; nt < 4; nt++) acc[mt][nt] = (f32x4)(0.0f);

#pragma unroll
  for (int ks = 0; ks < 2; ks++) {
    const int kk = ks * 32 + quad * 8;
    short8 af[4], bfr[4];
#pragma unroll
    for (int mt = 0; mt < 4; mt++)
      af[mt] = *reinterpret_cast<const short8*>(&As[(wm * 64 + mt * 16 + lm) * 72 + kk]);
#pragma unroll
    for (int nt = 0; nt < 4; nt++)
      bfr[nt] = *reinterpret_cast<const short8*>(&Bs[(wn * 64 + nt * 16 + lm) * 72 + kk]);
#pragma unroll
    for (int mt = 0; mt < 4; mt++)
#pragma unroll
      for (int nt = 0; nt < 4; nt++)
        acc[mt][nt] = __builtin_amdgcn_mfma_f32_16x16x32_bf16(af[mt], bfr[nt], acc[mt][nt], 0, 0, 0);
  }

  __syncthreads();
  unsigned short* st = sh;
#pragma unroll
  for (int nt = 0; nt < 4; nt++) {
    int col = wn * 64 + nt * 16 + lm;
#pragma unroll
    for (int mt = 0; mt < 4; mt++) {
#pragma unroll
      for (int reg = 0; reg < 4; reg++) {
        int row = wm * 64 + mt * 16 + quad * 4 + reg;
        st[row * 132 + col] = f2b(acc[mt][nt][reg]);
      }
    }
  }
  __syncthreads();
  const int r16 = t >> 4;
  const int c8 = (t & 15) * 8;
#pragma unroll
  for (int it = 0; it < 8; it++) {
    int row = it * 16 + r16;
    int n = n0 + row;
    if (n < NN) {
      uint2 v0 = *reinterpret_cast<const uint2*>(&st[row * 132 + c8]);
      uint2 v1 = *reinterpret_cast<const uint2*>(&st[row * 132 + c8 + 4]);
      uint4 v = make_uint4(v0.x, v0.y, v1.x, v1.y);
      *reinterpret_cast<uint4*>(Tc + (size_t)n * (64 * KC) + c0 + c8) = v;
    }
  }
}

// ---- grouped edge pass: 4 nodes/block, T pre-unpacked, dual acc -----------
__global__ __launch_bounds__(256) void k_group(const unsigned short* __restrict__ Tc,
                                               const unsigned short* __restrict__ s_bf,
                                               const float* __restrict__ xb2,
                                               const int* __restrict__ ei,
                                               const int* __restrict__ eptr,
                                               const int* __restrict__ eord,
                                               float* __restrict__ agg) {
  const int n = blockIdx.x * 4 + (threadIdx.x >> 6);
  const int lane = threadIdx.x & 63;
  const int beg = eptr[n], end = eptr[n + 1];
  if (beg == end) return;
  const uint4* trow = reinterpret_cast<const uint4*>(Tc + (size_t)n * 8192 + (size_t)lane * 128);
  float tf[128];
#pragma unroll
  for (int j = 0; j < 16; j++) {
    uint4 v = trow[j];
    tf[8 * j + 0] = b2f_lo(v.x); tf[8 * j + 1] = b2f_hi(v.x);
    tf[8 * j + 2] = b2f_lo(v.y); tf[8 * j + 3] = b2f_hi(v.y);
    tf[8 * j + 4] = b2f_lo(v.z); tf[8 * j + 5] = b2f_hi(v.z);
    tf[8 * j + 6] = b2f_lo(v.w); tf[8 * j + 7] = b2f_hi(v.w);
  }
  const float xbv = xb2[(size_t)n * 64 + lane];
  for (int j = beg; j < end; j++) {
    int e = eord[j];
    int dst = ei[EE + e];
    int sw = ((const int*)(s_bf + (size_t)e * 128))[lane];
    float a0 = 0.0f, a1 = 0.0f;
#pragma unroll
    for (int q = 0; q < 64; q += 2) {
      unsigned s0 = (unsigned)__builtin_amdgcn_readlane(sw, q);
      unsigned s1 = (unsigned)__builtin_amdgcn_readlane(sw, q + 1);
      a0 += b2f_lo(s0) * tf[2 * q] + b2f_hi(s0) * tf[2 * q + 1];
      a1 += b2f_lo(s1) * tf[2 * q + 2] + b2f_hi(s1) * tf[2 * q + 3];
    }
    atomicAdd(agg + (size_t)dst * 64 + lane, a0 + a1 + xbv);
  }
}

// ---- fallback per-edge chunk dot (KC<128) ---------------------------------
template <int KC>
__global__ __launch_bounds__(256) void k_emsg(const unsigned short* __restrict__ Tc,
                                              const unsigned short* __restrict__ s_bf,
                                              const int* __restrict__ ei,
                                              float* __restrict__ m, int K0, int first) {
  int e = blockIdx.x * 4 + (threadIdx.x >> 6);
  int o = threadIdx.x & 63;
  int src = ei[e];
  const uint4* tv = reinterpret_cast<const uint4*>(Tc + ((size_t)src * 64 + o) * KC);
  const uint4* sv = reinterpret_cast<const uint4*>(s_bf + (size_t)e * 128 + K0);
  float acc = 0.0f;
#pragma unroll
  for (int j = 0; j < KC / 8; j++) {
    uint4 a = tv[j], b = sv[j];
    unsigned aa[4] = {a.x, a.y, a.z, a.w};
    unsigned bb[4] = {b.x, b.y, b.z, b.w};
#pragma unroll
    for (int q = 0; q < 4; q++)
      acc += b2f_lo(aa[q]) * b2f_lo(bb[q]) + b2f_hi(aa[q]) * b2f_hi(bb[q]);
  }
  float* mp = m + (size_t)e * 64 + o;
  if (first) *mp = acc;
  else *mp += acc;
}

__global__ __launch_bounds__(256) void k_aggm(const float* __restrict__ m,
                                              const float* __restrict__ xb2,
                                              const int* __restrict__ ei,
                                              float* __restrict__ agg) {
  int e = blockIdx.x * 4 + (threadIdx.x >> 6);
  int o = threadIdx.x & 63;
  int src = ei[e], dst = ei[EE + e];
  atomicAdd(agg + (size_t)dst * 64 + o, m[(size_t)e * 64 + o] + xb2[(size_t)src * 64 + o]);
}

// ---- fused xc + GRU + next-layer xb2/agg0 (v2: tiled weights, 4 blk/CU) ---
__global__ __launch_bounds__(256, 4) void k_xcgru(float* __restrict__ x,
                                                  unsigned short* __restrict__ xb,
                                                  float* __restrict__ agg,
                                                  const float* __restrict__ invd,
                                                  const float* __restrict__ rW,
                                                  const float* __restrict__ rb,
                                                  const float* __restrict__ Wih,
                                                  const float* __restrict__ Whh,
                                                  const float* __restrict__ bih,
                                                  const float* __restrict__ bhh,
                                                  const float* __restrict__ b2,
                                                  float* __restrict__ xb2,
                                                  int last) {
  __shared__ float Ax[64 * 34];    // old x -> new x, [k][n]
  __shared__ float Axc[64 * 34];   // xc, [k][n]
  __shared__ float Bt[64 * 68];    // one 64x64 weight tile [k][o]
  const int t = threadIdx.x;
  const int n0 = blockIdx.x * 32;
  const int tn = t >> 4, to = t & 15;

  // stage old x + rootW tile
  for (int p = t; p < 32 * 64; p += 256) {
    int n = p >> 6, k = p & 63;
    Ax[k * 34 + n] = (n0 + n < NN) ? x[(n0 + n) * 64 + k] : 0.0f;
  }
  for (int p = t; p < 64 * 64; p += 256) {
    int o = p >> 6, k = p & 63;
    Bt[k * 68 + o] = rW[p];
  }
  __syncthreads();

  // xc = silu(x@rW.T + rb + agg*invd) -> Axc; zero agg
  {
    float acc[2][4] = {{0, 0, 0, 0}, {0, 0, 0, 0}};
    for (int k = 0; k < 64; k++) {
      f32x2 a = *reinterpret_cast<const f32x2*>(&Ax[k * 34 + tn * 2]);
      f32x4 b = *reinterpret_cast<const f32x4*>(&Bt[k * 68 + to * 4]);
#pragma unroll
      for (int j = 0; j < 4; j++) {
        acc[0][j] += a[0] * b[j];
        acc[1][j] += a[1] * b[j];
      }
    }
#pragma unroll
    for (int nn = 0; nn < 2; nn++) {
      int n = n0 + tn * 2 + nn;
#pragma unroll
      for (int j = 0; j < 4; j++) {
        int o = to * 4 + j;
        float v = 0.0f;
        if (n < NN) {
          v = siluf(acc[nn][j] + rb[o] + agg[(size_t)n * 64 + o] * invd[n]);
          agg[(size_t)n * 64 + o] = 0.0f;
        }
        Axc[o * 34 + tn * 2 + nn] = v;
      }
    }
  }
  __syncthreads();

  float ai[2][3][4], ah[2][3][4];
#pragma unroll
  for (int j = 0; j < 3; j++)
#pragma unroll
    for (int hh = 0; hh < 4; hh++) {
      float bv = bih[j * 64 + to * 4 + hh];
      ai[0][j][hh] = bv; ai[1][j][hh] = bv;
      float bv2 = bhh[j * 64 + to * 4 + hh];
      ah[0][j][hh] = bv2; ah[1][j][hh] = bv2;
    }

  // gi: 3 tiles of Wih over Axc
#pragma unroll 1
  for (int j = 0; j < 3; j++) {
    for (int p = t; p < 64 * 64; p += 256) {
      int o = p >> 6, k = p & 63;
      Bt[k * 68 + o] = Wih[(j * 64 + o) * 64 + k];
    }
    __syncthreads();
    for (int k = 0; k < 64; k++) {
      f32x2 a = *reinterpret_cast<const f32x2*>(&Axc[k * 34 + tn * 2]);
      f32x4 b = *reinterpret_cast<const f32x4*>(&Bt[k * 68 + to * 4]);
#pragma unroll
      for (int hh = 0; hh < 4; hh++) {
        ai[0][j][hh] += a[0] * b[hh];
        ai[1][j][hh] += a[1] * b[hh];
      }
    }
    __syncthreads();
  }
  // gh: 3 tiles of Whh over Ax
#pragma unroll 1
  for (int j = 0; j < 3; j++) {
    for (int p = t; p < 64 * 64; p += 256) {
      int o = p >> 6, k = p & 63;
      Bt[k * 68 + o] = Whh[(j * 64 + o) * 64 + k];
    }
    __syncthreads();
    for (int k = 0; k < 64; k++) {
      f32x2 a = *reinterpret_cast<const f32x2*>(&Ax[k * 34 + tn * 2]);
      f32x4 b = *reinterpret_cast<const f32x4*>(&Bt[k * 68 + to * 4]);
#pragma unroll
      for (int hh = 0; hh < 4; hh++) {
        ah[0][j][hh] += a[0] * b[hh];
        ah[1][j][hh] += a[1] * b[hh];
      }
    }
    __syncthreads();
  }

  // gates; write x (+xb unless last); own Ax slots -> new x
#pragma unroll
  for (int nn = 0; nn < 2; nn++) {
    int n = n0 + tn * 2 + nn;
    f32x4 xn;
#pragma unroll
    for (int hh = 0; hh < 4; hh++) {
      float r = sigm(ai[nn][0][hh] + ah[nn][0][hh]);
      float z = sigm(ai[nn][1][hh] + ah[nn][1][hh]);
      float ng = tanhf(ai[nn][2][hh] + r * ah[nn][2][hh]);
      float hold = Ax[(to * 4 + hh) * 34 + tn * 2 + nn];
      xn[hh] = (1.0f - z) * ng + z * hold;
      Ax[(to * 4 + hh) * 34 + tn * 2 + nn] = xn[hh];
    }
    if (n < NN) {
      *reinterpret_cast<f32x4*>(x + n * 64 + to * 4) = xn;
      if (!last) {
        unsigned p0 = (unsigned)f2b(xn[0]) | ((unsigned)f2b(xn[1]) << 16);
        unsigned p1 = (unsigned)f2b(xn[2]) | ((unsigned)f2b(xn[3]) << 16);
        *reinterpret_cast<uint2*>(xb + (size_t)n * 64 + to * 4) = make_uint2(p0, p1);
      }
    }
  }
  if (last) return;

  // xb2 = x_new @ b2
  for (int p = t; p < 64 * 64; p += 256) {
    int i = p >> 6, o = p & 63;
    Bt[i * 68 + o] = b2[p];
  }
  __syncthreads();
  {
    float acc[2][4] = {{0, 0, 0, 0}, {0, 0, 0, 0}};
    for (int i = 0; i < 64; i++) {
      f32x2 a = *reinterpret_cast<const f32x2*>(&Ax[i * 34 + tn * 2]);
      f32x4 b = *reinterpret_cast<const f32x4*>(&Bt[i * 68 + to * 4]);
#pragma unroll
      for (int j = 0; j < 4; j++) {
        acc[0][j] += a[0] * b[j];
        acc[1][j] += a[1] * b[j];
      }
    }
#pragma unroll
    for (int nn = 0; nn < 2; nn++) {
      int n = n0 + tn * 2 + nn;
      if (n < NN)
        *reinterpret_cast<f32x4*>(xb2 + (size_t)n * 64 + to * 4) =
            *reinterpret_cast<f32x4*>(&acc[nn][0]);
    }
  }
}

// ---- fused Set2Set v2: 256 thr/graph, transposed weights, wave-parallel ---
__global__ __launch_bounds__(256) void k_s2s(const float* __restrict__ x,
                                             const int* __restrict__ batch,
                                             const float* __restrict__ WihT,
                                             const float* __restrict__ WhhT,
                                             const float* __restrict__ bih,
                                             const float* __restrict__ bhh,
                                             const float* __restrict__ W1T,
                                             const float* __restrict__ b1,
                                             const float* __restrict__ W2,
                                             const float* __restrict__ b2o,
                                             void* __restrict__ out,
                                             const int* __restrict__ flag) {
  const int b = blockIdx.x;
  const int t = threadIdx.x;
  const int lane = t & 63;
  const int w = t >> 6;
  int lo = 0, hi = NN;
  while (lo < hi) { int mid = (lo + hi) >> 1; if (batch[mid] < b) lo = mid + 1; else hi = mid; }
  const int ns = lo;
  hi = NN;
  while (lo < hi) { int mid = (lo + hi) >> 1; if (batch[mid] <= b) lo = mid + 1; else hi = mid; }
  const int cnt = lo - ns;

  __shared__ float hs[64], rs[64], cs[64], gs[256];
  __shared__ float es[512];
  __shared__ float red[4][64];
  __shared__ float wred[4], wsum[4];
  if (t < 64) { hs[t] = 0.0f; rs[t] = 0.0f; cs[t] = 0.0f; }
  __syncthreads();

  for (int step = 0; step < 3; step++) {
    float acc = bih[t] + bhh[t];
#pragma unroll 4
    for (int k = 0; k < 64; k++)
      acc += hs[k] * (WihT[k * 256 + t] + WhhT[k * 256 + t]);
#pragma unroll 4
    for (int k = 0; k < 64; k++)
      acc += rs[k] * WihT[(64 + k) * 256 + t];
    gs[t] = acc;
    __syncthreads();
    if (t < 64) {
      float ig = sigm(gs[t]), fg = sigm(gs[64 + t]);
      float gg = tanhf(gs[128 + t]), og = sigm(gs[192 + t]);
      float c = fg * cs[t] + ig * gg;
      cs[t] = c;
      hs[t] = og * tanhf(c);
    }
    __syncthreads();

    float mxw = -3.4e38f;
    for (int j = w; j < cnt; j += 4) {
      float v = x[(size_t)(ns + j) * 64 + lane] * hs[lane];
#pragma unroll
      for (int mm = 32; mm; mm >>= 1) v += __shfl_xor(v, mm, 64);
      if (lane == 0 && j < 512) es[j] = v;
      mxw = fmaxf(mxw, v);
    }
    if (lane == 0) wred[w] = mxw;
    __syncthreads();
    float mx = fmaxf(fmaxf(wred[0], wred[1]), fmaxf(wred[2], wred[3]));

    float ps = 0.0f;
    for (int i = t; i < cnt && i < 512; i += 256) {
      float a = __expf(es[i] - mx);
      es[i] = a;
      ps += a;
    }
#pragma unroll
    for (int mm = 32; mm; mm >>= 1) ps += __shfl_xor(ps, mm, 64);
    if (lane == 0) wsum[w] = ps;
    __syncthreads();
    float tot = wsum[0] + wsum[1] + wsum[2] + wsum[3];
    float inv = (cnt > 0) ? 1.0f / tot : 0.0f;

    float pr = 0.0f;
    for (int j = w; j < cnt && j < 512; j += 4)
      pr += es[j] * x[(size_t)(ns + j) * 64 + lane];
    red[w][lane] = pr;
    __syncthreads();
    if (t < 64)
      rs[t] = (red[0][t] + red[1][t] + red[2][t] + red[3][t]) * inv;
    __syncthreads();
  }

  if (t < 64) {
    float acc = b1[lane];
#pragma unroll 4
    for (int k = 0; k < 64; k++) acc += hs[k] * W1T[k * 64 + lane];
#pragma unroll 4
    for (int k = 0; k < 64; k++) acc += rs[k] * W1T[(64 + k) * 64 + lane];
    float u = siluf(acc) * W2[lane];
#pragma unroll
    for (int mm = 32; mm; mm >>= 1) u += __shfl_xor(u, mm, 64);
    if (lane == 0) {
      float v = u + b2o[0];
      if (*flag) ((unsigned short*)out)[b] = f2b(v);
      else ((float*)out)[b] = v;
    }
  }
}

// ---------------------------------------------------------------------------
template <int KC>
static void run_chunks(const unsigned short* xb, const unsigned short* W2t,
                       unsigned short* Tc, const unsigned short* s_bf,
                       const int* ei, float* m, hipStream_t stream) {
  const int nch = 128 / KC;
  for (int c = 0; c < nch; c++) {
    k_T<KC><<<dim3((NN + 127) / 128, (64 * KC) / 128), 256, 0, stream>>>(xb, W2t, Tc, c * KC);
    k_emsg<KC><<<EE / 4, 256, 0, stream>>>(Tc, s_bf, ei, m, c * KC, c == 0 ? 1 : 0);
  }
}

extern "C" void kernel_launch(void* const* d_in, const int* in_sizes, int n_in,
                              void* d_out, int out_size, void* d_ws, size_t ws_size,
                              hipStream_t stream) {
  (void)n_in; (void)out_size;
  const bool sig_order = (in_sizes[1] == 2 * EE);
  const void* p_x   = d_in[0];
  const void* p_ea  = sig_order ? d_in[2] : d_in[1];
  const void* p_pos = sig_order ? d_in[3] : d_in[2];
  const int* edge_index = (const int*)(sig_order ? d_in[1] : d_in[3]);
  const int* batch      = (const int*)d_in[4];
  const void* p_w[20];
  for (int i = 0; i < 20; i++) p_w[i] = d_in[5 + i];

  char* base = (char*)d_ws;
  size_t off = 0;
  auto alloc = [&](size_t bytes) -> char* {
    char* p = base + off;
    off = (off + bytes + 255) & ~(size_t)255;
    return p;
  };
  int* flag = (int*)alloc(4);
  static const int cvt_n[NCVT] = {
      64 * 11, 64, 128 * 5, 128, 4096 * 128, 4096,
      64 * 64, 64,
      192 * 64, 192 * 64, 192, 192,
      256 * 128, 256 * 64, 256, 256,
      64 * 128, 64, 64, 1};
  float* canon[NCVT];
  for (int i = 0; i < NCVT; i++) canon[i] = (float*)alloc((size_t)cvt_n[i] * 4);
  const float* c_flW  = canon[0];
  const float* c_flb  = canon[1];
  const float* c_W1   = canon[2];
  const float* c_b1   = canon[3];
  const float* c_W2   = canon[4];
  const float* c_b2   = canon[5];
  const float* c_rW   = canon[6];
  const float* c_rb   = canon[7];
  const float* c_gWih = canon[8];
  const float* c_gWhh = canon[9];
  const float* c_gbih = canon[10];
  const float* c_gbhh = canon[11];
  const float* c_lWih = canon[12];
  const float* c_lWhh = canon[13];
  const float* c_lbih = canon[14];
  const float* c_lbhh = canon[15];
  const float* c_oW1  = canon[16];
  const float* c_ob1  = canon[17];
  const float* c_oW2  = canon[18];
  const float* c_ob2  = canon[19];

  unsigned short* s_bf = (unsigned short*)alloc((size_t)EE * 128 * 2);
  float* m    = (float*)alloc((size_t)EE * 64 * 4);  // fallback only
  float* x    = (float*)alloc((size_t)NN * 64 * 4);
  unsigned short* xb = (unsigned short*)alloc((size_t)NN * 64 * 2);
  float* agg  = (float*)alloc((size_t)NN * 64 * 4);
  float* xb2  = (float*)alloc((size_t)NN * 64 * 4);
  unsigned short* W2t = (unsigned short*)alloc((size_t)4096 * 128 * 2);
  float* invd = (float*)alloc((size_t)NN * 4);
  int* cnt    = (int*)alloc((size_t)2 * NN * 4);
  int* cntd   = cnt + NN;
  int* eptr   = (int*)alloc((size_t)(NN + 1) * 4);
  int* cursor = (int*)alloc((size_t)NN * 4);
  int* eord   = (int*)alloc((size_t)EE * 4);
  float* WihT = (float*)alloc((size_t)128 * 256 * 4);
  float* WhhT = (float*)alloc((size_t)64 * 256 * 4);
  float* W1T  = (float*)alloc((size_t)128 * 64 * 4);
  size_t base_need = off;

  int KC = 0;
  const int kcs[5] = {128, 64, 32, 16, 8};
  for (int i = 0; i < 5; i++) {
    size_t need = base_need + (size_t)NN * 64 * kcs[i] * 2 + 256;
    if (need <= ws_size) { KC = kcs[i]; break; }
  }
  if (KC == 0) return;
  unsigned short* Tc = (unsigned short*)alloc((size_t)NN * 64 * KC * 2);

  // ---- dtype detect + weight convert + transposes ----
  k_detect<<<1, 256, 0, stream>>>((const unsigned*)p_ea, flag);
  Cvt cvt;
  for (int i = 0; i < 20; i++) cvt.src[i] = p_w[i];
  for (int i = 0; i < NCVT; i++) { cvt.dst[i] = canon[i]; cvt.n[i] = cvt_n[i]; }
  k_convert<<<512, 256, 0, stream>>>(cvt, flag);
  k_ltrans<<<224, 256, 0, stream>>>(c_lWih, c_lWhh, c_oW1, WihT, WhhT, W1T);

  // ---- prologue ----
  hipMemsetAsync(cnt, 0, (size_t)2 * NN * 4, stream);
  k_lift<<<NN / 4, 256, 0, stream>>>(p_x, c_flW, c_flb, c_b2, x, xb, xb2, agg, flag);
  k_sdeg<<<EE / 2, 256, 0, stream>>>(p_ea, p_pos, edge_index, c_W1, c_b1, s_bf, flag);
  k_w2t<<<(4096 * 128) / 256, 256, 0, stream>>>(c_W2, W2t);
  k_hist<<<(EE + 255) / 256, 256, 0, stream>>>(edge_index, cnt, cntd);
  k_scan<<<1, 256, 0, stream>>>(cnt, cntd, eptr, cursor, invd);
  k_scatter<<<(EE + 255) / 256, 256, 0, stream>>>(edge_index, cursor, eord);

  // ---- 4 message-passing layers ----
  for (int layer = 0; layer < 4; layer++) {
    if (KC == 128) {
      k_T<128><<<dim3((NN + 127) / 128, 64), 256, 0, stream>>>(xb, W2t, Tc, 0);
      k_group<<<NN / 4, 256, 0, stream>>>(Tc, s_bf, xb2, edge_index, eptr, eord, agg);
    } else {
      switch (KC) {
        case 64: run_chunks<64>(xb, W2t, Tc, s_bf, edge_index, m, stream); break;
        case 32: run_chunks<32>(xb, W2t, Tc, s_bf, edge_index, m, stream); break;
        case 16: run_chunks<16>(xb, W2t, Tc, s_bf, edge_index, m, stream); break;
        default: run_chunks<8>(xb, W2t, Tc, s_bf, edge_index, m, stream); break;
      }
      k_aggm<<<EE / 4, 256, 0, stream>>>(m, xb2, edge_index, agg);
    }
    k_xcgru<<<(NN + 31) / 32, 256, 0, stream>>>(x, xb, agg, invd, c_rW, c_rb,
                                                c_gWih, c_gWhh, c_gbih, c_gbhh,
                                                c_b2, xb2, layer == 3 ? 1 : 0);
  }

  // ---- Set2Set + output head (one kernel, 4 waves/graph) ----
  k_s2s<<<BBG, 256, 0, stream>>>(x, batch, WihT, WhhT, c_lbih, c_lbhh,
                                 W1T, c_ob1, c_oW2, c_ob2, d_out, flag);
}

// Round 9
// 1102.475 us; speedup vs baseline: 1.5853x; 1.5853x over previous
//
#include <hip/hip_runtime.h>
#include <stdint.h>

// ---------------------------------------------------------------------------
// SpatialGNN forward, round 9.
// R8: 1748us REGRESSION. __launch_bounds__(256,4) forced VGPR=64 -> scratch
// spills (FETCH 320MB, WRITE 283MB, 40ms first-touch dispatch). Tiled LDS
// structure itself is correct (passed).
// R9 = R8 with ONE change: k_xcgru uses plain __launch_bounds__(256), letting
// the allocator pick ~110-150 VGPR (no spill) while LDS 34.8KB permits
// 3-4 blocks/CU (vs R7's 2).
// ---------------------------------------------------------------------------

#define NN 10000
#define EE 50000
#define BBG 512

typedef __attribute__((ext_vector_type(8))) short short8;
typedef __attribute__((ext_vector_type(4))) float f32x4;
typedef __attribute__((ext_vector_type(2))) float f32x2;

__device__ __forceinline__ float b2f(unsigned short u) {
  return __uint_as_float(((unsigned)u) << 16);
}
__device__ __forceinline__ float b2f_lo(unsigned u) { return __uint_as_float(u << 16); }
__device__ __forceinline__ float b2f_hi(unsigned u) { return __uint_as_float(u & 0xFFFF0000u); }
__device__ __forceinline__ unsigned short f2b(float f) {
  unsigned u = __float_as_uint(f);
  u += 0x7FFFu + ((u >> 16) & 1u);  // RNE
  return (unsigned short)(u >> 16);
}
__device__ __forceinline__ float sigm(float x) { return 1.0f / (1.0f + __expf(-x)); }
__device__ __forceinline__ float siluf(float x) { return x / (1.0f + __expf(-x)); }
__device__ __forceinline__ float rawf(const void* p, int f, int i) {
  return f ? b2f(((const unsigned short*)p)[i]) : ((const float*)p)[i];
}

// ---------------- dtype detection on edge_attr (uniform[0,1)) --------------
__global__ __launch_bounds__(256) void k_detect(const unsigned* __restrict__ w,
                                                int* __restrict__ flag) {
  __shared__ int cnt;
  if (threadIdx.x == 0) cnt = 0;
  __syncthreads();
  int c = 0;
  for (int i = threadIdx.x; i < 4096; i += 256) {
    unsigned lo = w[i] & 0xFFFFu;
    if (lo - 0x3A00u < 0x600u) c++;
  }
  atomicAdd(&cnt, c);
  __syncthreads();
  if (threadIdx.x == 0) *flag = (cnt > 2048) ? 1 : 0;  // 1 = inputs are bf16
}

// ---------------- convert weight inputs to canonical fp32 ------------------
#define NCVT 20
struct Cvt {
  const void* src[NCVT];
  float* dst[NCVT];
  int n[NCVT];
};

__global__ __launch_bounds__(256) void k_convert(Cvt c, const int* __restrict__ flag) {
  const int f = *flag;
  const int stride = gridDim.x * blockDim.x;
  const int tid = blockIdx.x * blockDim.x + threadIdx.x;
#pragma unroll 1
  for (int a = 0; a < NCVT; a++) {
    const int n = c.n[a];
    const float* sf = (const float*)c.src[a];
    const unsigned short* sb = (const unsigned short*)c.src[a];
    float* d = c.dst[a];
    for (int i = tid; i < n; i += stride) d[i] = f ? b2f(sb[i]) : sf[i];
  }
}

// ---- LSTM/head weight transposes for coalesced k_s2s access ---------------
__global__ __launch_bounds__(256) void k_ltrans(const float* __restrict__ Wih,
                                                const float* __restrict__ Whh,
                                                const float* __restrict__ W1,
                                                float* __restrict__ WihT,
                                                float* __restrict__ WhhT,
                                                float* __restrict__ W1T) {
  int j = blockIdx.x * 256 + threadIdx.x;
  if (j < 32768) {
    int r = j & 255, k = j >> 8;
    WihT[k * 256 + r] = Wih[r * 128 + k];
  } else if (j < 49152) {
    int q = j - 32768;
    int r = q & 255, k = q >> 8;
    WhhT[k * 256 + r] = Whh[r * 64 + k];
  } else if (j < 57344) {
    int q = j - 49152;
    int o = q & 63, k = q >> 6;
    W1T[k * 64 + o] = W1[o * 128 + k];
  }
}

// ---------------- CSR by src + dst degree histogram ------------------------
__global__ __launch_bounds__(256) void k_hist(const int* __restrict__ ei,
                                              int* __restrict__ cnt,
                                              int* __restrict__ cntd) {
  int e = blockIdx.x * 256 + threadIdx.x;
  if (e < EE) {
    atomicAdd(cnt + ei[e], 1);
    atomicAdd(cntd + ei[EE + e], 1);
  }
}

__global__ __launch_bounds__(256) void k_scan(const int* __restrict__ cnt,
                                              const int* __restrict__ cntd,
                                              int* __restrict__ eptr,
                                              int* __restrict__ cursor,
                                              float* __restrict__ invd) {
  __shared__ int part[256];
  const int t = threadIdx.x;
  const int c0 = t * 40;
  int s = 0;
  for (int i = 0; i < 40; i++) {
    int idx = c0 + i;
    if (idx < NN) s += cnt[idx];
  }
  part[t] = s;
  __syncthreads();
  if (t == 0) {
    int run = 0;
    for (int i = 0; i < 256; i++) { int v = part[i]; part[i] = run; run += v; }
  }
  __syncthreads();
  int run = part[t];
  for (int i = 0; i < 40; i++) {
    int idx = c0 + i;
    if (idx < NN) {
      eptr[idx] = run;
      cursor[idx] = run;
      run += cnt[idx];
      invd[idx] = 1.0f / fmaxf((float)cntd[idx], 1.0f);
    }
  }
  if (t == 255) eptr[NN] = EE;
}

__global__ __launch_bounds__(256) void k_scatter(const int* __restrict__ ei,
                                                 int* __restrict__ cursor,
                                                 int* __restrict__ eord) {
  int e = blockIdx.x * 256 + threadIdx.x;
  if (e < EE) {
    int pos = atomicAdd(cursor + ei[e], 1);
    eord[pos] = e;
  }
}

// -------- lift: x = silu(x_in@flW.T+flb); also xb, xb2, agg=0 --------------
__global__ __launch_bounds__(256) void k_lift(const void* __restrict__ xin,
                                              const float* __restrict__ flW,
                                              const float* __restrict__ flb,
                                              const float* __restrict__ b2,
                                              float* __restrict__ x,
                                              unsigned short* __restrict__ xb,
                                              float* __restrict__ xb2,
                                              float* __restrict__ agg,
                                              const int* __restrict__ flag) {
  const int f = *flag;
  int node = blockIdx.x * 4 + (threadIdx.x >> 6);
  int h = threadIdx.x & 63;
  float acc = flb[h];
#pragma unroll
  for (int c = 0; c < 11; c++)
    acc += rawf(xin, f, node * 11 + c) * flW[h * 11 + c];
  float v = siluf(acc);
  x[node * 64 + h] = v;
  xb[node * 64 + h] = f2b(v);
  int xvi = __float_as_int(v);
  float a2 = 0.0f;
#pragma unroll 8
  for (int i = 0; i < 64; i++) {
    float xi = __int_as_float(__builtin_amdgcn_readlane(xvi, i));
    a2 += xi * b2[i * 64 + h];
  }
  xb2[node * 64 + h] = a2;
  agg[(size_t)node * 64 + h] = 0.0f;
}

// ---------- s[e,k] = silu(ef @ nn_W1.T + nn_b1) bf16 -----------------------
__global__ __launch_bounds__(256) void k_sdeg(const void* __restrict__ ea,
                                              const void* __restrict__ pos,
                                              const int* __restrict__ ei,
                                              const float* __restrict__ W1,
                                              const float* __restrict__ b1,
                                              unsigned short* __restrict__ s_bf,
                                              const int* __restrict__ flag) {
  const int f = *flag;
  int e = blockIdx.x * 2 + (threadIdx.x >> 7);
  int k = threadIdx.x & 127;
  int src = ei[e], dst = ei[EE + e];
  float dx = rawf(pos, f, src * 3 + 0) - rawf(pos, f, dst * 3 + 0);
  float dy = rawf(pos, f, src * 3 + 1) - rawf(pos, f, dst * 3 + 1);
  float dz = rawf(pos, f, src * 3 + 2) - rawf(pos, f, dst * 3 + 2);
  float dist = sqrtf(dx * dx + dy * dy + dz * dz);
  float acc = b1[k];
  acc += rawf(ea, f, e * 4 + 0) * W1[k * 5 + 0];
  acc += rawf(ea, f, e * 4 + 1) * W1[k * 5 + 1];
  acc += rawf(ea, f, e * 4 + 2) * W1[k * 5 + 2];
  acc += rawf(ea, f, e * 4 + 3) * W1[k * 5 + 3];
  acc += dist * W1[k * 5 + 4];
  s_bf[e * 128 + k] = f2b(siluf(acc));
}

// ---- W2t[(o*128+k)*64 + i] = bf16(W2[(i*64+o)*128 + k]) -------------------
__global__ __launch_bounds__(256) void k_w2t(const float* __restrict__ W2,
                                             unsigned short* __restrict__ W2t) {
  int j = blockIdx.x * 256 + threadIdx.x;
  int i = j & 63;
  int k = (j >> 6) & 127;
  int o = j >> 13;
  W2t[j] = f2b(W2[(size_t)(i * 64 + o) * 128 + k]);
}

// ---- T GEMM with LDS-staged coalesced epilogue ----------------------------
template <int KC>
__global__ __launch_bounds__(256) void k_T(const unsigned short* __restrict__ xb,
                                           const unsigned short* __restrict__ W2t,
                                           unsigned short* __restrict__ Tc, int K0) {
  __shared__ unsigned short sh[2 * 128 * 72];
  unsigned short* As = sh;
  unsigned short* Bs = sh + 128 * 72;
  const int t = threadIdx.x;
  const int n0 = blockIdx.x * 128;
  const int c0 = blockIdx.y * 128;
  const int lane = t & 63;
  const int w = t >> 6;
  const int lm = lane & 15;
  const int quad = lane >> 4;
  const int wm = w & 1;
  const int wn = w >> 1;

  for (int p = t; p < 128 * 8; p += 256) {
    int r = p >> 3, cc = (p & 7) * 8;
    uint4 v = make_uint4(0u, 0u, 0u, 0u);
    if (n0 + r < NN) v = *reinterpret_cast<const uint4*>(xb + (size_t)(n0 + r) * 64 + cc);
    *reinterpret_cast<uint4*>(&As[r * 72 + cc]) = v;
  }
  for (int p = t; p < 128 * 8; p += 256) {
    int r = p >> 3, cc = (p & 7) * 8;
    int c = c0 + r;
    int o = c / KC;
    int kg = K0 + (c % KC);
    uint4 v = *reinterpret_cast<const uint4*>(W2t + (size_t)(o * 128 + kg) * 64 + cc);
    *reinterpret_cast<uint4*>(&Bs[r * 72 + cc]) = v;
  }
  __syncthreads();

  f32x4 acc[4][4];
#pragma unroll
  for (int mt = 0; mt < 4; mt++)
#pragma unroll
    for (int nt = 0; nt < 4; nt++) acc[mt][nt] = (f32x4)(0.0f);

#pragma unroll
  for (int ks = 0; ks < 2; ks++) {
    const int kk = ks * 32 + quad * 8;
    short8 af[4], bfr[4];
#pragma unroll
    for (int mt = 0; mt < 4; mt++)
      af[mt] = *reinterpret_cast<const short8*>(&As[(wm * 64 + mt * 16 + lm) * 72 + kk]);
#pragma unroll
    for (int nt = 0; nt < 4; nt++)
      bfr[nt] = *reinterpret_cast<const short8*>(&Bs[(wn * 64 + nt * 16 + lm) * 72 + kk]);
#pragma unroll
    for (int mt = 0; mt < 4; mt++)
#pragma unroll
      for (int nt = 0; nt < 4; nt++)
        acc[mt][nt] = __builtin_amdgcn_mfma_f32_16x16x32_bf16(af[mt], bfr[nt], acc[mt][nt], 0, 0, 0);
  }

  __syncthreads();
  unsigned short* st = sh;
#pragma unroll
  for (int nt = 0; nt < 4; nt++) {
    int col = wn * 64 + nt * 16 + lm;
#pragma unroll
    for (int mt = 0; mt < 4; mt++) {
#pragma unroll
      for (int reg = 0; reg < 4; reg++) {
        int row = wm * 64 + mt * 16 + quad * 4 + reg;
        st[row * 132 + col] = f2b(acc[mt][nt][reg]);
      }
    }
  }
  __syncthreads();
  const int r16 = t >> 4;
  const int c8 = (t & 15) * 8;
#pragma unroll
  for (int it = 0; it < 8; it++) {
    int row = it * 16 + r16;
    int n = n0 + row;
    if (n < NN) {
      uint2 v0 = *reinterpret_cast<const uint2*>(&st[row * 132 + c8]);
      uint2 v1 = *reinterpret_cast<const uint2*>(&st[row * 132 + c8 + 4]);
      uint4 v = make_uint4(v0.x, v0.y, v1.x, v1.y);
      *reinterpret_cast<uint4*>(Tc + (size_t)n * (64 * KC) + c0 + c8) = v;
    }
  }
}

// ---- grouped edge pass: 4 nodes/block, T pre-unpacked, dual acc -----------
__global__ __launch_bounds__(256) void k_group(const unsigned short* __restrict__ Tc,
                                               const unsigned short* __restrict__ s_bf,
                                               const float* __restrict__ xb2,
                                               const int* __restrict__ ei,
                                               const int* __restrict__ eptr,
                                               const int* __restrict__ eord,
                                               float* __restrict__ agg) {
  const int n = blockIdx.x * 4 + (threadIdx.x >> 6);
  const int lane = threadIdx.x & 63;
  const int beg = eptr[n], end = eptr[n + 1];
  if (beg == end) return;
  const uint4* trow = reinterpret_cast<const uint4*>(Tc + (size_t)n * 8192 + (size_t)lane * 128);
  float tf[128];
#pragma unroll
  for (int j = 0; j < 16; j++) {
    uint4 v = trow[j];
    tf[8 * j + 0] = b2f_lo(v.x); tf[8 * j + 1] = b2f_hi(v.x);
    tf[8 * j + 2] = b2f_lo(v.y); tf[8 * j + 3] = b2f_hi(v.y);
    tf[8 * j + 4] = b2f_lo(v.z); tf[8 * j + 5] = b2f_hi(v.z);
    tf[8 * j + 6] = b2f_lo(v.w); tf[8 * j + 7] = b2f_hi(v.w);
  }
  const float xbv = xb2[(size_t)n * 64 + lane];
  for (int j = beg; j < end; j++) {
    int e = eord[j];
    int dst = ei[EE + e];
    int sw = ((const int*)(s_bf + (size_t)e * 128))[lane];
    float a0 = 0.0f, a1 = 0.0f;
#pragma unroll
    for (int q = 0; q < 64; q += 2) {
      unsigned s0 = (unsigned)__builtin_amdgcn_readlane(sw, q);
      unsigned s1 = (unsigned)__builtin_amdgcn_readlane(sw, q + 1);
      a0 += b2f_lo(s0) * tf[2 * q] + b2f_hi(s0) * tf[2 * q + 1];
      a1 += b2f_lo(s1) * tf[2 * q + 2] + b2f_hi(s1) * tf[2 * q + 3];
    }
    atomicAdd(agg + (size_t)dst * 64 + lane, a0 + a1 + xbv);
  }
}

// ---- fallback per-edge chunk dot (KC<128) ---------------------------------
template <int KC>
__global__ __launch_bounds__(256) void k_emsg(const unsigned short* __restrict__ Tc,
                                              const unsigned short* __restrict__ s_bf,
                                              const int* __restrict__ ei,
                                              float* __restrict__ m, int K0, int first) {
  int e = blockIdx.x * 4 + (threadIdx.x >> 6);
  int o = threadIdx.x & 63;
  int src = ei[e];
  const uint4* tv = reinterpret_cast<const uint4*>(Tc + ((size_t)src * 64 + o) * KC);
  const uint4* sv = reinterpret_cast<const uint4*>(s_bf + (size_t)e * 128 + K0);
  float acc = 0.0f;
#pragma unroll
  for (int j = 0; j < KC / 8; j++) {
    uint4 a = tv[j], b = sv[j];
    unsigned aa[4] = {a.x, a.y, a.z, a.w};
    unsigned bb[4] = {b.x, b.y, b.z, b.w};
#pragma unroll
    for (int q = 0; q < 4; q++)
      acc += b2f_lo(aa[q]) * b2f_lo(bb[q]) + b2f_hi(aa[q]) * b2f_hi(bb[q]);
  }
  float* mp = m + (size_t)e * 64 + o;
  if (first) *mp = acc;
  else *mp += acc;
}

__global__ __launch_bounds__(256) void k_aggm(const float* __restrict__ m,
                                              const float* __restrict__ xb2,
                                              const int* __restrict__ ei,
                                              float* __restrict__ agg) {
  int e = blockIdx.x * 4 + (threadIdx.x >> 6);
  int o = threadIdx.x & 63;
  int src = ei[e], dst = ei[EE + e];
  atomicAdd(agg + (size_t)dst * 64 + o, m[(size_t)e * 64 + o] + xb2[(size_t)src * 64 + o]);
}

// ---- fused xc + GRU + next-layer xb2/agg0 (tiled weights, natural VGPR) ---
__global__ __launch_bounds__(256) void k_xcgru(float* __restrict__ x,
                                               unsigned short* __restrict__ xb,
                                               float* __restrict__ agg,
                                               const float* __restrict__ invd,
                                               const float* __restrict__ rW,
                                               const float* __restrict__ rb,
                                               const float* __restrict__ Wih,
                                               const float* __restrict__ Whh,
                                               const float* __restrict__ bih,
                                               const float* __restrict__ bhh,
                                               const float* __restrict__ b2,
                                               float* __restrict__ xb2,
                                               int last) {
  __shared__ float Ax[64 * 34];    // old x -> new x, [k][n]
  __shared__ float Axc[64 * 34];   // xc, [k][n]
  __shared__ float Bt[64 * 68];    // one 64x64 weight tile [k][o]
  const int t = threadIdx.x;
  const int n0 = blockIdx.x * 32;
  const int tn = t >> 4, to = t & 15;

  for (int p = t; p < 32 * 64; p += 256) {
    int n = p >> 6, k = p & 63;
    Ax[k * 34 + n] = (n0 + n < NN) ? x[(n0 + n) * 64 + k] : 0.0f;
  }
  for (int p = t; p < 64 * 64; p += 256) {
    int o = p >> 6, k = p & 63;
    Bt[k * 68 + o] = rW[p];
  }
  __syncthreads();

  // xc = silu(x@rW.T + rb + agg*invd) -> Axc; zero agg
  {
    float acc[2][4] = {{0, 0, 0, 0}, {0, 0, 0, 0}};
    for (int k = 0; k < 64; k++) {
      f32x2 a = *reinterpret_cast<const f32x2*>(&Ax[k * 34 + tn * 2]);
      f32x4 b = *reinterpret_cast<const f32x4*>(&Bt[k * 68 + to * 4]);
#pragma unroll
      for (int j = 0; j < 4; j++) {
        acc[0][j] += a[0] * b[j];
        acc[1][j] += a[1] * b[j];
      }
    }
#pragma unroll
    for (int nn = 0; nn < 2; nn++) {
      int n = n0 + tn * 2 + nn;
#pragma unroll
      for (int j = 0; j < 4; j++) {
        int o = to * 4 + j;
        float v = 0.0f;
        if (n < NN) {
          v = siluf(acc[nn][j] + rb[o] + agg[(size_t)n * 64 + o] * invd[n]);
          agg[(size_t)n * 64 + o] = 0.0f;
        }
        Axc[o * 34 + tn * 2 + nn] = v;
      }
    }
  }
  __syncthreads();

  float ai[2][3][4], ah[2][3][4];
#pragma unroll
  for (int j = 0; j < 3; j++)
#pragma unroll
    for (int hh = 0; hh < 4; hh++) {
      float bv = bih[j * 64 + to * 4 + hh];
      ai[0][j][hh] = bv; ai[1][j][hh] = bv;
      float bv2 = bhh[j * 64 + to * 4 + hh];
      ah[0][j][hh] = bv2; ah[1][j][hh] = bv2;
    }

  // gi: 3 tiles of Wih over Axc
#pragma unroll 1
  for (int j = 0; j < 3; j++) {
    for (int p = t; p < 64 * 64; p += 256) {
      int o = p >> 6, k = p & 63;
      Bt[k * 68 + o] = Wih[(j * 64 + o) * 64 + k];
    }
    __syncthreads();
    for (int k = 0; k < 64; k++) {
      f32x2 a = *reinterpret_cast<const f32x2*>(&Axc[k * 34 + tn * 2]);
      f32x4 b = *reinterpret_cast<const f32x4*>(&Bt[k * 68 + to * 4]);
#pragma unroll
      for (int hh = 0; hh < 4; hh++) {
        ai[0][j][hh] += a[0] * b[hh];
        ai[1][j][hh] += a[1] * b[hh];
      }
    }
    __syncthreads();
  }
  // gh: 3 tiles of Whh over Ax
#pragma unroll 1
  for (int j = 0; j < 3; j++) {
    for (int p = t; p < 64 * 64; p += 256) {
      int o = p >> 6, k = p & 63;
      Bt[k * 68 + o] = Whh[(j * 64 + o) * 64 + k];
    }
    __syncthreads();
    for (int k = 0; k < 64; k++) {
      f32x2 a = *reinterpret_cast<const f32x2*>(&Ax[k * 34 + tn * 2]);
      f32x4 b = *reinterpret_cast<const f32x4*>(&Bt[k * 68 + to * 4]);
#pragma unroll
      for (int hh = 0; hh < 4; hh++) {
        ah[0][j][hh] += a[0] * b[hh];
        ah[1][j][hh] += a[1] * b[hh];
      }
    }
    __syncthreads();
  }

  // gates; write x (+xb unless last); own Ax slots -> new x
#pragma unroll
  for (int nn = 0; nn < 2; nn++) {
    int n = n0 + tn * 2 + nn;
    f32x4 xn;
#pragma unroll
    for (int hh = 0; hh < 4; hh++) {
      float r = sigm(ai[nn][0][hh] + ah[nn][0][hh]);
      float z = sigm(ai[nn][1][hh] + ah[nn][1][hh]);
      float ng = tanhf(ai[nn][2][hh] + r * ah[nn][2][hh]);
      float hold = Ax[(to * 4 + hh) * 34 + tn * 2 + nn];
      xn[hh] = (1.0f - z) * ng + z * hold;
      Ax[(to * 4 + hh) * 34 + tn * 2 + nn] = xn[hh];
    }
    if (n < NN) {
      *reinterpret_cast<f32x4*>(x + n * 64 + to * 4) = xn;
      if (!last) {
        unsigned p0 = (unsigned)f2b(xn[0]) | ((unsigned)f2b(xn[1]) << 16);
        unsigned p1 = (unsigned)f2b(xn[2]) | ((unsigned)f2b(xn[3]) << 16);
        *reinterpret_cast<uint2*>(xb + (size_t)n * 64 + to * 4) = make_uint2(p0, p1);
      }
    }
  }
  if (last) return;

  // xb2 = x_new @ b2
  for (int p = t; p < 64 * 64; p += 256) {
    int i = p >> 6, o = p & 63;
    Bt[i * 68 + o] = b2[p];
  }
  __syncthreads();
  {
    float acc[2][4] = {{0, 0, 0, 0}, {0, 0, 0, 0}};
    for (int i = 0; i < 64; i++) {
      f32x2 a = *reinterpret_cast<const f32x2*>(&Ax[i * 34 + tn * 2]);
      f32x4 b = *reinterpret_cast<const f32x4*>(&Bt[i * 68 + to * 4]);
#pragma unroll
      for (int j = 0; j < 4; j++) {
        acc[0][j] += a[0] * b[j];
        acc[1][j] += a[1] * b[j];
      }
    }
#pragma unroll
    for (int nn = 0; nn < 2; nn++) {
      int n = n0 + tn * 2 + nn;
      if (n < NN)
        *reinterpret_cast<f32x4*>(xb2 + (size_t)n * 64 + to * 4) =
            *reinterpret_cast<f32x4*>(&acc[nn][0]);
    }
  }
}

// ---- fused Set2Set v2: 256 thr/graph, transposed weights, wave-parallel ---
__global__ __launch_bounds__(256) void k_s2s(const float* __restrict__ x,
                                             const int* __restrict__ batch,
                                             const float* __restrict__ WihT,
                                             const float* __restrict__ WhhT,
                                             const float* __restrict__ bih,
                                             const float* __restrict__ bhh,
                                             const float* __restrict__ W1T,
                                             const float* __restrict__ b1,
                                             const float* __restrict__ W2,
                                             const float* __restrict__ b2o,
                                             void* __restrict__ out,
                                             const int* __restrict__ flag) {
  const int b = blockIdx.x;
  const int t = threadIdx.x;
  const int lane = t & 63;
  const int w = t >> 6;
  int lo = 0, hi = NN;
  while (lo < hi) { int mid = (lo + hi) >> 1; if (batch[mid] < b) lo = mid + 1; else hi = mid; }
  const int ns = lo;
  hi = NN;
  while (lo < hi) { int mid = (lo + hi) >> 1; if (batch[mid] <= b) lo = mid + 1; else hi = mid; }
  const int cnt = lo - ns;

  __shared__ float hs[64], rs[64], cs[64], gs[256];
  __shared__ float es[512];
  __shared__ float red[4][64];
  __shared__ float wred[4], wsum[4];
  if (t < 64) { hs[t] = 0.0f; rs[t] = 0.0f; cs[t] = 0.0f; }
  __syncthreads();

  for (int step = 0; step < 3; step++) {
    float acc = bih[t] + bhh[t];
#pragma unroll 4
    for (int k = 0; k < 64; k++)
      acc += hs[k] * (WihT[k * 256 + t] + WhhT[k * 256 + t]);
#pragma unroll 4
    for (int k = 0; k < 64; k++)
      acc += rs[k] * WihT[(64 + k) * 256 + t];
    gs[t] = acc;
    __syncthreads();
    if (t < 64) {
      float ig = sigm(gs[t]), fg = sigm(gs[64 + t]);
      float gg = tanhf(gs[128 + t]), og = sigm(gs[192 + t]);
      float c = fg * cs[t] + ig * gg;
      cs[t] = c;
      hs[t] = og * tanhf(c);
    }
    __syncthreads();

    float mxw = -3.4e38f;
    for (int j = w; j < cnt; j += 4) {
      float v = x[(size_t)(ns + j) * 64 + lane] * hs[lane];
#pragma unroll
      for (int mm = 32; mm; mm >>= 1) v += __shfl_xor(v, mm, 64);
      if (lane == 0 && j < 512) es[j] = v;
      mxw = fmaxf(mxw, v);
    }
    if (lane == 0) wred[w] = mxw;
    __syncthreads();
    float mx = fmaxf(fmaxf(wred[0], wred[1]), fmaxf(wred[2], wred[3]));

    float ps = 0.0f;
    for (int i = t; i < cnt && i < 512; i += 256) {
      float a = __expf(es[i] - mx);
      es[i] = a;
      ps += a;
    }
#pragma unroll
    for (int mm = 32; mm; mm >>= 1) ps += __shfl_xor(ps, mm, 64);
    if (lane == 0) wsum[w] = ps;
    __syncthreads();
    float tot = wsum[0] + wsum[1] + wsum[2] + wsum[3];
    float inv = (cnt > 0) ? 1.0f / tot : 0.0f;

    float pr = 0.0f;
    for (int j = w; j < cnt && j < 512; j += 4)
      pr += es[j] * x[(size_t)(ns + j) * 64 + lane];
    red[w][lane] = pr;
    __syncthreads();
    if (t < 64)
      rs[t] = (red[0][t] + red[1][t] + red[2][t] + red[3][t]) * inv;
    __syncthreads();
  }

  if (t < 64) {
    float acc = b1[lane];
#pragma unroll 4
    for (int k = 0; k < 64; k++) acc += hs[k] * W1T[k * 64 + lane];
#pragma unroll 4
    for (int k = 0; k < 64; k++) acc += rs[k] * W1T[(64 + k) * 64 + lane];
    float u = siluf(acc) * W2[lane];
#pragma unroll
    for (int mm = 32; mm; mm >>= 1) u += __shfl_xor(u, mm, 64);
    if (lane == 0) {
      float v = u + b2o[0];
      if (*flag) ((unsigned short*)out)[b] = f2b(v);
      else ((float*)out)[b] = v;
    }
  }
}

// ---------------------------------------------------------------------------
template <int KC>
static void run_chunks(const unsigned short* xb, const unsigned short* W2t,
                       unsigned short* Tc, const unsigned short* s_bf,
                       const int* ei, float* m, hipStream_t stream) {
  const int nch = 128 / KC;
  for (int c = 0; c < nch; c++) {
    k_T<KC><<<dim3((NN + 127) / 128, (64 * KC) / 128), 256, 0, stream>>>(xb, W2t, Tc, c * KC);
    k_emsg<KC><<<EE / 4, 256, 0, stream>>>(Tc, s_bf, ei, m, c * KC, c == 0 ? 1 : 0);
  }
}

extern "C" void kernel_launch(void* const* d_in, const int* in_sizes, int n_in,
                              void* d_out, int out_size, void* d_ws, size_t ws_size,
                              hipStream_t stream) {
  (void)n_in; (void)out_size;
  const bool sig_order = (in_sizes[1] == 2 * EE);
  const void* p_x   = d_in[0];
  const void* p_ea  = sig_order ? d_in[2] : d_in[1];
  const void* p_pos = sig_order ? d_in[3] : d_in[2];
  const int* edge_index = (const int*)(sig_order ? d_in[1] : d_in[3]);
  const int* batch      = (const int*)d_in[4];
  const void* p_w[20];
  for (int i = 0; i < 20; i++) p_w[i] = d_in[5 + i];

  char* base = (char*)d_ws;
  size_t off = 0;
  auto alloc = [&](size_t bytes) -> char* {
    char* p = base + off;
    off = (off + bytes + 255) & ~(size_t)255;
    return p;
  };
  int* flag = (int*)alloc(4);
  static const int cvt_n[NCVT] = {
      64 * 11, 64, 128 * 5, 128, 4096 * 128, 4096,
      64 * 64, 64,
      192 * 64, 192 * 64, 192, 192,
      256 * 128, 256 * 64, 256, 256,
      64 * 128, 64, 64, 1};
  float* canon[NCVT];
  for (int i = 0; i < NCVT; i++) canon[i] = (float*)alloc((size_t)cvt_n[i] * 4);
  const float* c_flW  = canon[0];
  const float* c_flb  = canon[1];
  const float* c_W1   = canon[2];
  const float* c_b1   = canon[3];
  const float* c_W2   = canon[4];
  const float* c_b2   = canon[5];
  const float* c_rW   = canon[6];
  const float* c_rb   = canon[7];
  const float* c_gWih = canon[8];
  const float* c_gWhh = canon[9];
  const float* c_gbih = canon[10];
  const float* c_gbhh = canon[11];
  const float* c_lWih = canon[12];
  const float* c_lWhh = canon[13];
  const float* c_lbih = canon[14];
  const float* c_lbhh = canon[15];
  const float* c_oW1  = canon[16];
  const float* c_ob1  = canon[17];
  const float* c_oW2  = canon[18];
  const float* c_ob2  = canon[19];

  unsigned short* s_bf = (unsigned short*)alloc((size_t)EE * 128 * 2);
  float* m    = (float*)alloc((size_t)EE * 64 * 4);  // fallback only
  float* x    = (float*)alloc((size_t)NN * 64 * 4);
  unsigned short* xb = (unsigned short*)alloc((size_t)NN * 64 * 2);
  float* agg  = (float*)alloc((size_t)NN * 64 * 4);
  float* xb2  = (float*)alloc((size_t)NN * 64 * 4);
  unsigned short* W2t = (unsigned short*)alloc((size_t)4096 * 128 * 2);
  float* invd = (float*)alloc((size_t)NN * 4);
  int* cnt    = (int*)alloc((size_t)2 * NN * 4);
  int* cntd   = cnt + NN;
  int* eptr   = (int*)alloc((size_t)(NN + 1) * 4);
  int* cursor = (int*)alloc((size_t)NN * 4);
  int* eord   = (int*)alloc((size_t)EE * 4);
  float* WihT = (float*)alloc((size_t)128 * 256 * 4);
  float* WhhT = (float*)alloc((size_t)64 * 256 * 4);
  float* W1T  = (float*)alloc((size_t)128 * 64 * 4);
  size_t base_need = off;

  int KC = 0;
  const int kcs[5] = {128, 64, 32, 16, 8};
  for (int i = 0; i < 5; i++) {
    size_t need = base_need + (size_t)NN * 64 * kcs[i] * 2 + 256;
    if (need <= ws_size) { KC = kcs[i]; break; }
  }
  if (KC == 0) return;
  unsigned short* Tc = (unsigned short*)alloc((size_t)NN * 64 * KC * 2);

  // ---- dtype detect + weight convert + transposes ----
  k_detect<<<1, 256, 0, stream>>>((const unsigned*)p_ea, flag);
  Cvt cvt;
  for (int i = 0; i < 20; i++) cvt.src[i] = p_w[i];
  for (int i = 0; i < NCVT; i++) { cvt.dst[i] = canon[i]; cvt.n[i] = cvt_n[i]; }
  k_convert<<<512, 256, 0, stream>>>(cvt, flag);
  k_ltrans<<<224, 256, 0, stream>>>(c_lWih, c_lWhh, c_oW1, WihT, WhhT, W1T);

  // ---- prologue ----
  hipMemsetAsync(cnt, 0, (size_t)2 * NN * 4, stream);
  k_lift<<<NN / 4, 256, 0, stream>>>(p_x, c_flW, c_flb, c_b2, x, xb, xb2, agg, flag);
  k_sdeg<<<EE / 2, 256, 0, stream>>>(p_ea, p_pos, edge_index, c_W1, c_b1, s_bf, flag);
  k_w2t<<<(4096 * 128) / 256, 256, 0, stream>>>(c_W2, W2t);
  k_hist<<<(EE + 255) / 256, 256, 0, stream>>>(edge_index, cnt, cntd);
  k_scan<<<1, 256, 0, stream>>>(cnt, cntd, eptr, cursor, invd);
  k_scatter<<<(EE + 255) / 256, 256, 0, stream>>>(edge_index, cursor, eord);

  // ---- 4 message-passing layers ----
  for (int layer = 0; layer < 4; layer++) {
    if (KC == 128) {
      k_T<128><<<dim3((NN + 127) / 128, 64), 256, 0, stream>>>(xb, W2t, Tc, 0);
      k_group<<<NN / 4, 256, 0, stream>>>(Tc, s_bf, xb2, edge_index, eptr, eord, agg);
    } else {
      switch (KC) {
        case 64: run_chunks<64>(xb, W2t, Tc, s_bf, edge_index, m, stream); break;
        case 32: run_chunks<32>(xb, W2t, Tc, s_bf, edge_index, m, stream); break;
        case 16: run_chunks<16>(xb, W2t, Tc, s_bf, edge_index, m, stream); break;
        default: run_chunks<8>(xb, W2t, Tc, s_bf, edge_index, m, stream); break;
      }
      k_aggm<<<EE / 4, 256, 0, stream>>>(m, xb2, edge_index, agg);
    }
    k_xcgru<<<(NN + 31) / 32, 256, 0, stream>>>(x, xb, agg, invd, c_rW, c_rb,
                                                c_gWih, c_gWhh, c_gbih, c_gbhh,
                                                c_b2, xb2, layer == 3 ? 1 : 0);
  }

  // ---- Set2Set + output head (one kernel, 4 waves/graph) ----
  k_s2s<<<BBG, 256, 0, stream>>>(x, batch, WihT, WhhT, c_lbih, c_lbhh,
                                 W1T, c_ob1, c_oW2, c_ob2, d_out, flag);
}

// Round 10
// 861.009 us; speedup vs baseline: 2.0299x; 1.2804x over previous
//
#include <hip/hip_runtime.h>
#include <stdint.h>

// ---------------------------------------------------------------------------
// SpatialGNN forward, round 10.
// R7/R8/R9 all prove the block-LDS GRU is structurally latency-bound: 313
// blocks over 256 CUs leaves ~1 block/CU, so its barrier phases can't overlap
// (R7 80us, R9 tiled 115us, R8 vgpr-capped spilled).
// R10: k_xcgru v3 = wave-per-node, NO LDS, NO barriers. lane=channel, x/xc
// broadcast via readlane, transposed weight tables (rWT, WihT/WhhT [k][192],
// 112KB L2-resident) give coalesced 256B/wave loads. Grid 2500 blocks.
// Rest identical to R9.
// ---------------------------------------------------------------------------

#define NN 10000
#define EE 50000
#define BBG 512

typedef __attribute__((ext_vector_type(8))) short short8;
typedef __attribute__((ext_vector_type(4))) float f32x4;
typedef __attribute__((ext_vector_type(2))) float f32x2;

__device__ __forceinline__ float b2f(unsigned short u) {
  return __uint_as_float(((unsigned)u) << 16);
}
__device__ __forceinline__ float b2f_lo(unsigned u) { return __uint_as_float(u << 16); }
__device__ __forceinline__ float b2f_hi(unsigned u) { return __uint_as_float(u & 0xFFFF0000u); }
__device__ __forceinline__ unsigned short f2b(float f) {
  unsigned u = __float_as_uint(f);
  u += 0x7FFFu + ((u >> 16) & 1u);  // RNE
  return (unsigned short)(u >> 16);
}
__device__ __forceinline__ float sigm(float x) { return 1.0f / (1.0f + __expf(-x)); }
__device__ __forceinline__ float siluf(float x) { return x / (1.0f + __expf(-x)); }
__device__ __forceinline__ float rawf(const void* p, int f, int i) {
  return f ? b2f(((const unsigned short*)p)[i]) : ((const float*)p)[i];
}
__device__ __forceinline__ float rdlane(int v, int k) {
  return __int_as_float(__builtin_amdgcn_readlane(v, k));
}

// ---------------- dtype detection on edge_attr (uniform[0,1)) --------------
__global__ __launch_bounds__(256) void k_detect(const unsigned* __restrict__ w,
                                                int* __restrict__ flag) {
  __shared__ int cnt;
  if (threadIdx.x == 0) cnt = 0;
  __syncthreads();
  int c = 0;
  for (int i = threadIdx.x; i < 4096; i += 256) {
    unsigned lo = w[i] & 0xFFFFu;
    if (lo - 0x3A00u < 0x600u) c++;
  }
  atomicAdd(&cnt, c);
  __syncthreads();
  if (threadIdx.x == 0) *flag = (cnt > 2048) ? 1 : 0;  // 1 = inputs are bf16
}

// ---------------- convert weight inputs to canonical fp32 ------------------
#define NCVT 20
struct Cvt {
  const void* src[NCVT];
  float* dst[NCVT];
  int n[NCVT];
};

__global__ __launch_bounds__(256) void k_convert(Cvt c, const int* __restrict__ flag) {
  const int f = *flag;
  const int stride = gridDim.x * blockDim.x;
  const int tid = blockIdx.x * blockDim.x + threadIdx.x;
#pragma unroll 1
  for (int a = 0; a < NCVT; a++) {
    const int n = c.n[a];
    const float* sf = (const float*)c.src[a];
    const unsigned short* sb = (const unsigned short*)c.src[a];
    float* d = c.dst[a];
    for (int i = tid; i < n; i += stride) d[i] = f ? b2f(sb[i]) : sf[i];
  }
}

// ---- weight transposes: LSTM/head (k_s2s) + GRU/root (k_xcgru) ------------
__global__ __launch_bounds__(256) void k_ltrans(const float* __restrict__ Wih,
                                                const float* __restrict__ Whh,
                                                const float* __restrict__ W1,
                                                const float* __restrict__ rW,
                                                const float* __restrict__ gWih,
                                                const float* __restrict__ gWhh,
                                                float* __restrict__ WihT,
                                                float* __restrict__ WhhT,
                                                float* __restrict__ W1T,
                                                float* __restrict__ rWT,
                                                float* __restrict__ gWihT,
                                                float* __restrict__ gWhhT) {
  int j = blockIdx.x * 256 + threadIdx.x;
  if (j < 32768) {
    int r = j & 255, k = j >> 8;
    WihT[k * 256 + r] = Wih[r * 128 + k];
  } else if (j < 49152) {
    int q = j - 32768;
    int r = q & 255, k = q >> 8;
    WhhT[k * 256 + r] = Whh[r * 64 + k];
  } else if (j < 57344) {
    int q = j - 49152;
    int o = q & 63, k = q >> 6;
    W1T[k * 64 + o] = W1[o * 128 + k];
  } else if (j < 61440) {
    int q = j - 57344;
    int o = q & 63, k = q >> 6;
    rWT[k * 64 + o] = rW[o * 64 + k];
  } else if (j < 73728) {
    int q = j - 61440;
    int r = q % 192, k = q / 192;
    gWihT[k * 192 + r] = gWih[r * 64 + k];
  } else if (j < 86016) {
    int q = j - 73728;
    int r = q % 192, k = q / 192;
    gWhhT[k * 192 + r] = gWhh[r * 64 + k];
  }
}

// ---------------- CSR by src + dst degree histogram ------------------------
__global__ __launch_bounds__(256) void k_hist(const int* __restrict__ ei,
                                              int* __restrict__ cnt,
                                              int* __restrict__ cntd) {
  int e = blockIdx.x * 256 + threadIdx.x;
  if (e < EE) {
    atomicAdd(cnt + ei[e], 1);
    atomicAdd(cntd + ei[EE + e], 1);
  }
}

__global__ __launch_bounds__(256) void k_scan(const int* __restrict__ cnt,
                                              const int* __restrict__ cntd,
                                              int* __restrict__ eptr,
                                              int* __restrict__ cursor,
                                              float* __restrict__ invd) {
  __shared__ int part[256];
  const int t = threadIdx.x;
  const int c0 = t * 40;
  int s = 0;
  for (int i = 0; i < 40; i++) {
    int idx = c0 + i;
    if (idx < NN) s += cnt[idx];
  }
  part[t] = s;
  __syncthreads();
  if (t == 0) {
    int run = 0;
    for (int i = 0; i < 256; i++) { int v = part[i]; part[i] = run; run += v; }
  }
  __syncthreads();
  int run = part[t];
  for (int i = 0; i < 40; i++) {
    int idx = c0 + i;
    if (idx < NN) {
      eptr[idx] = run;
      cursor[idx] = run;
      run += cnt[idx];
      invd[idx] = 1.0f / fmaxf((float)cntd[idx], 1.0f);
    }
  }
  if (t == 255) eptr[NN] = EE;
}

__global__ __launch_bounds__(256) void k_scatter(const int* __restrict__ ei,
                                                 int* __restrict__ cursor,
                                                 int* __restrict__ eord) {
  int e = blockIdx.x * 256 + threadIdx.x;
  if (e < EE) {
    int pos = atomicAdd(cursor + ei[e], 1);
    eord[pos] = e;
  }
}

// -------- lift: x = silu(x_in@flW.T+flb); also xb, xb2, agg=0 --------------
__global__ __launch_bounds__(256) void k_lift(const void* __restrict__ xin,
                                              const float* __restrict__ flW,
                                              const float* __restrict__ flb,
                                              const float* __restrict__ b2,
                                              float* __restrict__ x,
                                              unsigned short* __restrict__ xb,
                                              float* __restrict__ xb2,
                                              float* __restrict__ agg,
                                              const int* __restrict__ flag) {
  const int f = *flag;
  int node = blockIdx.x * 4 + (threadIdx.x >> 6);
  int h = threadIdx.x & 63;
  float acc = flb[h];
#pragma unroll
  for (int c = 0; c < 11; c++)
    acc += rawf(xin, f, node * 11 + c) * flW[h * 11 + c];
  float v = siluf(acc);
  x[node * 64 + h] = v;
  xb[node * 64 + h] = f2b(v);
  int xvi = __float_as_int(v);
  float a2 = 0.0f;
#pragma unroll 8
  for (int i = 0; i < 64; i++) {
    float xi = rdlane(xvi, i);
    a2 += xi * b2[i * 64 + h];
  }
  xb2[node * 64 + h] = a2;
  agg[(size_t)node * 64 + h] = 0.0f;
}

// ---------- s[e,k] = silu(ef @ nn_W1.T + nn_b1) bf16 -----------------------
__global__ __launch_bounds__(256) void k_sdeg(const void* __restrict__ ea,
                                              const void* __restrict__ pos,
                                              const int* __restrict__ ei,
                                              const float* __restrict__ W1,
                                              const float* __restrict__ b1,
                                              unsigned short* __restrict__ s_bf,
                                              const int* __restrict__ flag) {
  const int f = *flag;
  int e = blockIdx.x * 2 + (threadIdx.x >> 7);
  int k = threadIdx.x & 127;
  int src = ei[e], dst = ei[EE + e];
  float dx = rawf(pos, f, src * 3 + 0) - rawf(pos, f, dst * 3 + 0);
  float dy = rawf(pos, f, src * 3 + 1) - rawf(pos, f, dst * 3 + 1);
  float dz = rawf(pos, f, src * 3 + 2) - rawf(pos, f, dst * 3 + 2);
  float dist = sqrtf(dx * dx + dy * dy + dz * dz);
  float acc = b1[k];
  acc += rawf(ea, f, e * 4 + 0) * W1[k * 5 + 0];
  acc += rawf(ea, f, e * 4 + 1) * W1[k * 5 + 1];
  acc += rawf(ea, f, e * 4 + 2) * W1[k * 5 + 2];
  acc += rawf(ea, f, e * 4 + 3) * W1[k * 5 + 3];
  acc += dist * W1[k * 5 + 4];
  s_bf[e * 128 + k] = f2b(siluf(acc));
}

// ---- W2t[(o*128+k)*64 + i] = bf16(W2[(i*64+o)*128 + k]) -------------------
__global__ __launch_bounds__(256) void k_w2t(const float* __restrict__ W2,
                                             unsigned short* __restrict__ W2t) {
  int j = blockIdx.x * 256 + threadIdx.x;
  int i = j & 63;
  int k = (j >> 6) & 127;
  int o = j >> 13;
  W2t[j] = f2b(W2[(size_t)(i * 64 + o) * 128 + k]);
}

// ---- T GEMM with LDS-staged coalesced epilogue ----------------------------
template <int KC>
__global__ __launch_bounds__(256) void k_T(const unsigned short* __restrict__ xb,
                                           const unsigned short* __restrict__ W2t,
                                           unsigned short* __restrict__ Tc, int K0) {
  __shared__ unsigned short sh[2 * 128 * 72];
  unsigned short* As = sh;
  unsigned short* Bs = sh + 128 * 72;
  const int t = threadIdx.x;
  const int n0 = blockIdx.x * 128;
  const int c0 = blockIdx.y * 128;
  const int lane = t & 63;
  const int w = t >> 6;
  const int lm = lane & 15;
  const int quad = lane >> 4;
  const int wm = w & 1;
  const int wn = w >> 1;

  for (int p = t; p < 128 * 8; p += 256) {
    int r = p >> 3, cc = (p & 7) * 8;
    uint4 v = make_uint4(0u, 0u, 0u, 0u);
    if (n0 + r < NN) v = *reinterpret_cast<const uint4*>(xb + (size_t)(n0 + r) * 64 + cc);
    *reinterpret_cast<uint4*>(&As[r * 72 + cc]) = v;
  }
  for (int p = t; p < 128 * 8; p += 256) {
    int r = p >> 3, cc = (p & 7) * 8;
    int c = c0 + r;
    int o = c / KC;
    int kg = K0 + (c % KC);
    uint4 v = *reinterpret_cast<const uint4*>(W2t + (size_t)(o * 128 + kg) * 64 + cc);
    *reinterpret_cast<uint4*>(&Bs[r * 72 + cc]) = v;
  }
  __syncthreads();

  f32x4 acc[4][4];
#pragma unroll
  for (int mt = 0; mt < 4; mt++)
#pragma unroll
    for (int nt = 0; nt < 4; nt++) acc[mt][nt] = (f32x4)(0.0f);

#pragma unroll
  for (int ks = 0; ks < 2; ks++) {
    const int kk = ks * 32 + quad * 8;
    short8 af[4], bfr[4];
#pragma unroll
    for (int mt = 0; mt < 4; mt++)
      af[mt] = *reinterpret_cast<const short8*>(&As[(wm * 64 + mt * 16 + lm) * 72 + kk]);
#pragma unroll
    for (int nt = 0; nt < 4; nt++)
      bfr[nt] = *reinterpret_cast<const short8*>(&Bs[(wn * 64 + nt * 16 + lm) * 72 + kk]);
#pragma unroll
    for (int mt = 0; mt < 4; mt++)
#pragma unroll
      for (int nt = 0; nt < 4; nt++)
        acc[mt][nt] = __builtin_amdgcn_mfma_f32_16x16x32_bf16(af[mt], bfr[nt], acc[mt][nt], 0, 0, 0);
  }

  __syncthreads();
  unsigned short* st = sh;
#pragma unroll
  for (int nt = 0; nt < 4; nt++) {
    int col = wn * 64 + nt * 16 + lm;
#pragma unroll
    for (int mt = 0; mt < 4; mt++) {
#pragma unroll
      for (int reg = 0; reg < 4; reg++) {
        int row = wm * 64 + mt * 16 + quad * 4 + reg;
        st[row * 132 + col] = f2b(acc[mt][nt][reg]);
      }
    }
  }
  __syncthreads();
  const int r16 = t >> 4;
  const int c8 = (t & 15) * 8;
#pragma unroll
  for (int it = 0; it < 8; it++) {
    int row = it * 16 + r16;
    int n = n0 + row;
    if (n < NN) {
      uint2 v0 = *reinterpret_cast<const uint2*>(&st[row * 132 + c8]);
      uint2 v1 = *reinterpret_cast<const uint2*>(&st[row * 132 + c8 + 4]);
      uint4 v = make_uint4(v0.x, v0.y, v1.x, v1.y);
      *reinterpret_cast<uint4*>(Tc + (size_t)n * (64 * KC) + c0 + c8) = v;
    }
  }
}

// ---- grouped edge pass: 4 nodes/block, T pre-unpacked, dual acc -----------
__global__ __launch_bounds__(256) void k_group(const unsigned short* __restrict__ Tc,
                                               const unsigned short* __restrict__ s_bf,
                                               const float* __restrict__ xb2,
                                               const int* __restrict__ ei,
                                               const int* __restrict__ eptr,
                                               const int* __restrict__ eord,
                                               float* __restrict__ agg) {
  const int n = blockIdx.x * 4 + (threadIdx.x >> 6);
  const int lane = threadIdx.x & 63;
  const int beg = eptr[n], end = eptr[n + 1];
  if (beg == end) return;
  const uint4* trow = reinterpret_cast<const uint4*>(Tc + (size_t)n * 8192 + (size_t)lane * 128);
  float tf[128];
#pragma unroll
  for (int j = 0; j < 16; j++) {
    uint4 v = trow[j];
    tf[8 * j + 0] = b2f_lo(v.x); tf[8 * j + 1] = b2f_hi(v.x);
    tf[8 * j + 2] = b2f_lo(v.y); tf[8 * j + 3] = b2f_hi(v.y);
    tf[8 * j + 4] = b2f_lo(v.z); tf[8 * j + 5] = b2f_hi(v.z);
    tf[8 * j + 6] = b2f_lo(v.w); tf[8 * j + 7] = b2f_hi(v.w);
  }
  const float xbv = xb2[(size_t)n * 64 + lane];
  for (int j = beg; j < end; j++) {
    int e = eord[j];
    int dst = ei[EE + e];
    int sw = ((const int*)(s_bf + (size_t)e * 128))[lane];
    float a0 = 0.0f, a1 = 0.0f;
#pragma unroll
    for (int q = 0; q < 64; q += 2) {
      unsigned s0 = (unsigned)__builtin_amdgcn_readlane(sw, q);
      unsigned s1 = (unsigned)__builtin_amdgcn_readlane(sw, q + 1);
      a0 += b2f_lo(s0) * tf[2 * q] + b2f_hi(s0) * tf[2 * q + 1];
      a1 += b2f_lo(s1) * tf[2 * q + 2] + b2f_hi(s1) * tf[2 * q + 3];
    }
    atomicAdd(agg + (size_t)dst * 64 + lane, a0 + a1 + xbv);
  }
}

// ---- fallback per-edge chunk dot (KC<128) ---------------------------------
template <int KC>
__global__ __launch_bounds__(256) void k_emsg(const unsigned short* __restrict__ Tc,
                                              const unsigned short* __restrict__ s_bf,
                                              const int* __restrict__ ei,
                                              float* __restrict__ m, int K0, int first) {
  int e = blockIdx.x * 4 + (threadIdx.x >> 6);
  int o = threadIdx.x & 63;
  int src = ei[e];
  const uint4* tv = reinterpret_cast<const uint4*>(Tc + ((size_t)src * 64 + o) * KC);
  const uint4* sv = reinterpret_cast<const uint4*>(s_bf + (size_t)e * 128 + K0);
  float acc = 0.0f;
#pragma unroll
  for (int j = 0; j < KC / 8; j++) {
    uint4 a = tv[j], b = sv[j];
    unsigned aa[4] = {a.x, a.y, a.z, a.w};
    unsigned bb[4] = {b.x, b.y, b.z, b.w};
#pragma unroll
    for (int q = 0; q < 4; q++)
      acc += b2f_lo(aa[q]) * b2f_lo(bb[q]) + b2f_hi(aa[q]) * b2f_hi(bb[q]);
  }
  float* mp = m + (size_t)e * 64 + o;
  if (first) *mp = acc;
  else *mp += acc;
}

__global__ __launch_bounds__(256) void k_aggm(const float* __restrict__ m,
                                              const float* __restrict__ xb2,
                                              const int* __restrict__ ei,
                                              float* __restrict__ agg) {
  int e = blockIdx.x * 4 + (threadIdx.x >> 6);
  int o = threadIdx.x & 63;
  int src = ei[e], dst = ei[EE + e];
  atomicAdd(agg + (size_t)dst * 64 + o, m[(size_t)e * 64 + o] + xb2[(size_t)src * 64 + o]);
}

// ---- xc + GRU + xb2/agg0: wave-per-node, no LDS, no barriers --------------
// lane = output channel; x/xc broadcast via readlane; transposed weights
// give coalesced 256B/wave loads (L1/L2-resident, 112KB total).
__global__ __launch_bounds__(256) void k_xcgru(float* __restrict__ x,
                                               unsigned short* __restrict__ xb,
                                               float* __restrict__ agg,
                                               const float* __restrict__ invd,
                                               const float* __restrict__ rWT,
                                               const float* __restrict__ rb,
                                               const float* __restrict__ WihT,
                                               const float* __restrict__ WhhT,
                                               const float* __restrict__ bih,
                                               const float* __restrict__ bhh,
                                               const float* __restrict__ b2,
                                               float* __restrict__ xb2,
                                               int last) {
  const int node = blockIdx.x * 4 + (threadIdx.x >> 6);
  const int lane = threadIdx.x & 63;
  const size_t base = (size_t)node * 64 + lane;
  const float xv = x[base];
  const float av = agg[base];
  agg[base] = 0.0f;
  const float idv = invd[node];
  const int xvi = __float_as_int(xv);

  // xc[lane] = silu(sum_k x_k * rWT[k][lane] + rb + agg*invd)
  float acc = 0.0f;
#pragma unroll 8
  for (int k = 0; k < 64; k++)
    acc += rdlane(xvi, k) * rWT[k * 64 + lane];
  const float xc = siluf(acc + rb[lane] + av * idv);
  const int xci = __float_as_int(xc);

  // gi (from xc) and gh (from x_old), fused loop
  float gi0 = bih[lane], gi1 = bih[64 + lane], gi2 = bih[128 + lane];
  float gh0 = bhh[lane], gh1 = bhh[64 + lane], gh2 = bhh[128 + lane];
#pragma unroll 4
  for (int k = 0; k < 64; k++) {
    const float xck = rdlane(xci, k);
    const float xvk = rdlane(xvi, k);
    const float* wi = WihT + k * 192;
    const float* wh = WhhT + k * 192;
    gi0 += xck * wi[lane];
    gi1 += xck * wi[64 + lane];
    gi2 += xck * wi[128 + lane];
    gh0 += xvk * wh[lane];
    gh1 += xvk * wh[64 + lane];
    gh2 += xvk * wh[128 + lane];
  }
  const float r = sigm(gi0 + gh0);
  const float z = sigm(gi1 + gh1);
  const float ng = tanhf(gi2 + r * gh2);
  const float xn = (1.0f - z) * ng + z * xv;
  x[base] = xn;

  if (!last) {
    xb[base] = f2b(xn);
    const int xni = __float_as_int(xn);
    float a2 = 0.0f;
#pragma unroll 8
    for (int i = 0; i < 64; i++)
      a2 += rdlane(xni, i) * b2[i * 64 + lane];
    xb2[base] = a2;
  }
}

// ---- fused Set2Set v2: 256 thr/graph, transposed weights, wave-parallel ---
__global__ __launch_bounds__(256) void k_s2s(const float* __restrict__ x,
                                             const int* __restrict__ batch,
                                             const float* __restrict__ WihT,
                                             const float* __restrict__ WhhT,
                                             const float* __restrict__ bih,
                                             const float* __restrict__ bhh,
                                             const float* __restrict__ W1T,
                                             const float* __restrict__ b1,
                                             const float* __restrict__ W2,
                                             const float* __restrict__ b2o,
                                             void* __restrict__ out,
                                             const int* __restrict__ flag) {
  const int b = blockIdx.x;
  const int t = threadIdx.x;
  const int lane = t & 63;
  const int w = t >> 6;
  int lo = 0, hi = NN;
  while (lo < hi) { int mid = (lo + hi) >> 1; if (batch[mid] < b) lo = mid + 1; else hi = mid; }
  const int ns = lo;
  hi = NN;
  while (lo < hi) { int mid = (lo + hi) >> 1; if (batch[mid] <= b) lo = mid + 1; else hi = mid; }
  const int cnt = lo - ns;

  __shared__ float hs[64], rs[64], cs[64], gs[256];
  __shared__ float es[512];
  __shared__ float red[4][64];
  __shared__ float wred[4], wsum[4];
  if (t < 64) { hs[t] = 0.0f; rs[t] = 0.0f; cs[t] = 0.0f; }
  __syncthreads();

  for (int step = 0; step < 3; step++) {
    float acc = bih[t] + bhh[t];
#pragma unroll 4
    for (int k = 0; k < 64; k++)
      acc += hs[k] * (WihT[k * 256 + t] + WhhT[k * 256 + t]);
#pragma unroll 4
    for (int k = 0; k < 64; k++)
      acc += rs[k] * WihT[(64 + k) * 256 + t];
    gs[t] = acc;
    __syncthreads();
    if (t < 64) {
      float ig = sigm(gs[t]), fg = sigm(gs[64 + t]);
      float gg = tanhf(gs[128 + t]), og = sigm(gs[192 + t]);
      float c = fg * cs[t] + ig * gg;
      cs[t] = c;
      hs[t] = og * tanhf(c);
    }
    __syncthreads();

    float mxw = -3.4e38f;
    for (int j = w; j < cnt; j += 4) {
      float v = x[(size_t)(ns + j) * 64 + lane] * hs[lane];
#pragma unroll
      for (int mm = 32; mm; mm >>= 1) v += __shfl_xor(v, mm, 64);
      if (lane == 0 && j < 512) es[j] = v;
      mxw = fmaxf(mxw, v);
    }
    if (lane == 0) wred[w] = mxw;
    __syncthreads();
    float mx = fmaxf(fmaxf(wred[0], wred[1]), fmaxf(wred[2], wred[3]));

    float ps = 0.0f;
    for (int i = t; i < cnt && i < 512; i += 256) {
      float a = __expf(es[i] - mx);
      es[i] = a;
      ps += a;
    }
#pragma unroll
    for (int mm = 32; mm; mm >>= 1) ps += __shfl_xor(ps, mm, 64);
    if (lane == 0) wsum[w] = ps;
    __syncthreads();
    float tot = wsum[0] + wsum[1] + wsum[2] + wsum[3];
    float inv = (cnt > 0) ? 1.0f / tot : 0.0f;

    float pr = 0.0f;
    for (int j = w; j < cnt && j < 512; j += 4)
      pr += es[j] * x[(size_t)(ns + j) * 64 + lane];
    red[w][lane] = pr;
    __syncthreads();
    if (t < 64)
      rs[t] = (red[0][t] + red[1][t] + red[2][t] + red[3][t]) * inv;
    __syncthreads();
  }

  if (t < 64) {
    float acc = b1[lane];
#pragma unroll 4
    for (int k = 0; k < 64; k++) acc += hs[k] * W1T[k * 64 + lane];
#pragma unroll 4
    for (int k = 0; k < 64; k++) acc += rs[k] * W1T[(64 + k) * 64 + lane];
    float u = siluf(acc) * W2[lane];
#pragma unroll
    for (int mm = 32; mm; mm >>= 1) u += __shfl_xor(u, mm, 64);
    if (lane == 0) {
      float v = u + b2o[0];
      if (*flag) ((unsigned short*)out)[b] = f2b(v);
      else ((float*)out)[b] = v;
    }
  }
}

// ---------------------------------------------------------------------------
template <int KC>
static void run_chunks(const unsigned short* xb, const unsigned short* W2t,
                       unsigned short* Tc, const unsigned short* s_bf,
                       const int* ei, float* m, hipStream_t stream) {
  const int nch = 128 / KC;
  for (int c = 0; c < nch; c++) {
    k_T<KC><<<dim3((NN + 127) / 128, (64 * KC) / 128), 256, 0, stream>>>(xb, W2t, Tc, c * KC);
    k_emsg<KC><<<EE / 4, 256, 0, stream>>>(Tc, s_bf, ei, m, c * KC, c == 0 ? 1 : 0);
  }
}

extern "C" void kernel_launch(void* const* d_in, const int* in_sizes, int n_in,
                              void* d_out, int out_size, void* d_ws, size_t ws_size,
                              hipStream_t stream) {
  (void)n_in; (void)out_size;
  const bool sig_order = (in_sizes[1] == 2 * EE);
  const void* p_x   = d_in[0];
  const void* p_ea  = sig_order ? d_in[2] : d_in[1];
  const void* p_pos = sig_order ? d_in[3] : d_in[2];
  const int* edge_index = (const int*)(sig_order ? d_in[1] : d_in[3]);
  const int* batch      = (const int*)d_in[4];
  const void* p_w[20];
  for (int i = 0; i < 20; i++) p_w[i] = d_in[5 + i];

  char* base = (char*)d_ws;
  size_t off = 0;
  auto alloc = [&](size_t bytes) -> char* {
    char* p = base + off;
    off = (off + bytes + 255) & ~(size_t)255;
    return p;
  };
  int* flag = (int*)alloc(4);
  static const int cvt_n[NCVT] = {
      64 * 11, 64, 128 * 5, 128, 4096 * 128, 4096,
      64 * 64, 64,
      192 * 64, 192 * 64, 192, 192,
      256 * 128, 256 * 64, 256, 256,
      64 * 128, 64, 64, 1};
  float* canon[NCVT];
  for (int i = 0; i < NCVT; i++) canon[i] = (float*)alloc((size_t)cvt_n[i] * 4);
  const float* c_flW  = canon[0];
  const float* c_flb  = canon[1];
  const float* c_W1   = canon[2];
  const float* c_b1   = canon[3];
  const float* c_W2   = canon[4];
  const float* c_b2   = canon[5];
  const float* c_rW   = canon[6];
  const float* c_rb   = canon[7];
  const float* c_gWih = canon[8];
  const float* c_gWhh = canon[9];
  const float* c_gbih = canon[10];
  const float* c_gbhh = canon[11];
  const float* c_lWih = canon[12];
  const float* c_lWhh = canon[13];
  const float* c_lbih = canon[14];
  const float* c_lbhh = canon[15];
  const float* c_oW1  = canon[16];
  const float* c_ob1  = canon[17];
  const float* c_oW2  = canon[18];
  const float* c_ob2  = canon[19];

  unsigned short* s_bf = (unsigned short*)alloc((size_t)EE * 128 * 2);
  float* m    = (float*)alloc((size_t)EE * 64 * 4);  // fallback only
  float* x    = (float*)alloc((size_t)NN * 64 * 4);
  unsigned short* xb = (unsigned short*)alloc((size_t)NN * 64 * 2);
  float* agg  = (float*)alloc((size_t)NN * 64 * 4);
  float* xb2  = (float*)alloc((size_t)NN * 64 * 4);
  unsigned short* W2t = (unsigned short*)alloc((size_t)4096 * 128 * 2);
  float* invd = (float*)alloc((size_t)NN * 4);
  int* cnt    = (int*)alloc((size_t)2 * NN * 4);
  int* cntd   = cnt + NN;
  int* eptr   = (int*)alloc((size_t)(NN + 1) * 4);
  int* cursor = (int*)alloc((size_t)NN * 4);
  int* eord   = (int*)alloc((size_t)EE * 4);
  float* WihT = (float*)alloc((size_t)128 * 256 * 4);
  float* WhhT = (float*)alloc((size_t)64 * 256 * 4);
  float* W1T  = (float*)alloc((size_t)128 * 64 * 4);
  float* rWT  = (float*)alloc((size_t)64 * 64 * 4);
  float* gWihT = (float*)alloc((size_t)64 * 192 * 4);
  float* gWhhT = (float*)alloc((size_t)64 * 192 * 4);
  size_t base_need = off;

  int KC = 0;
  const int kcs[5] = {128, 64, 32, 16, 8};
  for (int i = 0; i < 5; i++) {
    size_t need = base_need + (size_t)NN * 64 * kcs[i] * 2 + 256;
    if (need <= ws_size) { KC = kcs[i]; break; }
  }
  if (KC == 0) return;
  unsigned short* Tc = (unsigned short*)alloc((size_t)NN * 64 * KC * 2);

  // ---- dtype detect + weight convert + transposes ----
  k_detect<<<1, 256, 0, stream>>>((const unsigned*)p_ea, flag);
  Cvt cvt;
  for (int i = 0; i < 20; i++) cvt.src[i] = p_w[i];
  for (int i = 0; i < NCVT; i++) { cvt.dst[i] = canon[i]; cvt.n[i] = cvt_n[i]; }
  k_convert<<<512, 256, 0, stream>>>(cvt, flag);
  k_ltrans<<<336, 256, 0, stream>>>(c_lWih, c_lWhh, c_oW1, c_rW, c_gWih, c_gWhh,
                                    WihT, WhhT, W1T, rWT, gWihT, gWhhT);

  // ---- prologue ----
  hipMemsetAsync(cnt, 0, (size_t)2 * NN * 4, stream);
  k_lift<<<NN / 4, 256, 0, stream>>>(p_x, c_flW, c_flb, c_b2, x, xb, xb2, agg, flag);
  k_sdeg<<<EE / 2, 256, 0, stream>>>(p_ea, p_pos, edge_index, c_W1, c_b1, s_bf, flag);
  k_w2t<<<(4096 * 128) / 256, 256, 0, stream>>>(c_W2, W2t);
  k_hist<<<(EE + 255) / 256, 256, 0, stream>>>(edge_index, cnt, cntd);
  k_scan<<<1, 256, 0, stream>>>(cnt, cntd, eptr, cursor, invd);
  k_scatter<<<(EE + 255) / 256, 256, 0, stream>>>(edge_index, cursor, eord);

  // ---- 4 message-passing layers ----
  for (int layer = 0; layer < 4; layer++) {
    if (KC == 128) {
      k_T<128><<<dim3((NN + 127) / 128, 64), 256, 0, stream>>>(xb, W2t, Tc, 0);
      k_group<<<NN / 4, 256, 0, stream>>>(Tc, s_bf, xb2, edge_index, eptr, eord, agg);
    } else {
      switch (KC) {
        case 64: run_chunks<64>(xb, W2t, Tc, s_bf, edge_index, m, stream); break;
        case 32: run_chunks<32>(xb, W2t, Tc, s_bf, edge_index, m, stream); break;
        case 16: run_chunks<16>(xb, W2t, Tc, s_bf, edge_index, m, stream); break;
        default: run_chunks<8>(xb, W2t, Tc, s_bf, edge_index, m, stream); break;
      }
      k_aggm<<<EE / 4, 256, 0, stream>>>(m, xb2, edge_index, agg);
    }
    k_xcgru<<<NN / 4, 256, 0, stream>>>(x, xb, agg, invd, rWT, c_rb,
                                        gWihT, gWhhT, c_gbih, c_gbhh,
                                        c_b2, xb2, layer == 3 ? 1 : 0);
  }

  // ---- Set2Set + output head (one kernel, 4 waves/graph) ----
  k_s2s<<<BBG, 256, 0, stream>>>(x, batch, WihT, WhhT, c_lbih, c_lbhh,
                                 W1T, c_ob1, c_oW2, c_ob2, d_out, flag);
}

// Round 11
// 816.921 us; speedup vs baseline: 2.1395x; 1.0540x over previous
//
#include <hip/hip_runtime.h>
#include <stdint.h>

// ---------------------------------------------------------------------------
// SpatialGNN forward, round 11.
// R10: 861us. k_group 74us x4: NOT BW-bound (1.2TB/s) -- per-edge 3-deep
// dependent random-load chain (eord -> ei -> s_row), serial over ~5 edges.
// R11: (1) k_sperm pre-permutes s into eord order + gathers dst once
// (s layer-invariant => amortized over 4 layers); edge loop becomes
// sequential loads. (2) k_group inner reverted to R5's packed-tw form
// (fits 84 VGPR) + dual accumulators. Rest identical to R10.
// ---------------------------------------------------------------------------

#define NN 10000
#define EE 50000
#define BBG 512

typedef __attribute__((ext_vector_type(8))) short short8;
typedef __attribute__((ext_vector_type(4))) float f32x4;
typedef __attribute__((ext_vector_type(2))) float f32x2;

__device__ __forceinline__ float b2f(unsigned short u) {
  return __uint_as_float(((unsigned)u) << 16);
}
__device__ __forceinline__ float b2f_lo(unsigned u) { return __uint_as_float(u << 16); }
__device__ __forceinline__ float b2f_hi(unsigned u) { return __uint_as_float(u & 0xFFFF0000u); }
__device__ __forceinline__ unsigned short f2b(float f) {
  unsigned u = __float_as_uint(f);
  u += 0x7FFFu + ((u >> 16) & 1u);  // RNE
  return (unsigned short)(u >> 16);
}
__device__ __forceinline__ float sigm(float x) { return 1.0f / (1.0f + __expf(-x)); }
__device__ __forceinline__ float siluf(float x) { return x / (1.0f + __expf(-x)); }
__device__ __forceinline__ float rawf(const void* p, int f, int i) {
  return f ? b2f(((const unsigned short*)p)[i]) : ((const float*)p)[i];
}
__device__ __forceinline__ float rdlane(int v, int k) {
  return __int_as_float(__builtin_amdgcn_readlane(v, k));
}

// ---------------- dtype detection on edge_attr (uniform[0,1)) --------------
__global__ __launch_bounds__(256) void k_detect(const unsigned* __restrict__ w,
                                                int* __restrict__ flag) {
  __shared__ int cnt;
  if (threadIdx.x == 0) cnt = 0;
  __syncthreads();
  int c = 0;
  for (int i = threadIdx.x; i < 4096; i += 256) {
    unsigned lo = w[i] & 0xFFFFu;
    if (lo - 0x3A00u < 0x600u) c++;
  }
  atomicAdd(&cnt, c);
  __syncthreads();
  if (threadIdx.x == 0) *flag = (cnt > 2048) ? 1 : 0;  // 1 = inputs are bf16
}

// ---------------- convert weight inputs to canonical fp32 ------------------
#define NCVT 20
struct Cvt {
  const void* src[NCVT];
  float* dst[NCVT];
  int n[NCVT];
};

__global__ __launch_bounds__(256) void k_convert(Cvt c, const int* __restrict__ flag) {
  const int f = *flag;
  const int stride = gridDim.x * blockDim.x;
  const int tid = blockIdx.x * blockDim.x + threadIdx.x;
#pragma unroll 1
  for (int a = 0; a < NCVT; a++) {
    const int n = c.n[a];
    const float* sf = (const float*)c.src[a];
    const unsigned short* sb = (const unsigned short*)c.src[a];
    float* d = c.dst[a];
    for (int i = tid; i < n; i += stride) d[i] = f ? b2f(sb[i]) : sf[i];
  }
}

// ---- weight transposes: LSTM/head (k_s2s) + GRU/root (k_xcgru) ------------
__global__ __launch_bounds__(256) void k_ltrans(const float* __restrict__ Wih,
                                                const float* __restrict__ Whh,
                                                const float* __restrict__ W1,
                                                const float* __restrict__ rW,
                                                const float* __restrict__ gWih,
                                                const float* __restrict__ gWhh,
                                                float* __restrict__ WihT,
                                                float* __restrict__ WhhT,
                                                float* __restrict__ W1T,
                                                float* __restrict__ rWT,
                                                float* __restrict__ gWihT,
                                                float* __restrict__ gWhhT) {
  int j = blockIdx.x * 256 + threadIdx.x;
  if (j < 32768) {
    int r = j & 255, k = j >> 8;
    WihT[k * 256 + r] = Wih[r * 128 + k];
  } else if (j < 49152) {
    int q = j - 32768;
    int r = q & 255, k = q >> 8;
    WhhT[k * 256 + r] = Whh[r * 64 + k];
  } else if (j < 57344) {
    int q = j - 49152;
    int o = q & 63, k = q >> 6;
    W1T[k * 64 + o] = W1[o * 128 + k];
  } else if (j < 61440) {
    int q = j - 57344;
    int o = q & 63, k = q >> 6;
    rWT[k * 64 + o] = rW[o * 64 + k];
  } else if (j < 73728) {
    int q = j - 61440;
    int r = q % 192, k = q / 192;
    gWihT[k * 192 + r] = gWih[r * 64 + k];
  } else if (j < 86016) {
    int q = j - 73728;
    int r = q % 192, k = q / 192;
    gWhhT[k * 192 + r] = gWhh[r * 64 + k];
  }
}

// ---------------- CSR by src + dst degree histogram ------------------------
__global__ __launch_bounds__(256) void k_hist(const int* __restrict__ ei,
                                              int* __restrict__ cnt,
                                              int* __restrict__ cntd) {
  int e = blockIdx.x * 256 + threadIdx.x;
  if (e < EE) {
    atomicAdd(cnt + ei[e], 1);
    atomicAdd(cntd + ei[EE + e], 1);
  }
}

__global__ __launch_bounds__(256) void k_scan(const int* __restrict__ cnt,
                                              const int* __restrict__ cntd,
                                              int* __restrict__ eptr,
                                              int* __restrict__ cursor,
                                              float* __restrict__ invd) {
  __shared__ int part[256];
  const int t = threadIdx.x;
  const int c0 = t * 40;
  int s = 0;
  for (int i = 0; i < 40; i++) {
    int idx = c0 + i;
    if (idx < NN) s += cnt[idx];
  }
  part[t] = s;
  __syncthreads();
  if (t == 0) {
    int run = 0;
    for (int i = 0; i < 256; i++) { int v = part[i]; part[i] = run; run += v; }
  }
  __syncthreads();
  int run = part[t];
  for (int i = 0; i < 40; i++) {
    int idx = c0 + i;
    if (idx < NN) {
      eptr[idx] = run;
      cursor[idx] = run;
      run += cnt[idx];
      invd[idx] = 1.0f / fmaxf((float)cntd[idx], 1.0f);
    }
  }
  if (t == 255) eptr[NN] = EE;
}

__global__ __launch_bounds__(256) void k_scatter(const int* __restrict__ ei,
                                                 int* __restrict__ cursor,
                                                 int* __restrict__ eord) {
  int e = blockIdx.x * 256 + threadIdx.x;
  if (e < EE) {
    int pos = atomicAdd(cursor + ei[e], 1);
    eord[pos] = e;
  }
}

// ---- permute s into eord order + gather dst (once; reused 4 layers) -------
__global__ __launch_bounds__(256) void k_sperm(const unsigned short* __restrict__ s_bf,
                                               const int* __restrict__ ei,
                                               const int* __restrict__ eord,
                                               unsigned* __restrict__ s_srt,
                                               int* __restrict__ dst_srt) {
  const int j = blockIdx.x * 4 + (threadIdx.x >> 6);
  const int lane = threadIdx.x & 63;
  const int e = eord[j];
  s_srt[(size_t)j * 64 + lane] = ((const unsigned*)s_bf)[(size_t)e * 64 + lane];
  if (lane == 0) dst_srt[j] = ei[EE + e];
}

// -------- lift: x = silu(x_in@flW.T+flb); also xb, xb2, agg=0 --------------
__global__ __launch_bounds__(256) void k_lift(const void* __restrict__ xin,
                                              const float* __restrict__ flW,
                                              const float* __restrict__ flb,
                                              const float* __restrict__ b2,
                                              float* __restrict__ x,
                                              unsigned short* __restrict__ xb,
                                              float* __restrict__ xb2,
                                              float* __restrict__ agg,
                                              const int* __restrict__ flag) {
  const int f = *flag;
  int node = blockIdx.x * 4 + (threadIdx.x >> 6);
  int h = threadIdx.x & 63;
  float acc = flb[h];
#pragma unroll
  for (int c = 0; c < 11; c++)
    acc += rawf(xin, f, node * 11 + c) * flW[h * 11 + c];
  float v = siluf(acc);
  x[node * 64 + h] = v;
  xb[node * 64 + h] = f2b(v);
  int xvi = __float_as_int(v);
  float a2 = 0.0f;
#pragma unroll 8
  for (int i = 0; i < 64; i++) {
    float xi = rdlane(xvi, i);
    a2 += xi * b2[i * 64 + h];
  }
  xb2[node * 64 + h] = a2;
  agg[(size_t)node * 64 + h] = 0.0f;
}

// ---------- s[e,k] = silu(ef @ nn_W1.T + nn_b1) bf16 -----------------------
__global__ __launch_bounds__(256) void k_sdeg(const void* __restrict__ ea,
                                              const void* __restrict__ pos,
                                              const int* __restrict__ ei,
                                              const float* __restrict__ W1,
                                              const float* __restrict__ b1,
                                              unsigned short* __restrict__ s_bf,
                                              const int* __restrict__ flag) {
  const int f = *flag;
  int e = blockIdx.x * 2 + (threadIdx.x >> 7);
  int k = threadIdx.x & 127;
  int src = ei[e], dst = ei[EE + e];
  float dx = rawf(pos, f, src * 3 + 0) - rawf(pos, f, dst * 3 + 0);
  float dy = rawf(pos, f, src * 3 + 1) - rawf(pos, f, dst * 3 + 1);
  float dz = rawf(pos, f, src * 3 + 2) - rawf(pos, f, dst * 3 + 2);
  float dist = sqrtf(dx * dx + dy * dy + dz * dz);
  float acc = b1[k];
  acc += rawf(ea, f, e * 4 + 0) * W1[k * 5 + 0];
  acc += rawf(ea, f, e * 4 + 1) * W1[k * 5 + 1];
  acc += rawf(ea, f, e * 4 + 2) * W1[k * 5 + 2];
  acc += rawf(ea, f, e * 4 + 3) * W1[k * 5 + 3];
  acc += dist * W1[k * 5 + 4];
  s_bf[e * 128 + k] = f2b(siluf(acc));
}

// ---- W2t[(o*128+k)*64 + i] = bf16(W2[(i*64+o)*128 + k]) -------------------
__global__ __launch_bounds__(256) void k_w2t(const float* __restrict__ W2,
                                             unsigned short* __restrict__ W2t) {
  int j = blockIdx.x * 256 + threadIdx.x;
  int i = j & 63;
  int k = (j >> 6) & 127;
  int o = j >> 13;
  W2t[j] = f2b(W2[(size_t)(i * 64 + o) * 128 + k]);
}

// ---- T GEMM with LDS-staged coalesced epilogue ----------------------------
template <int KC>
__global__ __launch_bounds__(256) void k_T(const unsigned short* __restrict__ xb,
                                           const unsigned short* __restrict__ W2t,
                                           unsigned short* __restrict__ Tc, int K0) {
  __shared__ unsigned short sh[2 * 128 * 72];
  unsigned short* As = sh;
  unsigned short* Bs = sh + 128 * 72;
  const int t = threadIdx.x;
  const int n0 = blockIdx.x * 128;
  const int c0 = blockIdx.y * 128;
  const int lane = t & 63;
  const int w = t >> 6;
  const int lm = lane & 15;
  const int quad = lane >> 4;
  const int wm = w & 1;
  const int wn = w >> 1;

  for (int p = t; p < 128 * 8; p += 256) {
    int r = p >> 3, cc = (p & 7) * 8;
    uint4 v = make_uint4(0u, 0u, 0u, 0u);
    if (n0 + r < NN) v = *reinterpret_cast<const uint4*>(xb + (size_t)(n0 + r) * 64 + cc);
    *reinterpret_cast<uint4*>(&As[r * 72 + cc]) = v;
  }
  for (int p = t; p < 128 * 8; p += 256) {
    int r = p >> 3, cc = (p & 7) * 8;
    int c = c0 + r;
    int o = c / KC;
    int kg = K0 + (c % KC);
    uint4 v = *reinterpret_cast<const uint4*>(W2t + (size_t)(o * 128 + kg) * 64 + cc);
    *reinterpret_cast<uint4*>(&Bs[r * 72 + cc]) = v;
  }
  __syncthreads();

  f32x4 acc[4][4];
#pragma unroll
  for (int mt = 0; mt < 4; mt++)
#pragma unroll
    for (int nt = 0; nt < 4; nt++) acc[mt][nt] = (f32x4)(0.0f);

#pragma unroll
  for (int ks = 0; ks < 2; ks++) {
    const int kk = ks * 32 + quad * 8;
    short8 af[4], bfr[4];
#pragma unroll
    for (int mt = 0; mt < 4; mt++)
      af[mt] = *reinterpret_cast<const short8*>(&As[(wm * 64 + mt * 16 + lm) * 72 + kk]);
#pragma unroll
    for (int nt = 0; nt < 4; nt++)
      bfr[nt] = *reinterpret_cast<const short8*>(&Bs[(wn * 64 + nt * 16 + lm) * 72 + kk]);
#pragma unroll
    for (int mt = 0; mt < 4; mt++)
#pragma unroll
      for (int nt = 0; nt < 4; nt++)
        acc[mt][nt] = __builtin_amdgcn_mfma_f32_16x16x32_bf16(af[mt], bfr[nt], acc[mt][nt], 0, 0, 0);
  }

  __syncthreads();
  unsigned short* st = sh;
#pragma unroll
  for (int nt = 0; nt < 4; nt++) {
    int col = wn * 64 + nt * 16 + lm;
#pragma unroll
    for (int mt = 0; mt < 4; mt++) {
#pragma unroll
      for (int reg = 0; reg < 4; reg++) {
        int row = wm * 64 + mt * 16 + quad * 4 + reg;
        st[row * 132 + col] = f2b(acc[mt][nt][reg]);
      }
    }
  }
  __syncthreads();
  const int r16 = t >> 4;
  const int c8 = (t & 15) * 8;
#pragma unroll
  for (int it = 0; it < 8; it++) {
    int row = it * 16 + r16;
    int n = n0 + row;
    if (n < NN) {
      uint2 v0 = *reinterpret_cast<const uint2*>(&st[row * 132 + c8]);
      uint2 v1 = *reinterpret_cast<const uint2*>(&st[row * 132 + c8 + 4]);
      uint4 v = make_uint4(v0.x, v0.y, v1.x, v1.y);
      *reinterpret_cast<uint4*>(Tc + (size_t)n * (64 * KC) + c0 + c8) = v;
    }
  }
}

// ---- grouped edge pass v3: sorted s + dst, packed tw, dual acc ------------
__global__ __launch_bounds__(256) void k_group(const unsigned short* __restrict__ Tc,
                                               const unsigned* __restrict__ s_srt,
                                               const int* __restrict__ dst_srt,
                                               const float* __restrict__ xb2,
                                               const int* __restrict__ eptr,
                                               float* __restrict__ agg) {
  const int n = blockIdx.x * 4 + (threadIdx.x >> 6);
  const int lane = threadIdx.x & 63;
  const int beg = eptr[n], end = eptr[n + 1];
  if (beg == end) return;
  const uint4* trow = reinterpret_cast<const uint4*>(Tc + (size_t)n * 8192 + (size_t)lane * 128);
  unsigned tw[64];
#pragma unroll
  for (int j = 0; j < 16; j++) {
    uint4 v = trow[j];
    tw[4 * j + 0] = v.x; tw[4 * j + 1] = v.y;
    tw[4 * j + 2] = v.z; tw[4 * j + 3] = v.w;
  }
  const float xbv = xb2[(size_t)n * 64 + lane];
  for (int j = beg; j < end; j++) {
    const int dst = dst_srt[j];
    const int sw = ((const int*)s_srt)[(size_t)j * 64 + lane];
    float a0 = 0.0f, a1 = 0.0f;
#pragma unroll
    for (int q = 0; q < 64; q += 2) {
      unsigned s0 = (unsigned)__builtin_amdgcn_readlane(sw, q);
      unsigned s1 = (unsigned)__builtin_amdgcn_readlane(sw, q + 1);
      a0 += b2f_lo(s0) * b2f_lo(tw[q]) + b2f_hi(s0) * b2f_hi(tw[q]);
      a1 += b2f_lo(s1) * b2f_lo(tw[q + 1]) + b2f_hi(s1) * b2f_hi(tw[q + 1]);
    }
    atomicAdd(agg + (size_t)dst * 64 + lane, a0 + a1 + xbv);
  }
}

// ---- fallback per-edge chunk dot (KC<128) ---------------------------------
template <int KC>
__global__ __launch_bounds__(256) void k_emsg(const unsigned short* __restrict__ Tc,
                                              const unsigned short* __restrict__ s_bf,
                                              const int* __restrict__ ei,
                                              float* __restrict__ m, int K0, int first) {
  int e = blockIdx.x * 4 + (threadIdx.x >> 6);
  int o = threadIdx.x & 63;
  int src = ei[e];
  const uint4* tv = reinterpret_cast<const uint4*>(Tc + ((size_t)src * 64 + o) * KC);
  const uint4* sv = reinterpret_cast<const uint4*>(s_bf + (size_t)e * 128 + K0);
  float acc = 0.0f;
#pragma unroll
  for (int j = 0; j < KC / 8; j++) {
    uint4 a = tv[j], b = sv[j];
    unsigned aa[4] = {a.x, a.y, a.z, a.w};
    unsigned bb[4] = {b.x, b.y, b.z, b.w};
#pragma unroll
    for (int q = 0; q < 4; q++)
      acc += b2f_lo(aa[q]) * b2f_lo(bb[q]) + b2f_hi(aa[q]) * b2f_hi(bb[q]);
  }
  float* mp = m + (size_t)e * 64 + o;
  if (first) *mp = acc;
  else *mp += acc;
}

__global__ __launch_bounds__(256) void k_aggm(const float* __restrict__ m,
                                              const float* __restrict__ xb2,
                                              const int* __restrict__ ei,
                                              float* __restrict__ agg) {
  int e = blockIdx.x * 4 + (threadIdx.x >> 6);
  int o = threadIdx.x & 63;
  int src = ei[e], dst = ei[EE + e];
  atomicAdd(agg + (size_t)dst * 64 + o, m[(size_t)e * 64 + o] + xb2[(size_t)src * 64 + o]);
}

// ---- xc + GRU + xb2/agg0: wave-per-node, no LDS, no barriers --------------
__global__ __launch_bounds__(256) void k_xcgru(float* __restrict__ x,
                                               unsigned short* __restrict__ xb,
                                               float* __restrict__ agg,
                                               const float* __restrict__ invd,
                                               const float* __restrict__ rWT,
                                               const float* __restrict__ rb,
                                               const float* __restrict__ WihT,
                                               const float* __restrict__ WhhT,
                                               const float* __restrict__ bih,
                                               const float* __restrict__ bhh,
                                               const float* __restrict__ b2,
                                               float* __restrict__ xb2,
                                               int last) {
  const int node = blockIdx.x * 4 + (threadIdx.x >> 6);
  const int lane = threadIdx.x & 63;
  const size_t base = (size_t)node * 64 + lane;
  const float xv = x[base];
  const float av = agg[base];
  agg[base] = 0.0f;
  const float idv = invd[node];
  const int xvi = __float_as_int(xv);

  float acc = 0.0f;
#pragma unroll 8
  for (int k = 0; k < 64; k++)
    acc += rdlane(xvi, k) * rWT[k * 64 + lane];
  const float xc = siluf(acc + rb[lane] + av * idv);
  const int xci = __float_as_int(xc);

  float gi0 = bih[lane], gi1 = bih[64 + lane], gi2 = bih[128 + lane];
  float gh0 = bhh[lane], gh1 = bhh[64 + lane], gh2 = bhh[128 + lane];
#pragma unroll 4
  for (int k = 0; k < 64; k++) {
    const float xck = rdlane(xci, k);
    const float xvk = rdlane(xvi, k);
    const float* wi = WihT + k * 192;
    const float* wh = WhhT + k * 192;
    gi0 += xck * wi[lane];
    gi1 += xck * wi[64 + lane];
    gi2 += xck * wi[128 + lane];
    gh0 += xvk * wh[lane];
    gh1 += xvk * wh[64 + lane];
    gh2 += xvk * wh[128 + lane];
  }
  const float r = sigm(gi0 + gh0);
  const float z = sigm(gi1 + gh1);
  const float ng = tanhf(gi2 + r * gh2);
  const float xn = (1.0f - z) * ng + z * xv;
  x[base] = xn;

  if (!last) {
    xb[base] = f2b(xn);
    const int xni = __float_as_int(xn);
    float a2 = 0.0f;
#pragma unroll 8
    for (int i = 0; i < 64; i++)
      a2 += rdlane(xni, i) * b2[i * 64 + lane];
    xb2[base] = a2;
  }
}

// ---- fused Set2Set v2: 256 thr/graph, transposed weights, wave-parallel ---
__global__ __launch_bounds__(256) void k_s2s(const float* __restrict__ x,
                                             const int* __restrict__ batch,
                                             const float* __restrict__ WihT,
                                             const float* __restrict__ WhhT,
                                             const float* __restrict__ bih,
                                             const float* __restrict__ bhh,
                                             const float* __restrict__ W1T,
                                             const float* __restrict__ b1,
                                             const float* __restrict__ W2,
                                             const float* __restrict__ b2o,
                                             void* __restrict__ out,
                                             const int* __restrict__ flag) {
  const int b = blockIdx.x;
  const int t = threadIdx.x;
  const int lane = t & 63;
  const int w = t >> 6;
  int lo = 0, hi = NN;
  while (lo < hi) { int mid = (lo + hi) >> 1; if (batch[mid] < b) lo = mid + 1; else hi = mid; }
  const int ns = lo;
  hi = NN;
  while (lo < hi) { int mid = (lo + hi) >> 1; if (batch[mid] <= b) lo = mid + 1; else hi = mid; }
  const int cnt = lo - ns;

  __shared__ float hs[64], rs[64], cs[64], gs[256];
  __shared__ float es[512];
  __shared__ float red[4][64];
  __shared__ float wred[4], wsum[4];
  if (t < 64) { hs[t] = 0.0f; rs[t] = 0.0f; cs[t] = 0.0f; }
  __syncthreads();

  for (int step = 0; step < 3; step++) {
    float acc = bih[t] + bhh[t];
#pragma unroll 4
    for (int k = 0; k < 64; k++)
      acc += hs[k] * (WihT[k * 256 + t] + WhhT[k * 256 + t]);
#pragma unroll 4
    for (int k = 0; k < 64; k++)
      acc += rs[k] * WihT[(64 + k) * 256 + t];
    gs[t] = acc;
    __syncthreads();
    if (t < 64) {
      float ig = sigm(gs[t]), fg = sigm(gs[64 + t]);
      float gg = tanhf(gs[128 + t]), og = sigm(gs[192 + t]);
      float c = fg * cs[t] + ig * gg;
      cs[t] = c;
      hs[t] = og * tanhf(c);
    }
    __syncthreads();

    float mxw = -3.4e38f;
    for (int j = w; j < cnt; j += 4) {
      float v = x[(size_t)(ns + j) * 64 + lane] * hs[lane];
#pragma unroll
      for (int mm = 32; mm; mm >>= 1) v += __shfl_xor(v, mm, 64);
      if (lane == 0 && j < 512) es[j] = v;
      mxw = fmaxf(mxw, v);
    }
    if (lane == 0) wred[w] = mxw;
    __syncthreads();
    float mx = fmaxf(fmaxf(wred[0], wred[1]), fmaxf(wred[2], wred[3]));

    float ps = 0.0f;
    for (int i = t; i < cnt && i < 512; i += 256) {
      float a = __expf(es[i] - mx);
      es[i] = a;
      ps += a;
    }
#pragma unroll
    for (int mm = 32; mm; mm >>= 1) ps += __shfl_xor(ps, mm, 64);
    if (lane == 0) wsum[w] = ps;
    __syncthreads();
    float tot = wsum[0] + wsum[1] + wsum[2] + wsum[3];
    float inv = (cnt > 0) ? 1.0f / tot : 0.0f;

    float pr = 0.0f;
    for (int j = w; j < cnt && j < 512; j += 4)
      pr += es[j] * x[(size_t)(ns + j) * 64 + lane];
    red[w][lane] = pr;
    __syncthreads();
    if (t < 64)
      rs[t] = (red[0][t] + red[1][t] + red[2][t] + red[3][t]) * inv;
    __syncthreads();
  }

  if (t < 64) {
    float acc = b1[lane];
#pragma unroll 4
    for (int k = 0; k < 64; k++) acc += hs[k] * W1T[k * 64 + lane];
#pragma unroll 4
    for (int k = 0; k < 64; k++) acc += rs[k] * W1T[(64 + k) * 64 + lane];
    float u = siluf(acc) * W2[lane];
#pragma unroll
    for (int mm = 32; mm; mm >>= 1) u += __shfl_xor(u, mm, 64);
    if (lane == 0) {
      float v = u + b2o[0];
      if (*flag) ((unsigned short*)out)[b] = f2b(v);
      else ((float*)out)[b] = v;
    }
  }
}

// ---------------------------------------------------------------------------
template <int KC>
static void run_chunks(const unsigned short* xb, const unsigned short* W2t,
                       unsigned short* Tc, const unsigned short* s_bf,
                       const int* ei, float* m, hipStream_t stream) {
  const int nch = 128 / KC;
  for (int c = 0; c < nch; c++) {
    k_T<KC><<<dim3((NN + 127) / 128, (64 * KC) / 128), 256, 0, stream>>>(xb, W2t, Tc, c * KC);
    k_emsg<KC><<<EE / 4, 256, 0, stream>>>(Tc, s_bf, ei, m, c * KC, c == 0 ? 1 : 0);
  }
}

extern "C" void kernel_launch(void* const* d_in, const int* in_sizes, int n_in,
                              void* d_out, int out_size, void* d_ws, size_t ws_size,
                              hipStream_t stream) {
  (void)n_in; (void)out_size;
  const bool sig_order = (in_sizes[1] == 2 * EE);
  const void* p_x   = d_in[0];
  const void* p_ea  = sig_order ? d_in[2] : d_in[1];
  const void* p_pos = sig_order ? d_in[3] : d_in[2];
  const int* edge_index = (const int*)(sig_order ? d_in[1] : d_in[3]);
  const int* batch      = (const int*)d_in[4];
  const void* p_w[20];
  for (int i = 0; i < 20; i++) p_w[i] = d_in[5 + i];

  char* base = (char*)d_ws;
  size_t off = 0;
  auto alloc = [&](size_t bytes) -> char* {
    char* p = base + off;
    off = (off + bytes + 255) & ~(size_t)255;
    return p;
  };
  int* flag = (int*)alloc(4);
  static const int cvt_n[NCVT] = {
      64 * 11, 64, 128 * 5, 128, 4096 * 128, 4096,
      64 * 64, 64,
      192 * 64, 192 * 64, 192, 192,
      256 * 128, 256 * 64, 256, 256,
      64 * 128, 64, 64, 1};
  float* canon[NCVT];
  for (int i = 0; i < NCVT; i++) canon[i] = (float*)alloc((size_t)cvt_n[i] * 4);
  const float* c_flW  = canon[0];
  const float* c_flb  = canon[1];
  const float* c_W1   = canon[2];
  const float* c_b1   = canon[3];
  const float* c_W2   = canon[4];
  const float* c_b2   = canon[5];
  const float* c_rW   = canon[6];
  const float* c_rb   = canon[7];
  const float* c_gWih = canon[8];
  const float* c_gWhh = canon[9];
  const float* c_gbih = canon[10];
  const float* c_gbhh = canon[11];
  const float* c_lWih = canon[12];
  const float* c_lWhh = canon[13];
  const float* c_lbih = canon[14];
  const float* c_lbhh = canon[15];
  const float* c_oW1  = canon[16];
  const float* c_ob1  = canon[17];
  const float* c_oW2  = canon[18];
  const float* c_ob2  = canon[19];

  unsigned short* s_bf = (unsigned short*)alloc((size_t)EE * 128 * 2);
  unsigned* s_srt = (unsigned*)alloc((size_t)EE * 64 * 4);       // 12.8MB sorted s
  int* dst_srt = (int*)alloc((size_t)EE * 4);
  float* m    = (float*)alloc((size_t)EE * 64 * 4);  // fallback only
  float* x    = (float*)alloc((size_t)NN * 64 * 4);
  unsigned short* xb = (unsigned short*)alloc((size_t)NN * 64 * 2);
  float* agg  = (float*)alloc((size_t)NN * 64 * 4);
  float* xb2  = (float*)alloc((size_t)NN * 64 * 4);
  unsigned short* W2t = (unsigned short*)alloc((size_t)4096 * 128 * 2);
  float* invd = (float*)alloc((size_t)NN * 4);
  int* cnt    = (int*)alloc((size_t)2 * NN * 4);
  int* cntd   = cnt + NN;
  int* eptr   = (int*)alloc((size_t)(NN + 1) * 4);
  int* cursor = (int*)alloc((size_t)NN * 4);
  int* eord   = (int*)alloc((size_t)EE * 4);
  float* WihT = (float*)alloc((size_t)128 * 256 * 4);
  float* WhhT = (float*)alloc((size_t)64 * 256 * 4);
  float* W1T  = (float*)alloc((size_t)128 * 64 * 4);
  float* rWT  = (float*)alloc((size_t)64 * 64 * 4);
  float* gWihT = (float*)alloc((size_t)64 * 192 * 4);
  float* gWhhT = (float*)alloc((size_t)64 * 192 * 4);
  size_t base_need = off;

  int KC = 0;
  const int kcs[5] = {128, 64, 32, 16, 8};
  for (int i = 0; i < 5; i++) {
    size_t need = base_need + (size_t)NN * 64 * kcs[i] * 2 + 256;
    if (need <= ws_size) { KC = kcs[i]; break; }
  }
  if (KC == 0) return;
  unsigned short* Tc = (unsigned short*)alloc((size_t)NN * 64 * KC * 2);

  // ---- dtype detect + weight convert + transposes ----
  k_detect<<<1, 256, 0, stream>>>((const unsigned*)p_ea, flag);
  Cvt cvt;
  for (int i = 0; i < 20; i++) cvt.src[i] = p_w[i];
  for (int i = 0; i < NCVT; i++) { cvt.dst[i] = canon[i]; cvt.n[i] = cvt_n[i]; }
  k_convert<<<512, 256, 0, stream>>>(cvt, flag);
  k_ltrans<<<336, 256, 0, stream>>>(c_lWih, c_lWhh, c_oW1, c_rW, c_gWih, c_gWhh,
                                    WihT, WhhT, W1T, rWT, gWihT, gWhhT);

  // ---- prologue ----
  hipMemsetAsync(cnt, 0, (size_t)2 * NN * 4, stream);
  k_lift<<<NN / 4, 256, 0, stream>>>(p_x, c_flW, c_flb, c_b2, x, xb, xb2, agg, flag);
  k_sdeg<<<EE / 2, 256, 0, stream>>>(p_ea, p_pos, edge_index, c_W1, c_b1, s_bf, flag);
  k_w2t<<<(4096 * 128) / 256, 256, 0, stream>>>(c_W2, W2t);
  k_hist<<<(EE + 255) / 256, 256, 0, stream>>>(edge_index, cnt, cntd);
  k_scan<<<1, 256, 0, stream>>>(cnt, cntd, eptr, cursor, invd);
  k_scatter<<<(EE + 255) / 256, 256, 0, stream>>>(edge_index, cursor, eord);
  k_sperm<<<EE / 4, 256, 0, stream>>>(s_bf, edge_index, eord, s_srt, dst_srt);

  // ---- 4 message-passing layers ----
  for (int layer = 0; layer < 4; layer++) {
    if (KC == 128) {
      k_T<128><<<dim3((NN + 127) / 128, 64), 256, 0, stream>>>(xb, W2t, Tc, 0);
      k_group<<<NN / 4, 256, 0, stream>>>(Tc, s_srt, dst_srt, xb2, eptr, agg);
    } else {
      switch (KC) {
        case 64: run_chunks<64>(xb, W2t, Tc, s_bf, edge_index, m, stream); break;
        case 32: run_chunks<32>(xb, W2t, Tc, s_bf, edge_index, m, stream); break;
        case 16: run_chunks<16>(xb, W2t, Tc, s_bf, edge_index, m, stream); break;
        default: run_chunks<8>(xb, W2t, Tc, s_bf, edge_index, m, stream); break;
      }
      k_aggm<<<EE / 4, 256, 0, stream>>>(m, xb2, edge_index, agg);
    }
    k_xcgru<<<NN / 4, 256, 0, stream>>>(x, xb, agg, invd, rWT, c_rb,
                                        gWihT, gWhhT, c_gbih, c_gbhh,
                                        c_b2, xb2, layer == 3 ? 1 : 0);
  }

  // ---- Set2Set + output head (one kernel, 4 waves/graph) ----
  k_s2s<<<BBG, 256, 0, stream>>>(x, batch, WihT, WhhT, c_lbih, c_lbhh,
                                 W1T, c_ob1, c_oW2, c_ob2, d_out, flag);
}

// Round 12
// 722.389 us; speedup vs baseline: 2.4194x; 1.1309x over previous
//
#include <hip/hip_runtime.h>
#include <stdint.h>

// ---------------------------------------------------------------------------
// SpatialGNN forward, round 12.
// R11: 817us. k_group 59us x4: VALU floor ~28us (700 inst/edge readlane dot)
// + 6 waves/SIMD cap (tw[64] -> VGPR 84). Not BW-bound (1.7TB/s).
// R12: k_group v4 = MFMA per node. Edges sorted by src share one T row:
// [<=16 edges,128] @ [128,64] per node = 16 mfma_16x16x32_bf16 per tile.
// A-frag from s_srt (lane=edge), B-frag from Tc (lane=o col, 16B loads),
// C-layout predicated atomic epilogue (+xb2). Kills the readlane loop and
// the 64-reg tw block -> ~50 VGPR, 8 waves/SIMD, purely Tc-read-bound.
// Rest identical to R11.
// ---------------------------------------------------------------------------

#define NN 10000
#define EE 50000
#define BBG 512

typedef __attribute__((ext_vector_type(8))) short short8;
typedef __attribute__((ext_vector_type(4))) float f32x4;
typedef __attribute__((ext_vector_type(2))) float f32x2;

__device__ __forceinline__ float b2f(unsigned short u) {
  return __uint_as_float(((unsigned)u) << 16);
}
__device__ __forceinline__ float b2f_lo(unsigned u) { return __uint_as_float(u << 16); }
__device__ __forceinline__ float b2f_hi(unsigned u) { return __uint_as_float(u & 0xFFFF0000u); }
__device__ __forceinline__ unsigned short f2b(float f) {
  unsigned u = __float_as_uint(f);
  u += 0x7FFFu + ((u >> 16) & 1u);  // RNE
  return (unsigned short)(u >> 16);
}
__device__ __forceinline__ float sigm(float x) { return 1.0f / (1.0f + __expf(-x)); }
__device__ __forceinline__ float siluf(float x) { return x / (1.0f + __expf(-x)); }
__device__ __forceinline__ float rawf(const void* p, int f, int i) {
  return f ? b2f(((const unsigned short*)p)[i]) : ((const float*)p)[i];
}
__device__ __forceinline__ float rdlane(int v, int k) {
  return __int_as_float(__builtin_amdgcn_readlane(v, k));
}

// ---------------- dtype detection on edge_attr (uniform[0,1)) --------------
__global__ __launch_bounds__(256) void k_detect(const unsigned* __restrict__ w,
                                                int* __restrict__ flag) {
  __shared__ int cnt;
  if (threadIdx.x == 0) cnt = 0;
  __syncthreads();
  int c = 0;
  for (int i = threadIdx.x; i < 4096; i += 256) {
    unsigned lo = w[i] & 0xFFFFu;
    if (lo - 0x3A00u < 0x600u) c++;
  }
  atomicAdd(&cnt, c);
  __syncthreads();
  if (threadIdx.x == 0) *flag = (cnt > 2048) ? 1 : 0;  // 1 = inputs are bf16
}

// ---------------- convert weight inputs to canonical fp32 ------------------
#define NCVT 20
struct Cvt {
  const void* src[NCVT];
  float* dst[NCVT];
  int n[NCVT];
};

__global__ __launch_bounds__(256) void k_convert(Cvt c, const int* __restrict__ flag) {
  const int f = *flag;
  const int stride = gridDim.x * blockDim.x;
  const int tid = blockIdx.x * blockDim.x + threadIdx.x;
#pragma unroll 1
  for (int a = 0; a < NCVT; a++) {
    const int n = c.n[a];
    const float* sf = (const float*)c.src[a];
    const unsigned short* sb = (const unsigned short*)c.src[a];
    float* d = c.dst[a];
    for (int i = tid; i < n; i += stride) d[i] = f ? b2f(sb[i]) : sf[i];
  }
}

// ---- weight transposes: LSTM/head (k_s2s) + GRU/root (k_xcgru) ------------
__global__ __launch_bounds__(256) void k_ltrans(const float* __restrict__ Wih,
                                                const float* __restrict__ Whh,
                                                const float* __restrict__ W1,
                                                const float* __restrict__ rW,
                                                const float* __restrict__ gWih,
                                                const float* __restrict__ gWhh,
                                                float* __restrict__ WihT,
                                                float* __restrict__ WhhT,
                                                float* __restrict__ W1T,
                                                float* __restrict__ rWT,
                                                float* __restrict__ gWihT,
                                                float* __restrict__ gWhhT) {
  int j = blockIdx.x * 256 + threadIdx.x;
  if (j < 32768) {
    int r = j & 255, k = j >> 8;
    WihT[k * 256 + r] = Wih[r * 128 + k];
  } else if (j < 49152) {
    int q = j - 32768;
    int r = q & 255, k = q >> 8;
    WhhT[k * 256 + r] = Whh[r * 64 + k];
  } else if (j < 57344) {
    int q = j - 49152;
    int o = q & 63, k = q >> 6;
    W1T[k * 64 + o] = W1[o * 128 + k];
  } else if (j < 61440) {
    int q = j - 57344;
    int o = q & 63, k = q >> 6;
    rWT[k * 64 + o] = rW[o * 64 + k];
  } else if (j < 73728) {
    int q = j - 61440;
    int r = q % 192, k = q / 192;
    gWihT[k * 192 + r] = gWih[r * 64 + k];
  } else if (j < 86016) {
    int q = j - 73728;
    int r = q % 192, k = q / 192;
    gWhhT[k * 192 + r] = gWhh[r * 64 + k];
  }
}

// ---------------- CSR by src + dst degree histogram ------------------------
__global__ __launch_bounds__(256) void k_hist(const int* __restrict__ ei,
                                              int* __restrict__ cnt,
                                              int* __restrict__ cntd) {
  int e = blockIdx.x * 256 + threadIdx.x;
  if (e < EE) {
    atomicAdd(cnt + ei[e], 1);
    atomicAdd(cntd + ei[EE + e], 1);
  }
}

__global__ __launch_bounds__(256) void k_scan(const int* __restrict__ cnt,
                                              const int* __restrict__ cntd,
                                              int* __restrict__ eptr,
                                              int* __restrict__ cursor,
                                              float* __restrict__ invd) {
  __shared__ int part[256];
  const int t = threadIdx.x;
  const int c0 = t * 40;
  int s = 0;
  for (int i = 0; i < 40; i++) {
    int idx = c0 + i;
    if (idx < NN) s += cnt[idx];
  }
  part[t] = s;
  __syncthreads();
  if (t == 0) {
    int run = 0;
    for (int i = 0; i < 256; i++) { int v = part[i]; part[i] = run; run += v; }
  }
  __syncthreads();
  int run = part[t];
  for (int i = 0; i < 40; i++) {
    int idx = c0 + i;
    if (idx < NN) {
      eptr[idx] = run;
      cursor[idx] = run;
      run += cnt[idx];
      invd[idx] = 1.0f / fmaxf((float)cntd[idx], 1.0f);
    }
  }
  if (t == 255) eptr[NN] = EE;
}

__global__ __launch_bounds__(256) void k_scatter(const int* __restrict__ ei,
                                                 int* __restrict__ cursor,
                                                 int* __restrict__ eord) {
  int e = blockIdx.x * 256 + threadIdx.x;
  if (e < EE) {
    int pos = atomicAdd(cursor + ei[e], 1);
    eord[pos] = e;
  }
}

// ---- permute s into eord order + gather dst (once; reused 4 layers) -------
__global__ __launch_bounds__(256) void k_sperm(const unsigned short* __restrict__ s_bf,
                                               const int* __restrict__ ei,
                                               const int* __restrict__ eord,
                                               unsigned* __restrict__ s_srt,
                                               int* __restrict__ dst_srt) {
  const int j = blockIdx.x * 4 + (threadIdx.x >> 6);
  const int lane = threadIdx.x & 63;
  const int e = eord[j];
  s_srt[(size_t)j * 64 + lane] = ((const unsigned*)s_bf)[(size_t)e * 64 + lane];
  if (lane == 0) dst_srt[j] = ei[EE + e];
}

// -------- lift: x = silu(x_in@flW.T+flb); also xb, xb2, agg=0 --------------
__global__ __launch_bounds__(256) void k_lift(const void* __restrict__ xin,
                                              const float* __restrict__ flW,
                                              const float* __restrict__ flb,
                                              const float* __restrict__ b2,
                                              float* __restrict__ x,
                                              unsigned short* __restrict__ xb,
                                              float* __restrict__ xb2,
                                              float* __restrict__ agg,
                                              const int* __restrict__ flag) {
  const int f = *flag;
  int node = blockIdx.x * 4 + (threadIdx.x >> 6);
  int h = threadIdx.x & 63;
  float acc = flb[h];
#pragma unroll
  for (int c = 0; c < 11; c++)
    acc += rawf(xin, f, node * 11 + c) * flW[h * 11 + c];
  float v = siluf(acc);
  x[node * 64 + h] = v;
  xb[node * 64 + h] = f2b(v);
  int xvi = __float_as_int(v);
  float a2 = 0.0f;
#pragma unroll 8
  for (int i = 0; i < 64; i++) {
    float xi = rdlane(xvi, i);
    a2 += xi * b2[i * 64 + h];
  }
  xb2[node * 64 + h] = a2;
  agg[(size_t)node * 64 + h] = 0.0f;
}

// ---------- s[e,k] = silu(ef @ nn_W1.T + nn_b1) bf16 -----------------------
__global__ __launch_bounds__(256) void k_sdeg(const void* __restrict__ ea,
                                              const void* __restrict__ pos,
                                              const int* __restrict__ ei,
                                              const float* __restrict__ W1,
                                              const float* __restrict__ b1,
                                              unsigned short* __restrict__ s_bf,
                                              const int* __restrict__ flag) {
  const int f = *flag;
  int e = blockIdx.x * 2 + (threadIdx.x >> 7);
  int k = threadIdx.x & 127;
  int src = ei[e], dst = ei[EE + e];
  float dx = rawf(pos, f, src * 3 + 0) - rawf(pos, f, dst * 3 + 0);
  float dy = rawf(pos, f, src * 3 + 1) - rawf(pos, f, dst * 3 + 1);
  float dz = rawf(pos, f, src * 3 + 2) - rawf(pos, f, dst * 3 + 2);
  float dist = sqrtf(dx * dx + dy * dy + dz * dz);
  float acc = b1[k];
  acc += rawf(ea, f, e * 4 + 0) * W1[k * 5 + 0];
  acc += rawf(ea, f, e * 4 + 1) * W1[k * 5 + 1];
  acc += rawf(ea, f, e * 4 + 2) * W1[k * 5 + 2];
  acc += rawf(ea, f, e * 4 + 3) * W1[k * 5 + 3];
  acc += dist * W1[k * 5 + 4];
  s_bf[e * 128 + k] = f2b(siluf(acc));
}

// ---- W2t[(o*128+k)*64 + i] = bf16(W2[(i*64+o)*128 + k]) -------------------
__global__ __launch_bounds__(256) void k_w2t(const float* __restrict__ W2,
                                             unsigned short* __restrict__ W2t) {
  int j = blockIdx.x * 256 + threadIdx.x;
  int i = j & 63;
  int k = (j >> 6) & 127;
  int o = j >> 13;
  W2t[j] = f2b(W2[(size_t)(i * 64 + o) * 128 + k]);
}

// ---- T GEMM with LDS-staged coalesced epilogue ----------------------------
template <int KC>
__global__ __launch_bounds__(256) void k_T(const unsigned short* __restrict__ xb,
                                           const unsigned short* __restrict__ W2t,
                                           unsigned short* __restrict__ Tc, int K0) {
  __shared__ unsigned short sh[2 * 128 * 72];
  unsigned short* As = sh;
  unsigned short* Bs = sh + 128 * 72;
  const int t = threadIdx.x;
  const int n0 = blockIdx.x * 128;
  const int c0 = blockIdx.y * 128;
  const int lane = t & 63;
  const int w = t >> 6;
  const int lm = lane & 15;
  const int quad = lane >> 4;
  const int wm = w & 1;
  const int wn = w >> 1;

  for (int p = t; p < 128 * 8; p += 256) {
    int r = p >> 3, cc = (p & 7) * 8;
    uint4 v = make_uint4(0u, 0u, 0u, 0u);
    if (n0 + r < NN) v = *reinterpret_cast<const uint4*>(xb + (size_t)(n0 + r) * 64 + cc);
    *reinterpret_cast<uint4*>(&As[r * 72 + cc]) = v;
  }
  for (int p = t; p < 128 * 8; p += 256) {
    int r = p >> 3, cc = (p & 7) * 8;
    int c = c0 + r;
    int o = c / KC;
    int kg = K0 + (c % KC);
    uint4 v = *reinterpret_cast<const uint4*>(W2t + (size_t)(o * 128 + kg) * 64 + cc);
    *reinterpret_cast<uint4*>(&Bs[r * 72 + cc]) = v;
  }
  __syncthreads();

  f32x4 acc[4][4];
#pragma unroll
  for (int mt = 0; mt < 4; mt++)
#pragma unroll
    for (int nt = 0; nt < 4; nt++) acc[mt][nt] = (f32x4)(0.0f);

#pragma unroll
  for (int ks = 0; ks < 2; ks++) {
    const int kk = ks * 32 + quad * 8;
    short8 af[4], bfr[4];
#pragma unroll
    for (int mt = 0; mt < 4; mt++)
      af[mt] = *reinterpret_cast<const short8*>(&As[(wm * 64 + mt * 16 + lm) * 72 + kk]);
#pragma unroll
    for (int nt = 0; nt < 4; nt++)
      bfr[nt] = *reinterpret_cast<const short8*>(&Bs[(wn * 64 + nt * 16 + lm) * 72 + kk]);
#pragma unroll
    for (int mt = 0; mt < 4; mt++)
#pragma unroll
      for (int nt = 0; nt < 4; nt++)
        acc[mt][nt] = __builtin_amdgcn_mfma_f32_16x16x32_bf16(af[mt], bfr[nt], acc[mt][nt], 0, 0, 0);
  }

  __syncthreads();
  unsigned short* st = sh;
#pragma unroll
  for (int nt = 0; nt < 4; nt++) {
    int col = wn * 64 + nt * 16 + lm;
#pragma unroll
    for (int mt = 0; mt < 4; mt++) {
#pragma unroll
      for (int reg = 0; reg < 4; reg++) {
        int row = wm * 64 + mt * 16 + quad * 4 + reg;
        st[row * 132 + col] = f2b(acc[mt][nt][reg]);
      }
    }
  }
  __syncthreads();
  const int r16 = t >> 4;
  const int c8 = (t & 15) * 8;
#pragma unroll
  for (int it = 0; it < 8; it++) {
    int row = it * 16 + r16;
    int n = n0 + row;
    if (n < NN) {
      uint2 v0 = *reinterpret_cast<const uint2*>(&st[row * 132 + c8]);
      uint2 v1 = *reinterpret_cast<const uint2*>(&st[row * 132 + c8 + 4]);
      uint4 v = make_uint4(v0.x, v0.y, v1.x, v1.y);
      *reinterpret_cast<uint4*>(Tc + (size_t)n * (64 * KC) + c0 + c8) = v;
    }
  }
}

// ---- grouped edge pass v4: MFMA per node ----------------------------------
// Wave = node. Per 16-edge tile: A = s_srt rows (m=edge), B = Tc cols
// (n=o, contiguous 128 bf16), D[m][o] via 4 ks x 4 ot mfma_16x16x32_bf16.
// Epilogue: predicated atomicAdd(agg[dst[edge]], D + xb2[n]).
__global__ __launch_bounds__(256) void k_group(const unsigned short* __restrict__ Tc,
                                               const unsigned* __restrict__ s_srt,
                                               const int* __restrict__ dst_srt,
                                               const float* __restrict__ xb2,
                                               const int* __restrict__ eptr,
                                               float* __restrict__ agg) {
  const int n = blockIdx.x * 4 + (threadIdx.x >> 6);
  const int lane = threadIdx.x & 63;
  const int beg = eptr[n], end = eptr[n + 1];
  if (beg == end) return;
  const int lm = lane & 15;   // A row (edge) / B col (o) / C col (o)
  const int quad = lane >> 4; // k-slice / C row group

  // B fragments: T row of node n, 4 o-tiles x 4 k-steps (loaded once)
  short8 bf[4][4];
#pragma unroll
  for (int ks = 0; ks < 4; ks++)
#pragma unroll
    for (int ot = 0; ot < 4; ot++)
      bf[ks][ot] = *reinterpret_cast<const short8*>(
          Tc + (size_t)n * 8192 + (ot * 16 + lm) * 128 + ks * 32 + quad * 8);

  // xb2 term per o column
  float xv[4];
#pragma unroll
  for (int ot = 0; ot < 4; ot++) xv[ot] = xb2[(size_t)n * 64 + ot * 16 + lm];

  for (int tile = beg; tile < end; tile += 16) {
    int eidx = tile + lm;
    if (eidx >= EE) eidx = EE - 1;  // clamp padding rows (rows independent)
    f32x4 acc[4];
#pragma unroll
    for (int ot = 0; ot < 4; ot++) acc[ot] = (f32x4)(0.0f);
#pragma unroll
    for (int ks = 0; ks < 4; ks++) {
      short8 af = *reinterpret_cast<const short8*>(
          (const unsigned short*)s_srt + (size_t)eidx * 128 + ks * 32 + quad * 8);
#pragma unroll
      for (int ot = 0; ot < 4; ot++)
        acc[ot] = __builtin_amdgcn_mfma_f32_16x16x32_bf16(af, bf[ks][ot], acc[ot], 0, 0, 0);
    }
    // epilogue: row = quad*4+reg (edge), col = ot*16+lm (o)
#pragma unroll
    for (int reg = 0; reg < 4; reg++) {
      int edge = tile + quad * 4 + reg;
      if (edge < end) {
        int dst = dst_srt[edge];
#pragma unroll
        for (int ot = 0; ot < 4; ot++)
          atomicAdd(agg + (size_t)dst * 64 + ot * 16 + lm, acc[ot][reg] + xv[ot]);
      }
    }
  }
}

// ---- fallback per-edge chunk dot (KC<128) ---------------------------------
template <int KC>
__global__ __launch_bounds__(256) void k_emsg(const unsigned short* __restrict__ Tc,
                                              const unsigned short* __restrict__ s_bf,
                                              const int* __restrict__ ei,
                                              float* __restrict__ m, int K0, int first) {
  int e = blockIdx.x * 4 + (threadIdx.x >> 6);
  int o = threadIdx.x & 63;
  int src = ei[e];
  const uint4* tv = reinterpret_cast<const uint4*>(Tc + ((size_t)src * 64 + o) * KC);
  const uint4* sv = reinterpret_cast<const uint4*>(s_bf + (size_t)e * 128 + K0);
  float acc = 0.0f;
#pragma unroll
  for (int j = 0; j < KC / 8; j++) {
    uint4 a = tv[j], b = sv[j];
    unsigned aa[4] = {a.x, a.y, a.z, a.w};
    unsigned bb[4] = {b.x, b.y, b.z, b.w};
#pragma unroll
    for (int q = 0; q < 4; q++)
      acc += b2f_lo(aa[q]) * b2f_lo(bb[q]) + b2f_hi(aa[q]) * b2f_hi(bb[q]);
  }
  float* mp = m + (size_t)e * 64 + o;
  if (first) *mp = acc;
  else *mp += acc;
}

__global__ __launch_bounds__(256) void k_aggm(const float* __restrict__ m,
                                              const float* __restrict__ xb2,
                                              const int* __restrict__ ei,
                                              float* __restrict__ agg) {
  int e = blockIdx.x * 4 + (threadIdx.x >> 6);
  int o = threadIdx.x & 63;
  int src = ei[e], dst = ei[EE + e];
  atomicAdd(agg + (size_t)dst * 64 + o, m[(size_t)e * 64 + o] + xb2[(size_t)src * 64 + o]);
}

// ---- xc + GRU + xb2/agg0: wave-per-node, no LDS, no barriers --------------
__global__ __launch_bounds__(256) void k_xcgru(float* __restrict__ x,
                                               unsigned short* __restrict__ xb,
                                               float* __restrict__ agg,
                                               const float* __restrict__ invd,
                                               const float* __restrict__ rWT,
                                               const float* __restrict__ rb,
                                               const float* __restrict__ WihT,
                                               const float* __restrict__ WhhT,
                                               const float* __restrict__ bih,
                                               const float* __restrict__ bhh,
                                               const float* __restrict__ b2,
                                               float* __restrict__ xb2,
                                               int last) {
  const int node = blockIdx.x * 4 + (threadIdx.x >> 6);
  const int lane = threadIdx.x & 63;
  const size_t base = (size_t)node * 64 + lane;
  const float xv = x[base];
  const float av = agg[base];
  agg[base] = 0.0f;
  const float idv = invd[node];
  const int xvi = __float_as_int(xv);

  float acc = 0.0f;
#pragma unroll 8
  for (int k = 0; k < 64; k++)
    acc += rdlane(xvi, k) * rWT[k * 64 + lane];
  const float xc = siluf(acc + rb[lane] + av * idv);
  const int xci = __float_as_int(xc);

  float gi0 = bih[lane], gi1 = bih[64 + lane], gi2 = bih[128 + lane];
  float gh0 = bhh[lane], gh1 = bhh[64 + lane], gh2 = bhh[128 + lane];
#pragma unroll 4
  for (int k = 0; k < 64; k++) {
    const float xck = rdlane(xci, k);
    const float xvk = rdlane(xvi, k);
    const float* wi = WihT + k * 192;
    const float* wh = WhhT + k * 192;
    gi0 += xck * wi[lane];
    gi1 += xck * wi[64 + lane];
    gi2 += xck * wi[128 + lane];
    gh0 += xvk * wh[lane];
    gh1 += xvk * wh[64 + lane];
    gh2 += xvk * wh[128 + lane];
  }
  const float r = sigm(gi0 + gh0);
  const float z = sigm(gi1 + gh1);
  const float ng = tanhf(gi2 + r * gh2);
  const float xn = (1.0f - z) * ng + z * xv;
  x[base] = xn;

  if (!last) {
    xb[base] = f2b(xn);
    const int xni = __float_as_int(xn);
    float a2 = 0.0f;
#pragma unroll 8
    for (int i = 0; i < 64; i++)
      a2 += rdlane(xni, i) * b2[i * 64 + lane];
    xb2[base] = a2;
  }
}

// ---- fused Set2Set v2: 256 thr/graph, transposed weights, wave-parallel ---
__global__ __launch_bounds__(256) void k_s2s(const float* __restrict__ x,
                                             const int* __restrict__ batch,
                                             const float* __restrict__ WihT,
                                             const float* __restrict__ WhhT,
                                             const float* __restrict__ bih,
                                             const float* __restrict__ bhh,
                                             const float* __restrict__ W1T,
                                             const float* __restrict__ b1,
                                             const float* __restrict__ W2,
                                             const float* __restrict__ b2o,
                                             void* __restrict__ out,
                                             const int* __restrict__ flag) {
  const int b = blockIdx.x;
  const int t = threadIdx.x;
  const int lane = t & 63;
  const int w = t >> 6;
  int lo = 0, hi = NN;
  while (lo < hi) { int mid = (lo + hi) >> 1; if (batch[mid] < b) lo = mid + 1; else hi = mid; }
  const int ns = lo;
  hi = NN;
  while (lo < hi) { int mid = (lo + hi) >> 1; if (batch[mid] <= b) lo = mid + 1; else hi = mid; }
  const int cnt = lo - ns;

  __shared__ float hs[64], rs[64], cs[64], gs[256];
  __shared__ float es[512];
  __shared__ float red[4][64];
  __shared__ float wred[4], wsum[4];
  if (t < 64) { hs[t] = 0.0f; rs[t] = 0.0f; cs[t] = 0.0f; }
  __syncthreads();

  for (int step = 0; step < 3; step++) {
    float acc = bih[t] + bhh[t];
#pragma unroll 4
    for (int k = 0; k < 64; k++)
      acc += hs[k] * (WihT[k * 256 + t] + WhhT[k * 256 + t]);
#pragma unroll 4
    for (int k = 0; k < 64; k++)
      acc += rs[k] * WihT[(64 + k) * 256 + t];
    gs[t] = acc;
    __syncthreads();
    if (t < 64) {
      float ig = sigm(gs[t]), fg = sigm(gs[64 + t]);
      float gg = tanhf(gs[128 + t]), og = sigm(gs[192 + t]);
      float c = fg * cs[t] + ig * gg;
      cs[t] = c;
      hs[t] = og * tanhf(c);
    }
    __syncthreads();

    float mxw = -3.4e38f;
    for (int j = w; j < cnt; j += 4) {
      float v = x[(size_t)(ns + j) * 64 + lane] * hs[lane];
#pragma unroll
      for (int mm = 32; mm; mm >>= 1) v += __shfl_xor(v, mm, 64);
      if (lane == 0 && j < 512) es[j] = v;
      mxw = fmaxf(mxw, v);
    }
    if (lane == 0) wred[w] = mxw;
    __syncthreads();
    float mx = fmaxf(fmaxf(wred[0], wred[1]), fmaxf(wred[2], wred[3]));

    float ps = 0.0f;
    for (int i = t; i < cnt && i < 512; i += 256) {
      float a = __expf(es[i] - mx);
      es[i] = a;
      ps += a;
    }
#pragma unroll
    for (int mm = 32; mm; mm >>= 1) ps += __shfl_xor(ps, mm, 64);
    if (lane == 0) wsum[w] = ps;
    __syncthreads();
    float tot = wsum[0] + wsum[1] + wsum[2] + wsum[3];
    float inv = (cnt > 0) ? 1.0f / tot : 0.0f;

    float pr = 0.0f;
    for (int j = w; j < cnt && j < 512; j += 4)
      pr += es[j] * x[(size_t)(ns + j) * 64 + lane];
    red[w][lane] = pr;
    __syncthreads();
    if (t < 64)
      rs[t] = (red[0][t] + red[1][t] + red[2][t] + red[3][t]) * inv;
    __syncthreads();
  }

  if (t < 64) {
    float acc = b1[lane];
#pragma unroll 4
    for (int k = 0; k < 64; k++) acc += hs[k] * W1T[k * 64 + lane];
#pragma unroll 4
    for (int k = 0; k < 64; k++) acc += rs[k] * W1T[(64 + k) * 64 + lane];
    float u = siluf(acc) * W2[lane];
#pragma unroll
    for (int mm = 32; mm; mm >>= 1) u += __shfl_xor(u, mm, 64);
    if (lane == 0) {
      float v = u + b2o[0];
      if (*flag) ((unsigned short*)out)[b] = f2b(v);
      else ((float*)out)[b] = v;
    }
  }
}

// ---------------------------------------------------------------------------
template <int KC>
static void run_chunks(const unsigned short* xb, const unsigned short* W2t,
                       unsigned short* Tc, const unsigned short* s_bf,
                       const int* ei, float* m, hipStream_t stream) {
  const int nch = 128 / KC;
  for (int c = 0; c < nch; c++) {
    k_T<KC><<<dim3((NN + 127) / 128, (64 * KC) / 128), 256, 0, stream>>>(xb, W2t, Tc, c * KC);
    k_emsg<KC><<<EE / 4, 256, 0, stream>>>(Tc, s_bf, ei, m, c * KC, c == 0 ? 1 : 0);
  }
}

extern "C" void kernel_launch(void* const* d_in, const int* in_sizes, int n_in,
                              void* d_out, int out_size, void* d_ws, size_t ws_size,
                              hipStream_t stream) {
  (void)n_in; (void)out_size;
  const bool sig_order = (in_sizes[1] == 2 * EE);
  const void* p_x   = d_in[0];
  const void* p_ea  = sig_order ? d_in[2] : d_in[1];
  const void* p_pos = sig_order ? d_in[3] : d_in[2];
  const int* edge_index = (const int*)(sig_order ? d_in[1] : d_in[3]);
  const int* batch      = (const int*)d_in[4];
  const void* p_w[20];
  for (int i = 0; i < 20; i++) p_w[i] = d_in[5 + i];

  char* base = (char*)d_ws;
  size_t off = 0;
  auto alloc = [&](size_t bytes) -> char* {
    char* p = base + off;
    off = (off + bytes + 255) & ~(size_t)255;
    return p;
  };
  int* flag = (int*)alloc(4);
  static const int cvt_n[NCVT] = {
      64 * 11, 64, 128 * 5, 128, 4096 * 128, 4096,
      64 * 64, 64,
      192 * 64, 192 * 64, 192, 192,
      256 * 128, 256 * 64, 256, 256,
      64 * 128, 64, 64, 1};
  float* canon[NCVT];
  for (int i = 0; i < NCVT; i++) canon[i] = (float*)alloc((size_t)cvt_n[i] * 4);
  const float* c_flW  = canon[0];
  const float* c_flb  = canon[1];
  const float* c_W1   = canon[2];
  const float* c_b1   = canon[3];
  const float* c_W2   = canon[4];
  const float* c_b2   = canon[5];
  const float* c_rW   = canon[6];
  const float* c_rb   = canon[7];
  const float* c_gWih = canon[8];
  const float* c_gWhh = canon[9];
  const float* c_gbih = canon[10];
  const float* c_gbhh = canon[11];
  const float* c_lWih = canon[12];
  const float* c_lWhh = canon[13];
  const float* c_lbih = canon[14];
  const float* c_lbhh = canon[15];
  const float* c_oW1  = canon[16];
  const float* c_ob1  = canon[17];
  const float* c_oW2  = canon[18];
  const float* c_ob2  = canon[19];

  unsigned short* s_bf = (unsigned short*)alloc((size_t)EE * 128 * 2);
  unsigned* s_srt = (unsigned*)alloc((size_t)EE * 64 * 4 + 4096);  // +pad for clamped tile reads
  int* dst_srt = (int*)alloc((size_t)EE * 4);
  float* m    = (float*)alloc((size_t)EE * 64 * 4);  // fallback only
  float* x    = (float*)alloc((size_t)NN * 64 * 4);
  unsigned short* xb = (unsigned short*)alloc((size_t)NN * 64 * 2);
  float* agg  = (float*)alloc((size_t)NN * 64 * 4);
  float* xb2  = (float*)alloc((size_t)NN * 64 * 4);
  unsigned short* W2t = (unsigned short*)alloc((size_t)4096 * 128 * 2);
  float* invd = (float*)alloc((size_t)NN * 4);
  int* cnt    = (int*)alloc((size_t)2 * NN * 4);
  int* cntd   = cnt + NN;
  int* eptr   = (int*)alloc((size_t)(NN + 1) * 4);
  int* cursor = (int*)alloc((size_t)NN * 4);
  int* eord   = (int*)alloc((size_t)EE * 4);
  float* WihT = (float*)alloc((size_t)128 * 256 * 4);
  float* WhhT = (float*)alloc((size_t)64 * 256 * 4);
  float* W1T  = (float*)alloc((size_t)128 * 64 * 4);
  float* rWT  = (float*)alloc((size_t)64 * 64 * 4);
  float* gWihT = (float*)alloc((size_t)64 * 192 * 4);
  float* gWhhT = (float*)alloc((size_t)64 * 192 * 4);
  size_t base_need = off;

  int KC = 0;
  const int kcs[5] = {128, 64, 32, 16, 8};
  for (int i = 0; i < 5; i++) {
    size_t need = base_need + (size_t)NN * 64 * kcs[i] * 2 + 256;
    if (need <= ws_size) { KC = kcs[i]; break; }
  }
  if (KC == 0) return;
  unsigned short* Tc = (unsigned short*)alloc((size_t)NN * 64 * KC * 2);

  // ---- dtype detect + weight convert + transposes ----
  k_detect<<<1, 256, 0, stream>>>((const unsigned*)p_ea, flag);
  Cvt cvt;
  for (int i = 0; i < 20; i++) cvt.src[i] = p_w[i];
  for (int i = 0; i < NCVT; i++) { cvt.dst[i] = canon[i]; cvt.n[i] = cvt_n[i]; }
  k_convert<<<512, 256, 0, stream>>>(cvt, flag);
  k_ltrans<<<336, 256, 0, stream>>>(c_lWih, c_lWhh, c_oW1, c_rW, c_gWih, c_gWhh,
                                    WihT, WhhT, W1T, rWT, gWihT, gWhhT);

  // ---- prologue ----
  hipMemsetAsync(cnt, 0, (size_t)2 * NN * 4, stream);
  k_lift<<<NN / 4, 256, 0, stream>>>(p_x, c_flW, c_flb, c_b2, x, xb, xb2, agg, flag);
  k_sdeg<<<EE / 2, 256, 0, stream>>>(p_ea, p_pos, edge_index, c_W1, c_b1, s_bf, flag);
  k_w2t<<<(4096 * 128) / 256, 256, 0, stream>>>(c_W2, W2t);
  k_hist<<<(EE + 255) / 256, 256, 0, stream>>>(edge_index, cnt, cntd);
  k_scan<<<1, 256, 0, stream>>>(cnt, cntd, eptr, cursor, invd);
  k_scatter<<<(EE + 255) / 256, 256, 0, stream>>>(edge_index, cursor, eord);
  k_sperm<<<EE / 4, 256, 0, stream>>>(s_bf, edge_index, eord, s_srt, dst_srt);

  // ---- 4 message-passing layers ----
  for (int layer = 0; layer < 4; layer++) {
    if (KC == 128) {
      k_T<128><<<dim3((NN + 127) / 128, 64), 256, 0, stream>>>(xb, W2t, Tc, 0);
      k_group<<<NN / 4, 256, 0, stream>>>(Tc, s_srt, dst_srt, xb2, eptr, agg);
    } else {
      switch (KC) {
        case 64: run_chunks<64>(xb, W2t, Tc, s_bf, edge_index, m, stream); break;
        case 32: run_chunks<32>(xb, W2t, Tc, s_bf, edge_index, m, stream); break;
        case 16: run_chunks<16>(xb, W2t, Tc, s_bf, edge_index, m, stream); break;
        default: run_chunks<8>(xb, W2t, Tc, s_bf, edge_index, m, stream); break;
      }
      k_aggm<<<EE / 4, 256, 0, stream>>>(m, xb2, edge_index, agg);
    }
    k_xcgru<<<NN / 4, 256, 0, stream>>>(x, xb, agg, invd, rWT, c_rb,
                                        gWihT, gWhhT, c_gbih, c_gbhh,
                                        c_b2, xb2, layer == 3 ? 1 : 0);
  }

  // ---- Set2Set + output head (one kernel, 4 waves/graph) ----
  k_s2s<<<BBG, 256, 0, stream>>>(x, batch, WihT, WhhT, c_lbih, c_lbhh,
                                 W1T, c_ob1, c_oW2, c_ob2, d_out, flag);
}

// Round 13
// 655.251 us; speedup vs baseline: 2.6673x; 1.1025x over previous
//
#include <hip/hip_runtime.h>
#include <stdint.h>

// ---------------------------------------------------------------------------
// SpatialGNN forward, round 13.
// R12: 722us. k_xcgru 49.5us x4 leader: each wave (1 node) re-reads 128KB of
// weight tables -> 1.28GB L2 traffic/layer ~= 40us at 35TB/s. L2-BW-bound.
// R13: k_xcgru v4 = 4 nodes/wave: load each weight once, apply to 4 nodes
// via readlane (24 FMA / 6 loads). Weight traffic /4 -> ~9us; VALU ~5us.
// Rest identical to R12.
// ---------------------------------------------------------------------------

#define NN 10000
#define EE 50000
#define BBG 512

typedef __attribute__((ext_vector_type(8))) short short8;
typedef __attribute__((ext_vector_type(4))) float f32x4;
typedef __attribute__((ext_vector_type(2))) float f32x2;

__device__ __forceinline__ float b2f(unsigned short u) {
  return __uint_as_float(((unsigned)u) << 16);
}
__device__ __forceinline__ float b2f_lo(unsigned u) { return __uint_as_float(u << 16); }
__device__ __forceinline__ float b2f_hi(unsigned u) { return __uint_as_float(u & 0xFFFF0000u); }
__device__ __forceinline__ unsigned short f2b(float f) {
  unsigned u = __float_as_uint(f);
  u += 0x7FFFu + ((u >> 16) & 1u);  // RNE
  return (unsigned short)(u >> 16);
}
__device__ __forceinline__ float sigm(float x) { return 1.0f / (1.0f + __expf(-x)); }
__device__ __forceinline__ float siluf(float x) { return x / (1.0f + __expf(-x)); }
__device__ __forceinline__ float rawf(const void* p, int f, int i) {
  return f ? b2f(((const unsigned short*)p)[i]) : ((const float*)p)[i];
}
__device__ __forceinline__ float rdlane(int v, int k) {
  return __int_as_float(__builtin_amdgcn_readlane(v, k));
}

// ---------------- dtype detection on edge_attr (uniform[0,1)) --------------
__global__ __launch_bounds__(256) void k_detect(const unsigned* __restrict__ w,
                                                int* __restrict__ flag) {
  __shared__ int cnt;
  if (threadIdx.x == 0) cnt = 0;
  __syncthreads();
  int c = 0;
  for (int i = threadIdx.x; i < 4096; i += 256) {
    unsigned lo = w[i] & 0xFFFFu;
    if (lo - 0x3A00u < 0x600u) c++;
  }
  atomicAdd(&cnt, c);
  __syncthreads();
  if (threadIdx.x == 0) *flag = (cnt > 2048) ? 1 : 0;  // 1 = inputs are bf16
}

// ---------------- convert weight inputs to canonical fp32 ------------------
#define NCVT 20
struct Cvt {
  const void* src[NCVT];
  float* dst[NCVT];
  int n[NCVT];
};

__global__ __launch_bounds__(256) void k_convert(Cvt c, const int* __restrict__ flag) {
  const int f = *flag;
  const int stride = gridDim.x * blockDim.x;
  const int tid = blockIdx.x * blockDim.x + threadIdx.x;
#pragma unroll 1
  for (int a = 0; a < NCVT; a++) {
    const int n = c.n[a];
    const float* sf = (const float*)c.src[a];
    const unsigned short* sb = (const unsigned short*)c.src[a];
    float* d = c.dst[a];
    for (int i = tid; i < n; i += stride) d[i] = f ? b2f(sb[i]) : sf[i];
  }
}

// ---- weight transposes: LSTM/head (k_s2s) + GRU/root (k_xcgru) ------------
__global__ __launch_bounds__(256) void k_ltrans(const float* __restrict__ Wih,
                                                const float* __restrict__ Whh,
                                                const float* __restrict__ W1,
                                                const float* __restrict__ rW,
                                                const float* __restrict__ gWih,
                                                const float* __restrict__ gWhh,
                                                float* __restrict__ WihT,
                                                float* __restrict__ WhhT,
                                                float* __restrict__ W1T,
                                                float* __restrict__ rWT,
                                                float* __restrict__ gWihT,
                                                float* __restrict__ gWhhT) {
  int j = blockIdx.x * 256 + threadIdx.x;
  if (j < 32768) {
    int r = j & 255, k = j >> 8;
    WihT[k * 256 + r] = Wih[r * 128 + k];
  } else if (j < 49152) {
    int q = j - 32768;
    int r = q & 255, k = q >> 8;
    WhhT[k * 256 + r] = Whh[r * 64 + k];
  } else if (j < 57344) {
    int q = j - 49152;
    int o = q & 63, k = q >> 6;
    W1T[k * 64 + o] = W1[o * 128 + k];
  } else if (j < 61440) {
    int q = j - 57344;
    int o = q & 63, k = q >> 6;
    rWT[k * 64 + o] = rW[o * 64 + k];
  } else if (j < 73728) {
    int q = j - 61440;
    int r = q % 192, k = q / 192;
    gWihT[k * 192 + r] = gWih[r * 64 + k];
  } else if (j < 86016) {
    int q = j - 73728;
    int r = q % 192, k = q / 192;
    gWhhT[k * 192 + r] = gWhh[r * 64 + k];
  }
}

// ---------------- CSR by src + dst degree histogram ------------------------
__global__ __launch_bounds__(256) void k_hist(const int* __restrict__ ei,
                                              int* __restrict__ cnt,
                                              int* __restrict__ cntd) {
  int e = blockIdx.x * 256 + threadIdx.x;
  if (e < EE) {
    atomicAdd(cnt + ei[e], 1);
    atomicAdd(cntd + ei[EE + e], 1);
  }
}

__global__ __launch_bounds__(256) void k_scan(const int* __restrict__ cnt,
                                              const int* __restrict__ cntd,
                                              int* __restrict__ eptr,
                                              int* __restrict__ cursor,
                                              float* __restrict__ invd) {
  __shared__ int part[256];
  const int t = threadIdx.x;
  const int c0 = t * 40;
  int s = 0;
  for (int i = 0; i < 40; i++) {
    int idx = c0 + i;
    if (idx < NN) s += cnt[idx];
  }
  part[t] = s;
  __syncthreads();
  if (t == 0) {
    int run = 0;
    for (int i = 0; i < 256; i++) { int v = part[i]; part[i] = run; run += v; }
  }
  __syncthreads();
  int run = part[t];
  for (int i = 0; i < 40; i++) {
    int idx = c0 + i;
    if (idx < NN) {
      eptr[idx] = run;
      cursor[idx] = run;
      run += cnt[idx];
      invd[idx] = 1.0f / fmaxf((float)cntd[idx], 1.0f);
    }
  }
  if (t == 255) eptr[NN] = EE;
}

__global__ __launch_bounds__(256) void k_scatter(const int* __restrict__ ei,
                                                 int* __restrict__ cursor,
                                                 int* __restrict__ eord) {
  int e = blockIdx.x * 256 + threadIdx.x;
  if (e < EE) {
    int pos = atomicAdd(cursor + ei[e], 1);
    eord[pos] = e;
  }
}

// ---- permute s into eord order + gather dst (once; reused 4 layers) -------
__global__ __launch_bounds__(256) void k_sperm(const unsigned short* __restrict__ s_bf,
                                               const int* __restrict__ ei,
                                               const int* __restrict__ eord,
                                               unsigned* __restrict__ s_srt,
                                               int* __restrict__ dst_srt) {
  const int j = blockIdx.x * 4 + (threadIdx.x >> 6);
  const int lane = threadIdx.x & 63;
  const int e = eord[j];
  s_srt[(size_t)j * 64 + lane] = ((const unsigned*)s_bf)[(size_t)e * 64 + lane];
  if (lane == 0) dst_srt[j] = ei[EE + e];
}

// -------- lift: x = silu(x_in@flW.T+flb); also xb, xb2, agg=0 --------------
__global__ __launch_bounds__(256) void k_lift(const void* __restrict__ xin,
                                              const float* __restrict__ flW,
                                              const float* __restrict__ flb,
                                              const float* __restrict__ b2,
                                              float* __restrict__ x,
                                              unsigned short* __restrict__ xb,
                                              float* __restrict__ xb2,
                                              float* __restrict__ agg,
                                              const int* __restrict__ flag) {
  const int f = *flag;
  int node = blockIdx.x * 4 + (threadIdx.x >> 6);
  int h = threadIdx.x & 63;
  float acc = flb[h];
#pragma unroll
  for (int c = 0; c < 11; c++)
    acc += rawf(xin, f, node * 11 + c) * flW[h * 11 + c];
  float v = siluf(acc);
  x[node * 64 + h] = v;
  xb[node * 64 + h] = f2b(v);
  int xvi = __float_as_int(v);
  float a2 = 0.0f;
#pragma unroll 8
  for (int i = 0; i < 64; i++) {
    float xi = rdlane(xvi, i);
    a2 += xi * b2[i * 64 + h];
  }
  xb2[node * 64 + h] = a2;
  agg[(size_t)node * 64 + h] = 0.0f;
}

// ---------- s[e,k] = silu(ef @ nn_W1.T + nn_b1) bf16 -----------------------
__global__ __launch_bounds__(256) void k_sdeg(const void* __restrict__ ea,
                                              const void* __restrict__ pos,
                                              const int* __restrict__ ei,
                                              const float* __restrict__ W1,
                                              const float* __restrict__ b1,
                                              unsigned short* __restrict__ s_bf,
                                              const int* __restrict__ flag) {
  const int f = *flag;
  int e = blockIdx.x * 2 + (threadIdx.x >> 7);
  int k = threadIdx.x & 127;
  int src = ei[e], dst = ei[EE + e];
  float dx = rawf(pos, f, src * 3 + 0) - rawf(pos, f, dst * 3 + 0);
  float dy = rawf(pos, f, src * 3 + 1) - rawf(pos, f, dst * 3 + 1);
  float dz = rawf(pos, f, src * 3 + 2) - rawf(pos, f, dst * 3 + 2);
  float dist = sqrtf(dx * dx + dy * dy + dz * dz);
  float acc = b1[k];
  acc += rawf(ea, f, e * 4 + 0) * W1[k * 5 + 0];
  acc += rawf(ea, f, e * 4 + 1) * W1[k * 5 + 1];
  acc += rawf(ea, f, e * 4 + 2) * W1[k * 5 + 2];
  acc += rawf(ea, f, e * 4 + 3) * W1[k * 5 + 3];
  acc += dist * W1[k * 5 + 4];
  s_bf[e * 128 + k] = f2b(siluf(acc));
}

// ---- W2t[(o*128+k)*64 + i] = bf16(W2[(i*64+o)*128 + k]) -------------------
__global__ __launch_bounds__(256) void k_w2t(const float* __restrict__ W2,
                                             unsigned short* __restrict__ W2t) {
  int j = blockIdx.x * 256 + threadIdx.x;
  int i = j & 63;
  int k = (j >> 6) & 127;
  int o = j >> 13;
  W2t[j] = f2b(W2[(size_t)(i * 64 + o) * 128 + k]);
}

// ---- T GEMM with LDS-staged coalesced epilogue ----------------------------
template <int KC>
__global__ __launch_bounds__(256) void k_T(const unsigned short* __restrict__ xb,
                                           const unsigned short* __restrict__ W2t,
                                           unsigned short* __restrict__ Tc, int K0) {
  __shared__ unsigned short sh[2 * 128 * 72];
  unsigned short* As = sh;
  unsigned short* Bs = sh + 128 * 72;
  const int t = threadIdx.x;
  const int n0 = blockIdx.x * 128;
  const int c0 = blockIdx.y * 128;
  const int lane = t & 63;
  const int w = t >> 6;
  const int lm = lane & 15;
  const int quad = lane >> 4;
  const int wm = w & 1;
  const int wn = w >> 1;

  for (int p = t; p < 128 * 8; p += 256) {
    int r = p >> 3, cc = (p & 7) * 8;
    uint4 v = make_uint4(0u, 0u, 0u, 0u);
    if (n0 + r < NN) v = *reinterpret_cast<const uint4*>(xb + (size_t)(n0 + r) * 64 + cc);
    *reinterpret_cast<uint4*>(&As[r * 72 + cc]) = v;
  }
  for (int p = t; p < 128 * 8; p += 256) {
    int r = p >> 3, cc = (p & 7) * 8;
    int c = c0 + r;
    int o = c / KC;
    int kg = K0 + (c % KC);
    uint4 v = *reinterpret_cast<const uint4*>(W2t + (size_t)(o * 128 + kg) * 64 + cc);
    *reinterpret_cast<uint4*>(&Bs[r * 72 + cc]) = v;
  }
  __syncthreads();

  f32x4 acc[4][4];
#pragma unroll
  for (int mt = 0; mt < 4; mt++)
#pragma unroll
    for (int nt = 0; nt < 4; nt++) acc[mt][nt] = (f32x4)(0.0f);

#pragma unroll
  for (int ks = 0; ks < 2; ks++) {
    const int kk = ks * 32 + quad * 8;
    short8 af[4], bfr[4];
#pragma unroll
    for (int mt = 0; mt < 4; mt++)
      af[mt] = *reinterpret_cast<const short8*>(&As[(wm * 64 + mt * 16 + lm) * 72 + kk]);
#pragma unroll
    for (int nt = 0; nt < 4; nt++)
      bfr[nt] = *reinterpret_cast<const short8*>(&Bs[(wn * 64 + nt * 16 + lm) * 72 + kk]);
#pragma unroll
    for (int mt = 0; mt < 4; mt++)
#pragma unroll
      for (int nt = 0; nt < 4; nt++)
        acc[mt][nt] = __builtin_amdgcn_mfma_f32_16x16x32_bf16(af[mt], bfr[nt], acc[mt][nt], 0, 0, 0);
  }

  __syncthreads();
  unsigned short* st = sh;
#pragma unroll
  for (int nt = 0; nt < 4; nt++) {
    int col = wn * 64 + nt * 16 + lm;
#pragma unroll
    for (int mt = 0; mt < 4; mt++) {
#pragma unroll
      for (int reg = 0; reg < 4; reg++) {
        int row = wm * 64 + mt * 16 + quad * 4 + reg;
        st[row * 132 + col] = f2b(acc[mt][nt][reg]);
      }
    }
  }
  __syncthreads();
  const int r16 = t >> 4;
  const int c8 = (t & 15) * 8;
#pragma unroll
  for (int it = 0; it < 8; it++) {
    int row = it * 16 + r16;
    int n = n0 + row;
    if (n < NN) {
      uint2 v0 = *reinterpret_cast<const uint2*>(&st[row * 132 + c8]);
      uint2 v1 = *reinterpret_cast<const uint2*>(&st[row * 132 + c8 + 4]);
      uint4 v = make_uint4(v0.x, v0.y, v1.x, v1.y);
      *reinterpret_cast<uint4*>(Tc + (size_t)n * (64 * KC) + c0 + c8) = v;
    }
  }
}

// ---- grouped edge pass v4: MFMA per node ----------------------------------
__global__ __launch_bounds__(256) void k_group(const unsigned short* __restrict__ Tc,
                                               const unsigned* __restrict__ s_srt,
                                               const int* __restrict__ dst_srt,
                                               const float* __restrict__ xb2,
                                               const int* __restrict__ eptr,
                                               float* __restrict__ agg) {
  const int n = blockIdx.x * 4 + (threadIdx.x >> 6);
  const int lane = threadIdx.x & 63;
  const int beg = eptr[n], end = eptr[n + 1];
  if (beg == end) return;
  const int lm = lane & 15;
  const int quad = lane >> 4;

  short8 bf[4][4];
#pragma unroll
  for (int ks = 0; ks < 4; ks++)
#pragma unroll
    for (int ot = 0; ot < 4; ot++)
      bf[ks][ot] = *reinterpret_cast<const short8*>(
          Tc + (size_t)n * 8192 + (ot * 16 + lm) * 128 + ks * 32 + quad * 8);

  float xv[4];
#pragma unroll
  for (int ot = 0; ot < 4; ot++) xv[ot] = xb2[(size_t)n * 64 + ot * 16 + lm];

  for (int tile = beg; tile < end; tile += 16) {
    int eidx = tile + lm;
    if (eidx >= EE) eidx = EE - 1;
    f32x4 acc[4];
#pragma unroll
    for (int ot = 0; ot < 4; ot++) acc[ot] = (f32x4)(0.0f);
#pragma unroll
    for (int ks = 0; ks < 4; ks++) {
      short8 af = *reinterpret_cast<const short8*>(
          (const unsigned short*)s_srt + (size_t)eidx * 128 + ks * 32 + quad * 8);
#pragma unroll
      for (int ot = 0; ot < 4; ot++)
        acc[ot] = __builtin_amdgcn_mfma_f32_16x16x32_bf16(af, bf[ks][ot], acc[ot], 0, 0, 0);
    }
#pragma unroll
    for (int reg = 0; reg < 4; reg++) {
      int edge = tile + quad * 4 + reg;
      if (edge < end) {
        int dst = dst_srt[edge];
#pragma unroll
        for (int ot = 0; ot < 4; ot++)
          atomicAdd(agg + (size_t)dst * 64 + ot * 16 + lm, acc[ot][reg] + xv[ot]);
      }
    }
  }
}

// ---- fallback per-edge chunk dot (KC<128) ---------------------------------
template <int KC>
__global__ __launch_bounds__(256) void k_emsg(const unsigned short* __restrict__ Tc,
                                              const unsigned short* __restrict__ s_bf,
                                              const int* __restrict__ ei,
                                              float* __restrict__ m, int K0, int first) {
  int e = blockIdx.x * 4 + (threadIdx.x >> 6);
  int o = threadIdx.x & 63;
  int src = ei[e];
  const uint4* tv = reinterpret_cast<const uint4*>(Tc + ((size_t)src * 64 + o) * KC);
  const uint4* sv = reinterpret_cast<const uint4*>(s_bf + (size_t)e * 128 + K0);
  float acc = 0.0f;
#pragma unroll
  for (int j = 0; j < KC / 8; j++) {
    uint4 a = tv[j], b = sv[j];
    unsigned aa[4] = {a.x, a.y, a.z, a.w};
    unsigned bb[4] = {b.x, b.y, b.z, b.w};
#pragma unroll
    for (int q = 0; q < 4; q++)
      acc += b2f_lo(aa[q]) * b2f_lo(bb[q]) + b2f_hi(aa[q]) * b2f_hi(bb[q]);
  }
  float* mp = m + (size_t)e * 64 + o;
  if (first) *mp = acc;
  else *mp += acc;
}

__global__ __launch_bounds__(256) void k_aggm(const float* __restrict__ m,
                                              const float* __restrict__ xb2,
                                              const int* __restrict__ ei,
                                              float* __restrict__ agg) {
  int e = blockIdx.x * 4 + (threadIdx.x >> 6);
  int o = threadIdx.x & 63;
  int src = ei[e], dst = ei[EE + e];
  atomicAdd(agg + (size_t)dst * 64 + o, m[(size_t)e * 64 + o] + xb2[(size_t)src * 64 + o]);
}

// ---- xc + GRU + xb2/agg0 v4: 4 nodes/wave, weights loaded once per 4 ------
__global__ __launch_bounds__(256) void k_xcgru(float* __restrict__ x,
                                               unsigned short* __restrict__ xb,
                                               float* __restrict__ agg,
                                               const float* __restrict__ invd,
                                               const float* __restrict__ rWT,
                                               const float* __restrict__ rb,
                                               const float* __restrict__ WihT,
                                               const float* __restrict__ WhhT,
                                               const float* __restrict__ bih,
                                               const float* __restrict__ bhh,
                                               const float* __restrict__ b2,
                                               float* __restrict__ xb2,
                                               int last) {
  const int node0 = (blockIdx.x * 4 + (threadIdx.x >> 6)) * 4;  // 4 nodes/wave
  const int lane = threadIdx.x & 63;

  float xv[4], av[4], idv[4];
  int xvi[4];
#pragma unroll
  for (int nn = 0; nn < 4; nn++) {
    size_t base = (size_t)(node0 + nn) * 64 + lane;
    xv[nn] = x[base];
    av[nn] = agg[base];
    agg[base] = 0.0f;
    idv[nn] = invd[node0 + nn];
    xvi[nn] = __float_as_int(xv[nn]);
  }

  // xc = silu(x@rWT + rb + agg*invd)
  float acc[4] = {0, 0, 0, 0};
#pragma unroll 8
  for (int k = 0; k < 64; k++) {
    float rw = rWT[k * 64 + lane];
#pragma unroll
    for (int nn = 0; nn < 4; nn++) acc[nn] += rdlane(xvi[nn], k) * rw;
  }
  const float rbv = rb[lane];
  int xci[4];
#pragma unroll
  for (int nn = 0; nn < 4; nn++)
    xci[nn] = __float_as_int(siluf(acc[nn] + rbv + av[nn] * idv[nn]));

  // gi (xc) + gh (x_old), weights shared across 4 nodes
  float gi0[4], gi1[4], gi2[4], gh0[4], gh1[4], gh2[4];
  {
    const float bi0 = bih[lane], bi1 = bih[64 + lane], bi2 = bih[128 + lane];
    const float bh0 = bhh[lane], bh1 = bhh[64 + lane], bh2 = bhh[128 + lane];
#pragma unroll
    for (int nn = 0; nn < 4; nn++) {
      gi0[nn] = bi0; gi1[nn] = bi1; gi2[nn] = bi2;
      gh0[nn] = bh0; gh1[nn] = bh1; gh2[nn] = bh2;
    }
  }
#pragma unroll 2
  for (int k = 0; k < 64; k++) {
    const float* wi = WihT + k * 192;
    const float* wh = WhhT + k * 192;
    const float wi0 = wi[lane], wi1 = wi[64 + lane], wi2 = wi[128 + lane];
    const float wh0 = wh[lane], wh1 = wh[64 + lane], wh2 = wh[128 + lane];
#pragma unroll
    for (int nn = 0; nn < 4; nn++) {
      const float xck = rdlane(xci[nn], k);
      const float xvk = rdlane(xvi[nn], k);
      gi0[nn] += xck * wi0; gi1[nn] += xck * wi1; gi2[nn] += xck * wi2;
      gh0[nn] += xvk * wh0; gh1[nn] += xvk * wh1; gh2[nn] += xvk * wh2;
    }
  }

  int xni[4];
#pragma unroll
  for (int nn = 0; nn < 4; nn++) {
    const float r = sigm(gi0[nn] + gh0[nn]);
    const float z = sigm(gi1[nn] + gh1[nn]);
    const float ng = tanhf(gi2[nn] + r * gh2[nn]);
    const float xn = (1.0f - z) * ng + z * xv[nn];
    x[(size_t)(node0 + nn) * 64 + lane] = xn;
    xni[nn] = __float_as_int(xn);
  }

  if (!last) {
#pragma unroll
    for (int nn = 0; nn < 4; nn++)
      xb[(size_t)(node0 + nn) * 64 + lane] = f2b(__int_as_float(xni[nn]));
    float a2[4] = {0, 0, 0, 0};
#pragma unroll 8
    for (int i = 0; i < 64; i++) {
      const float bv = b2[i * 64 + lane];
#pragma unroll
      for (int nn = 0; nn < 4; nn++) a2[nn] += rdlane(xni[nn], i) * bv;
    }
#pragma unroll
    for (int nn = 0; nn < 4; nn++)
      xb2[(size_t)(node0 + nn) * 64 + lane] = a2[nn];
  }
}

// ---- fused Set2Set v2: 256 thr/graph, transposed weights, wave-parallel ---
__global__ __launch_bounds__(256) void k_s2s(const float* __restrict__ x,
                                             const int* __restrict__ batch,
                                             const float* __restrict__ WihT,
                                             const float* __restrict__ WhhT,
                                             const float* __restrict__ bih,
                                             const float* __restrict__ bhh,
                                             const float* __restrict__ W1T,
                                             const float* __restrict__ b1,
                                             const float* __restrict__ W2,
                                             const float* __restrict__ b2o,
                                             void* __restrict__ out,
                                             const int* __restrict__ flag) {
  const int b = blockIdx.x;
  const int t = threadIdx.x;
  const int lane = t & 63;
  const int w = t >> 6;
  int lo = 0, hi = NN;
  while (lo < hi) { int mid = (lo + hi) >> 1; if (batch[mid] < b) lo = mid + 1; else hi = mid; }
  const int ns = lo;
  hi = NN;
  while (lo < hi) { int mid = (lo + hi) >> 1; if (batch[mid] <= b) lo = mid + 1; else hi = mid; }
  const int cnt = lo - ns;

  __shared__ float hs[64], rs[64], cs[64], gs[256];
  __shared__ float es[512];
  __shared__ float red[4][64];
  __shared__ float wred[4], wsum[4];
  if (t < 64) { hs[t] = 0.0f; rs[t] = 0.0f; cs[t] = 0.0f; }
  __syncthreads();

  for (int step = 0; step < 3; step++) {
    float acc = bih[t] + bhh[t];
#pragma unroll 4
    for (int k = 0; k < 64; k++)
      acc += hs[k] * (WihT[k * 256 + t] + WhhT[k * 256 + t]);
#pragma unroll 4
    for (int k = 0; k < 64; k++)
      acc += rs[k] * WihT[(64 + k) * 256 + t];
    gs[t] = acc;
    __syncthreads();
    if (t < 64) {
      float ig = sigm(gs[t]), fg = sigm(gs[64 + t]);
      float gg = tanhf(gs[128 + t]), og = sigm(gs[192 + t]);
      float c = fg * cs[t] + ig * gg;
      cs[t] = c;
      hs[t] = og * tanhf(c);
    }
    __syncthreads();

    float mxw = -3.4e38f;
    for (int j = w; j < cnt; j += 4) {
      float v = x[(size_t)(ns + j) * 64 + lane] * hs[lane];
#pragma unroll
      for (int mm = 32; mm; mm >>= 1) v += __shfl_xor(v, mm, 64);
      if (lane == 0 && j < 512) es[j] = v;
      mxw = fmaxf(mxw, v);
    }
    if (lane == 0) wred[w] = mxw;
    __syncthreads();
    float mx = fmaxf(fmaxf(wred[0], wred[1]), fmaxf(wred[2], wred[3]));

    float ps = 0.0f;
    for (int i = t; i < cnt && i < 512; i += 256) {
      float a = __expf(es[i] - mx);
      es[i] = a;
      ps += a;
    }
#pragma unroll
    for (int mm = 32; mm; mm >>= 1) ps += __shfl_xor(ps, mm, 64);
    if (lane == 0) wsum[w] = ps;
    __syncthreads();
    float tot = wsum[0] + wsum[1] + wsum[2] + wsum[3];
    float inv = (cnt > 0) ? 1.0f / tot : 0.0f;

    float pr = 0.0f;
    for (int j = w; j < cnt && j < 512; j += 4)
      pr += es[j] * x[(size_t)(ns + j) * 64 + lane];
    red[w][lane] = pr;
    __syncthreads();
    if (t < 64)
      rs[t] = (red[0][t] + red[1][t] + red[2][t] + red[3][t]) * inv;
    __syncthreads();
  }

  if (t < 64) {
    float acc = b1[lane];
#pragma unroll 4
    for (int k = 0; k < 64; k++) acc += hs[k] * W1T[k * 64 + lane];
#pragma unroll 4
    for (int k = 0; k < 64; k++) acc += rs[k] * W1T[(64 + k) * 64 + lane];
    float u = siluf(acc) * W2[lane];
#pragma unroll
    for (int mm = 32; mm; mm >>= 1) u += __shfl_xor(u, mm, 64);
    if (lane == 0) {
      float v = u + b2o[0];
      if (*flag) ((unsigned short*)out)[b] = f2b(v);
      else ((float*)out)[b] = v;
    }
  }
}

// ---------------------------------------------------------------------------
template <int KC>
static void run_chunks(const unsigned short* xb, const unsigned short* W2t,
                       unsigned short* Tc, const unsigned short* s_bf,
                       const int* ei, float* m, hipStream_t stream) {
  const int nch = 128 / KC;
  for (int c = 0; c < nch; c++) {
    k_T<KC><<<dim3((NN + 127) / 128, (64 * KC) / 128), 256, 0, stream>>>(xb, W2t, Tc, c * KC);
    k_emsg<KC><<<EE / 4, 256, 0, stream>>>(Tc, s_bf, ei, m, c * KC, c == 0 ? 1 : 0);
  }
}

extern "C" void kernel_launch(void* const* d_in, const int* in_sizes, int n_in,
                              void* d_out, int out_size, void* d_ws, size_t ws_size,
                              hipStream_t stream) {
  (void)n_in; (void)out_size;
  const bool sig_order = (in_sizes[1] == 2 * EE);
  const void* p_x   = d_in[0];
  const void* p_ea  = sig_order ? d_in[2] : d_in[1];
  const void* p_pos = sig_order ? d_in[3] : d_in[2];
  const int* edge_index = (const int*)(sig_order ? d_in[1] : d_in[3]);
  const int* batch      = (const int*)d_in[4];
  const void* p_w[20];
  for (int i = 0; i < 20; i++) p_w[i] = d_in[5 + i];

  char* base = (char*)d_ws;
  size_t off = 0;
  auto alloc = [&](size_t bytes) -> char* {
    char* p = base + off;
    off = (off + bytes + 255) & ~(size_t)255;
    return p;
  };
  int* flag = (int*)alloc(4);
  static const int cvt_n[NCVT] = {
      64 * 11, 64, 128 * 5, 128, 4096 * 128, 4096,
      64 * 64, 64,
      192 * 64, 192 * 64, 192, 192,
      256 * 128, 256 * 64, 256, 256,
      64 * 128, 64, 64, 1};
  float* canon[NCVT];
  for (int i = 0; i < NCVT; i++) canon[i] = (float*)alloc((size_t)cvt_n[i] * 4);
  const float* c_flW  = canon[0];
  const float* c_flb  = canon[1];
  const float* c_W1   = canon[2];
  const float* c_b1   = canon[3];
  const float* c_W2   = canon[4];
  const float* c_b2   = canon[5];
  const float* c_rW   = canon[6];
  const float* c_rb   = canon[7];
  const float* c_gWih = canon[8];
  const float* c_gWhh = canon[9];
  const float* c_gbih = canon[10];
  const float* c_gbhh = canon[11];
  const float* c_lWih = canon[12];
  const float* c_lWhh = canon[13];
  const float* c_lbih = canon[14];
  const float* c_lbhh = canon[15];
  const float* c_oW1  = canon[16];
  const float* c_ob1  = canon[17];
  const float* c_oW2  = canon[18];
  const float* c_ob2  = canon[19];

  unsigned short* s_bf = (unsigned short*)alloc((size_t)EE * 128 * 2);
  unsigned* s_srt = (unsigned*)alloc((size_t)EE * 64 * 4 + 4096);
  int* dst_srt = (int*)alloc((size_t)EE * 4);
  float* m    = (float*)alloc((size_t)EE * 64 * 4);  // fallback only
  float* x    = (float*)alloc((size_t)NN * 64 * 4);
  unsigned short* xb = (unsigned short*)alloc((size_t)NN * 64 * 2);
  float* agg  = (float*)alloc((size_t)NN * 64 * 4);
  float* xb2  = (float*)alloc((size_t)NN * 64 * 4);
  unsigned short* W2t = (unsigned short*)alloc((size_t)4096 * 128 * 2);
  float* invd = (float*)alloc((size_t)NN * 4);
  int* cnt    = (int*)alloc((size_t)2 * NN * 4);
  int* cntd   = cnt + NN;
  int* eptr   = (int*)alloc((size_t)(NN + 1) * 4);
  int* cursor = (int*)alloc((size_t)NN * 4);
  int* eord   = (int*)alloc((size_t)EE * 4);
  float* WihT = (float*)alloc((size_t)128 * 256 * 4);
  float* WhhT = (float*)alloc((size_t)64 * 256 * 4);
  float* W1T  = (float*)alloc((size_t)128 * 64 * 4);
  float* rWT  = (float*)alloc((size_t)64 * 64 * 4);
  float* gWihT = (float*)alloc((size_t)64 * 192 * 4);
  float* gWhhT = (float*)alloc((size_t)64 * 192 * 4);
  size_t base_need = off;

  int KC = 0;
  const int kcs[5] = {128, 64, 32, 16, 8};
  for (int i = 0; i < 5; i++) {
    size_t need = base_need + (size_t)NN * 64 * kcs[i] * 2 + 256;
    if (need <= ws_size) { KC = kcs[i]; break; }
  }
  if (KC == 0) return;
  unsigned short* Tc = (unsigned short*)alloc((size_t)NN * 64 * KC * 2);

  // ---- dtype detect + weight convert + transposes ----
  k_detect<<<1, 256, 0, stream>>>((const unsigned*)p_ea, flag);
  Cvt cvt;
  for (int i = 0; i < 20; i++) cvt.src[i] = p_w[i];
  for (int i = 0; i < NCVT; i++) { cvt.dst[i] = canon[i]; cvt.n[i] = cvt_n[i]; }
  k_convert<<<512, 256, 0, stream>>>(cvt, flag);
  k_ltrans<<<336, 256, 0, stream>>>(c_lWih, c_lWhh, c_oW1, c_rW, c_gWih, c_gWhh,
                                    WihT, WhhT, W1T, rWT, gWihT, gWhhT);

  // ---- prologue ----
  hipMemsetAsync(cnt, 0, (size_t)2 * NN * 4, stream);
  k_lift<<<NN / 4, 256, 0, stream>>>(p_x, c_flW, c_flb, c_b2, x, xb, xb2, agg, flag);
  k_sdeg<<<EE / 2, 256, 0, stream>>>(p_ea, p_pos, edge_index, c_W1, c_b1, s_bf, flag);
  k_w2t<<<(4096 * 128) / 256, 256, 0, stream>>>(c_W2, W2t);
  k_hist<<<(EE + 255) / 256, 256, 0, stream>>>(edge_index, cnt, cntd);
  k_scan<<<1, 256, 0, stream>>>(cnt, cntd, eptr, cursor, invd);
  k_scatter<<<(EE + 255) / 256, 256, 0, stream>>>(edge_index, cursor, eord);
  k_sperm<<<EE / 4, 256, 0, stream>>>(s_bf, edge_index, eord, s_srt, dst_srt);

  // ---- 4 message-passing layers ----
  for (int layer = 0; layer < 4; layer++) {
    if (KC == 128) {
      k_T<128><<<dim3((NN + 127) / 128, 64), 256, 0, stream>>>(xb, W2t, Tc, 0);
      k_group<<<NN / 4, 256, 0, stream>>>(Tc, s_srt, dst_srt, xb2, eptr, agg);
    } else {
      switch (KC) {
        case 64: run_chunks<64>(xb, W2t, Tc, s_bf, edge_index, m, stream); break;
        case 32: run_chunks<32>(xb, W2t, Tc, s_bf, edge_index, m, stream); break;
        case 16: run_chunks<16>(xb, W2t, Tc, s_bf, edge_index, m, stream); break;
        default: run_chunks<8>(xb, W2t, Tc, s_bf, edge_index, m, stream); break;
      }
      k_aggm<<<EE / 4, 256, 0, stream>>>(m, xb2, edge_index, agg);
    }
    k_xcgru<<<NN / 16, 256, 0, stream>>>(x, xb, agg, invd, rWT, c_rb,
                                         gWihT, gWhhT, c_gbih, c_gbhh,
                                         c_b2, xb2, layer == 3 ? 1 : 0);
  }

  // ---- Set2Set + output head (one kernel, 4 waves/graph) ----
  k_s2s<<<BBG, 256, 0, stream>>>(x, batch, WihT, WhhT, c_lbih, c_lbhh,
                                 W1T, c_ob1, c_oW2, c_ob2, d_out, flag);
}